// Round 1
// 3785.950 us; speedup vs baseline: 1.0617x; 1.0617x over previous
//
#include <hip/hip_runtime.h>

typedef unsigned long long ull;

#define N0_ 100000
#define N1_ 50000
#define N2_ 25000
#define N3_ 12500
#define EDG 1600000
#define CAP1 600000
#define CAP2 200000
#define CAP3 80000

struct Sel { ull prefix; int remaining; };

// ---------------- kernels ----------------

__global__ void sentinel_k(float* o, float v) { if (threadIdx.x == 0) o[0] = v; }

// C[n,128] = A[n,128] @ W[128,128] (+bias), ACC-typed accumulate. 64 rows/block.
template <typename TA, typename TC, typename ACC>
__global__ __launch_bounds__(256) void matmul128(const TA* __restrict__ A,
    const float* __restrict__ W, const float* __restrict__ bias,
    TC* __restrict__ C, int n) {
  __shared__ ACC Al[64 * 33];
  __shared__ ACC Wl[32 * 128];
  int tid = threadIdx.x;
  int colb = tid & 31;        // cols colb, colb+32, colb+64, colb+96
  int rg = tid >> 5;          // 0..7 -> rows rg*8..rg*8+7
  int row0 = blockIdx.x * 64;
  ACC acc[8][4];
#pragma unroll
  for (int r = 0; r < 8; ++r)
#pragma unroll
    for (int j = 0; j < 4; ++j) acc[r][j] = (ACC)0;
  for (int kt = 0; kt < 128; kt += 32) {
    for (int i = tid; i < 64 * 32; i += 256) {
      int r = i >> 5, kk = i & 31;
      int row = row0 + r;
      Al[r * 33 + kk] = (row < n) ? (ACC)A[(size_t)row * 128 + kt + kk] : (ACC)0;
    }
    for (int i = tid; i < 32 * 128; i += 256) {
      int kk = i >> 7, c = i & 127;
      Wl[i] = (ACC)W[(size_t)(kt + kk) * 128 + c];
    }
    __syncthreads();
#pragma unroll 4
    for (int kk = 0; kk < 32; ++kk) {
      ACC b0 = Wl[kk * 128 + colb];
      ACC b1 = Wl[kk * 128 + colb + 32];
      ACC b2 = Wl[kk * 128 + colb + 64];
      ACC b3 = Wl[kk * 128 + colb + 96];
#pragma unroll
      for (int r = 0; r < 8; ++r) {
        ACC a = Al[(rg * 8 + r) * 33 + kk];
        acc[r][0] += a * b0; acc[r][1] += a * b1;
        acc[r][2] += a * b2; acc[r][3] += a * b3;
      }
    }
    __syncthreads();
  }
  ACC bb0 = 0, bb1 = 0, bb2 = 0, bb3 = 0;
  if (bias) {
    bb0 = (ACC)bias[colb]; bb1 = (ACC)bias[colb + 32];
    bb2 = (ACC)bias[colb + 64]; bb3 = (ACC)bias[colb + 96];
  }
  for (int r = 0; r < 8; ++r) {
    int row = row0 + rg * 8 + r;
    if (row < n) {
      size_t o = (size_t)row * 128 + colb;
      C[o] = (TC)(acc[r][0] + bb0); C[o + 32] = (TC)(acc[r][1] + bb1);
      C[o + 64] = (TC)(acc[r][2] + bb2); C[o + 96] = (TC)(acc[r][3] + bb3);
    }
  }
}

// y[i,c] = di * sum_p h[src_p,c]*csrw[p] + h[i,c]*dgi[i] + b[c]
// unroll-8 neighbor loop: 8 independent row-gathers in flight per wave.
// All accumulation in double; storage types are template params.
template <typename TH, typename TY, bool RELU>
__global__ __launch_bounds__(256) void agg_conv(const TH* __restrict__ h,
    const int* __restrict__ off, const int* __restrict__ csrc,
    const float* __restrict__ csrw,
    const double* __restrict__ dinv, const double* __restrict__ dgi,
    const float* __restrict__ bias, TY* __restrict__ y, int n) {
  int c = threadIdx.x & 127;
  int node = blockIdx.x * 2 + (threadIdx.x >> 7);
  if (node >= n) return;
  double di = dinv[node];
  double self = (double)h[(size_t)node * 128 + c] * dgi[node];
  double accA = 0.0, accB = 0.0;
  int p = off[node], p1 = off[node + 1];
  for (; p + 8 <= p1; p += 8) {
    int s0 = csrc[p + 0], s1 = csrc[p + 1], s2 = csrc[p + 2], s3 = csrc[p + 3];
    int s4 = csrc[p + 4], s5 = csrc[p + 5], s6 = csrc[p + 6], s7 = csrc[p + 7];
    double w0 = (double)csrw[p + 0], w1 = (double)csrw[p + 1];
    double w2 = (double)csrw[p + 2], w3 = (double)csrw[p + 3];
    double w4 = (double)csrw[p + 4], w5 = (double)csrw[p + 5];
    double w6 = (double)csrw[p + 6], w7 = (double)csrw[p + 7];
    double v0 = (double)h[(size_t)s0 * 128 + c];
    double v1 = (double)h[(size_t)s1 * 128 + c];
    double v2 = (double)h[(size_t)s2 * 128 + c];
    double v3 = (double)h[(size_t)s3 * 128 + c];
    double v4 = (double)h[(size_t)s4 * 128 + c];
    double v5 = (double)h[(size_t)s5 * 128 + c];
    double v6 = (double)h[(size_t)s6 * 128 + c];
    double v7 = (double)h[(size_t)s7 * 128 + c];
    accA += v0 * w0; accB += v1 * w1; accA += v2 * w2; accB += v3 * w3;
    accA += v4 * w4; accB += v5 * w5; accA += v6 * w6; accB += v7 * w7;
  }
  for (; p + 4 <= p1; p += 4) {
    int s0 = csrc[p + 0], s1 = csrc[p + 1], s2 = csrc[p + 2], s3 = csrc[p + 3];
    double w0 = (double)csrw[p + 0], w1 = (double)csrw[p + 1];
    double w2 = (double)csrw[p + 2], w3 = (double)csrw[p + 3];
    double v0 = (double)h[(size_t)s0 * 128 + c];
    double v1 = (double)h[(size_t)s1 * 128 + c];
    double v2 = (double)h[(size_t)s2 * 128 + c];
    double v3 = (double)h[(size_t)s3 * 128 + c];
    accA += v0 * w0; accB += v1 * w1; accA += v2 * w2; accB += v3 * w3;
  }
  for (; p < p1; ++p)
    accA += (double)h[(size_t)csrc[p] * 128 + c] * (double)csrw[p];
  double r = (accA + accB) * di + self + (bias ? (double)bias[c] : 0.0);
  if (RELU) r = r > 0.0 ? r : 0.0;
  y[(size_t)node * 128 + c] = (TY)r;
}

// level-0 CSR build only
__global__ void count_deg(const int* __restrict__ dst, int m, int* __restrict__ cnt) {
  int e = blockIdx.x * 256 + threadIdx.x;
  if (e < m) atomicAdd(&cnt[dst[e]], 1);
}

__global__ void fin_deg(const int* __restrict__ cnt, double* __restrict__ dinv,
                        double* __restrict__ dgi, int n) {
  int i = blockIdx.x * 256 + threadIdx.x;
  if (i < n) {
    double d = 1.0 + (double)cnt[i];
    dinv[i] = 1.0 / sqrt(d);
    dgi[i] = 1.0 / d;
  }
}

__global__ __launch_bounds__(1024) void scan_excl(const int* __restrict__ in,
                                                  int* __restrict__ out, int n) {
  __shared__ int ls[1024];
  int t = threadIdx.x;
  int chunk = (n + 1023) >> 10;
  int base = t * chunk;
  int s = 0;
  for (int j = 0; j < chunk; ++j) { int i = base + j; if (i < n) s += in[i]; }
  ls[t] = s; __syncthreads();
  for (int d = 1; d < 1024; d <<= 1) {
    int v = (t >= d) ? ls[t - d] : 0;
    __syncthreads();
    ls[t] += v;
    __syncthreads();
  }
  int run = ls[t] - s;
  for (int j = 0; j < chunk; ++j) {
    int i = base + j;
    if (i < n) { out[i] = run; run += in[i]; }
  }
  if (t == 1023) out[n] = ls[1023];
}

__global__ void csr_fill(const int* __restrict__ src, const int* __restrict__ dst,
                         int m, const int* __restrict__ off,
                         int* __restrict__ cursor, int* __restrict__ csrs,
                         float* __restrict__ csrw, const double* __restrict__ dinv) {
  int e = blockIdx.x * 256 + threadIdx.x;
  if (e < m) {
    int d = dst[e];
    int s = src[e];
    int pos = off[d] + atomicAdd(&cursor[d], 1);
    csrs[pos] = s;
    csrw[pos] = (float)dinv[s];
  }
}

// ---- CSR-direct next-level build (no edge list, no atomics) ----
// knid[i] = new id if kept else -1.
__global__ void next_deg(const int* __restrict__ off, const int* __restrict__ csrs,
                         const int* __restrict__ knid, int* __restrict__ ndeg, int n) {
  int d = blockIdx.x * 256 + threadIdx.x;
  if (d >= n) return;
  int nd = knid[d];
  if (nd < 0) return;
  int cnt = 0;
  int p1 = off[d + 1];
  for (int p = off[d]; p < p1; ++p) cnt += (knid[csrs[p]] >= 0) ? 1 : 0;
  ndeg[nd] = cnt;
}

__global__ void next_fill(const int* __restrict__ off, const int* __restrict__ csrs,
                          const int* __restrict__ knid, const int* __restrict__ noff,
                          const double* __restrict__ ndinv,
                          int* __restrict__ ncsrs, float* __restrict__ ncsrw, int n) {
  int d = blockIdx.x * 256 + threadIdx.x;
  if (d >= n) return;
  int nd = knid[d];
  if (nd < 0) return;
  int pos = noff[nd];
  int p1 = off[d + 1];
  for (int p = off[d]; p < p1; ++p) {
    int s = knid[csrs[p]];
    if (s >= 0) { ncsrs[pos] = s; ncsrw[pos] = (float)ndinv[s]; ++pos; }
  }
}

// fixed grid of 256 blocks; deterministic per-block partials (no atomics).
template <typename T>
__global__ __launch_bounds__(256) void bn_stats(const T* __restrict__ x, int n,
                                                double* __restrict__ part) {
  __shared__ double lsum[256], lsq[256];
  int c = threadIdx.x & 127, half = threadIdx.x >> 7;
  double s = 0, q = 0;
  for (int row = blockIdx.x * 2 + half; row < n; row += 512) {
    double v = (double)x[(size_t)row * 128 + c];
    s += v; q += v * v;
  }
  lsum[threadIdx.x] = s; lsq[threadIdx.x] = q;
  __syncthreads();
  if (half == 0) {
    part[blockIdx.x * 256 + c] = lsum[c] + lsum[c + 128];
    part[blockIdx.x * 256 + 128 + c] = lsq[c] + lsq[c + 128];
  }
}

__global__ void bn_final(const double* __restrict__ part, const float* __restrict__ g,
                         const float* __restrict__ beta, double invn,
                         double* __restrict__ ss) {
  int c = threadIdx.x;  // 128
  double s = 0, q = 0;
  for (int b = 0; b < 256; ++b) {
    s += part[b * 256 + c];
    q += part[b * 256 + 128 + c];
  }
  double m = s * invn;
  double v = q * invn - m * m;
  double sc = (double)g[c] / sqrt(v + 1e-5);
  ss[c] = sc;
  ss[128 + c] = (double)beta[c] - m * sc;
}

// apply BN+ReLU in place; optionally write fp32 snapshot (skip connection).
template <typename T>
__global__ void bn_apply_relu(T* __restrict__ x, const double* __restrict__ ss,
                              float* __restrict__ snap, size_t total) {
  size_t i = (size_t)blockIdx.x * 256 + threadIdx.x;
  if (i < total) {
    int c = (int)(i & 127);
    double v = (double)x[i] * ss[c] + ss[128 + c];
    v = v > 0.0 ? v : 0.0;
    x[i] = (T)v;
    if (snap) snap[i] = (float)v;
  }
}

__global__ void wnorm_k(const float* __restrict__ w, double* __restrict__ wn) {
  __shared__ double red[128];
  int c = threadIdx.x;
  double v = (double)w[c];
  red[c] = v * v;
  __syncthreads();
  for (int s = 64; s > 0; s >>= 1) { if (c < s) red[c] += red[c + s]; __syncthreads(); }
  if (c == 0) wn[0] = sqrt(red[0]);
}

__global__ __launch_bounds__(256) void score_key_k(const float* __restrict__ x,
    const float* __restrict__ w, const double* __restrict__ wn,
    ull* __restrict__ keys, int n) {
  __shared__ double red[256];
  int c = threadIdx.x & 127;
  int node = blockIdx.x * 2 + (threadIdx.x >> 7);
  double p = 0.0;
  if (node < n) p = (double)x[(size_t)node * 128 + c] * (double)w[c];
  red[threadIdx.x] = p;
  __syncthreads();
  for (int s = 64; s > 0; s >>= 1) {
    if (c < s) red[threadIdx.x] += red[threadIdx.x + s];
    __syncthreads();
  }
  if (c == 0 && node < n) {
    double sc = tanh(red[threadIdx.x] / wn[0]);
    ull u = (ull)__double_as_longlong(sc);
    u = (u >> 63) ? ~u : (u | 0x8000000000000000ULL);
    keys[node] = u;
  }
}

__global__ void sel_init(Sel* sel, int k) {
  if (threadIdx.x == 0) { sel->prefix = 0ULL; sel->remaining = k; }
}

__global__ void rs_hist(const ull* __restrict__ keys, int n, const Sel* __restrict__ sel,
                        int shift, int pass, int* __restrict__ hist) {
  __shared__ int lh[256];
  lh[threadIdx.x] = 0;
  __syncthreads();
  int i = blockIdx.x * 256 + threadIdx.x;
  if (i < n) {
    ull k = keys[i];
    bool ok = (pass == 0) || (((k ^ sel->prefix) >> (shift + 8)) == 0);
    if (ok) atomicAdd(&lh[(int)((k >> shift) & 255)], 1);
  }
  __syncthreads();
  if (lh[threadIdx.x]) atomicAdd(&hist[threadIdx.x], lh[threadIdx.x]);
}

__global__ void rs_pick(const int* __restrict__ hist, Sel* sel, int shift) {
  __shared__ int lh[256];
  lh[threadIdx.x] = hist[threadIdx.x];
  __syncthreads();
  if (threadIdx.x == 0) {
    int rem = sel->remaining;
    for (int b = 255; b >= 0; --b) {
      int c = lh[b];
      if (c >= rem) { sel->prefix |= ((ull)b) << shift; break; }
      rem -= c;
    }
    sel->remaining = rem;
  }
}

__global__ void eq_flags(const ull* __restrict__ keys, const Sel* __restrict__ sel,
                         int* __restrict__ eqf, int n) {
  int i = blockIdx.x * 256 + threadIdx.x;
  if (i < n) eqf[i] = (keys[i] == sel->prefix) ? 1 : 0;
}

__global__ void kept_flags(const ull* __restrict__ keys, const Sel* __restrict__ sel,
                           const int* __restrict__ eqpre, int* __restrict__ kept, int n) {
  int i = blockIdx.x * 256 + threadIdx.x;
  if (i < n) {
    ull u = keys[i], p = sel->prefix;
    kept[i] = (u > p || (u == p && eqpre[i] < sel->remaining)) ? 1 : 0;
  }
}

// knid = new id if kept else -1; idx[newid] = old id.
__global__ void build_idx(const int* __restrict__ kept, const int* __restrict__ npre,
                          int* __restrict__ knid, int* __restrict__ idx, int n) {
  int i = blockIdx.x * 256 + threadIdx.x;
  if (i < n) {
    if (kept[i]) {
      int nid = npre[i];
      knid[i] = nid;
      idx[nid] = i;
    } else {
      knid[i] = -1;
    }
  }
}

__global__ void gather_rows(const float* __restrict__ xs, const int* __restrict__ idx,
                            float* __restrict__ xo, int k) {
  int i = blockIdx.x * 256 + threadIdx.x;
  if (i < k * 128) xo[i] = xs[(size_t)idx[i >> 7] * 128 + (i & 127)];
}

__global__ void scatter_add_rows(float* __restrict__ h, const float* __restrict__ t,
                                 const int* __restrict__ idx, int k) {
  int i = blockIdx.x * 256 + threadIdx.x;
  if (i < k * 128) h[(size_t)idx[i >> 7] * 128 + (i & 127)] += t[i];
}

// ---------------- host ----------------

extern "C" void kernel_launch(void* const* d_in, const int* in_sizes, int n_in,
                              void* d_out, int out_size, void* d_ws, size_t ws_size,
                              hipStream_t stream) {
  (void)in_sizes; (void)out_size;
  if (n_in < 17) return;
  const float* x_in   = (const float*)d_in[0];
  const int*   ei     = (const int*)  d_in[1];
  const float* in_W   = (const float*)d_in[2];
  const float* in_b   = (const float*)d_in[3];
  const float* dn_W   = (const float*)d_in[4];
  const float* dn_b   = (const float*)d_in[5];
  const float* dn_g   = (const float*)d_in[6];
  const float* dn_bt  = (const float*)d_in[7];
  const float* pool_w = (const float*)d_in[8];
  const float* bot_W  = (const float*)d_in[9];
  const float* bot_b  = (const float*)d_in[10];
  const float* up_W   = (const float*)d_in[11];
  const float* up_b   = (const float*)d_in[12];
  const float* up_g   = (const float*)d_in[13];
  const float* up_bt  = (const float*)d_in[14];
  const float* out_W  = (const float*)d_in[15];
  const float* out_b  = (const float*)d_in[16];
  float* outp = (float*)d_out;

  char* base = (char*)d_ws;
  size_t off = 0;
  auto alloc = [&](size_t b) -> void* {
    void* r = base + off;
    off = (off + b + 255) & ~(size_t)255;
    return r;
  };
  // fp32 storage everywhere; double accumulation inside kernels.
  float* bufA = (float*)alloc((size_t)N0_ * 128 * 4);   // 51.2 MB
  float* bufB = (float*)alloc((size_t)N0_ * 128 * 4);   // 51.2 MB
  float* xs0f = (float*)alloc((size_t)N0_ * 128 * 4);   // 51.2 MB
  float* xs1f = (float*)alloc((size_t)N1_ * 128 * 4);   // 25.6 MB
  float* xs2f = (float*)alloc((size_t)N2_ * 128 * 4);   // 12.8 MB

  int* csrs0 = (int*)alloc((size_t)EDG * 4);
  int* csrs1 = (int*)alloc((size_t)CAP1 * 4);
  int* csrs2 = (int*)alloc((size_t)CAP2 * 4);
  int* csrs3 = (int*)alloc((size_t)CAP3 * 4);
  float* csrw0 = (float*)alloc((size_t)EDG * 4);
  float* csrw1 = (float*)alloc((size_t)CAP1 * 4);
  float* csrw2 = (float*)alloc((size_t)CAP2 * 4);
  float* csrw3 = (float*)alloc((size_t)CAP3 * 4);
  int* csro0 = (int*)alloc((size_t)(N0_ + 1) * 4);
  int* csro1 = (int*)alloc((size_t)(N1_ + 1) * 4);
  int* csro2 = (int*)alloc((size_t)(N2_ + 1) * 4);
  int* csro3 = (int*)alloc((size_t)(N3_ + 1) * 4);
  double* dinv0 = (double*)alloc((size_t)N0_ * 8); double* dgi0 = (double*)alloc((size_t)N0_ * 8);
  double* dinv1 = (double*)alloc((size_t)N1_ * 8); double* dgi1 = (double*)alloc((size_t)N1_ * 8);
  double* dinv2 = (double*)alloc((size_t)N2_ * 8); double* dgi2 = (double*)alloc((size_t)N2_ * 8);
  double* dinv3 = (double*)alloc((size_t)N3_ * 8); double* dgi3 = (double*)alloc((size_t)N3_ * 8);
  ull* keys = (ull*)alloc((size_t)N0_ * 8);
  int* eqf   = (int*)alloc((size_t)N0_ * 4);
  int* eqpre = (int*)alloc((size_t)(N0_ + 1) * 4);
  int* kept  = (int*)alloc((size_t)N0_ * 4);
  int* npre  = (int*)alloc((size_t)(N0_ + 1) * 4);
  int* knid  = (int*)alloc((size_t)N0_ * 4);
  int* degcnt = (int*)alloc((size_t)N0_ * 4);
  int* cursor = (int*)alloc((size_t)N0_ * 4);
  int* idx0 = (int*)alloc((size_t)N1_ * 4);
  int* idx1 = (int*)alloc((size_t)N2_ * 4);
  int* idx2 = (int*)alloc((size_t)N3_ * 4);
  int* hist = (int*)alloc(8 * 256 * 4);
  Sel* sel  = (Sel*)alloc(256);
  double* bns = (double*)alloc((size_t)256 * 256 * 8);  // per-block BN partials
  double* ssb = (double*)alloc(256 * 8);
  double* wn  = (double*)alloc(256);
  if (off > ws_size) {  // signal: absmax will be ~ws_size
    sentinel_k<<<1, 64, 0, stream>>>(outp, (float)ws_size);
    return;
  }

  const int nL[4]   = {N0_, N1_, N2_, N3_};
  int* csrsL[4] = {csrs0, csrs1, csrs2, csrs3};
  float* csrwL[4] = {csrw0, csrw1, csrw2, csrw3};
  int* csroL[4] = {csro0, csro1, csro2, csro3};
  double* dinvL[4] = {dinv0, dinv1, dinv2, dinv3};
  double* dgiL[4]  = {dgi0, dgi1, dgi2, dgi3};
  int* idxL[3] = {idx0, idx1, idx2};

  auto cdiv = [](int a, int b) { return (a + b - 1) / b; };

  auto bn_f = [&](float* xp, int n, const float* g, const float* b, float* snap) {
    bn_stats<float><<<256, 256, 0, stream>>>(xp, n, bns);
    bn_final<<<1, 128, 0, stream>>>(bns, g, b, 1.0 / (double)n, ssb);
    bn_apply_relu<float><<<cdiv(n * 128, 256), 256, 0, stream>>>(xp, ssb, snap,
                                                                 (size_t)n * 128);
  };

  // pool level i: top-k on xcur; gather kept rows into xnext; build level i+1
  // CSR directly from level-i CSR (no edge list, no atomics).
  auto pool = [&](int i, const float* xcur, float* xnext) {
    int n = nL[i], k = nL[i + 1];
    wnorm_k<<<1, 128, 0, stream>>>(pool_w + i * 128, wn);
    score_key_k<<<cdiv(n, 2), 256, 0, stream>>>(xcur, pool_w + i * 128, wn, keys, n);
    sel_init<<<1, 64, 0, stream>>>(sel, k);
    hipMemsetAsync(hist, 0, 8 * 256 * 4, stream);
    for (int p = 0; p < 8; ++p) {
      int shift = 56 - 8 * p;
      rs_hist<<<cdiv(n, 256), 256, 0, stream>>>(keys, n, sel, shift, p, hist + p * 256);
      rs_pick<<<1, 256, 0, stream>>>(hist + p * 256, sel, shift);
    }
    eq_flags<<<cdiv(n, 256), 256, 0, stream>>>(keys, sel, eqf, n);
    scan_excl<<<1, 1024, 0, stream>>>(eqf, eqpre, n);
    kept_flags<<<cdiv(n, 256), 256, 0, stream>>>(keys, sel, eqpre, kept, n);
    scan_excl<<<1, 1024, 0, stream>>>(kept, npre, n);
    build_idx<<<cdiv(n, 256), 256, 0, stream>>>(kept, npre, knid, idxL[i], n);
    gather_rows<<<cdiv(k * 128, 256), 256, 0, stream>>>(xcur, idxL[i], xnext, k);
    // next-level CSR: deg -> dinv/dgi -> offsets -> fill
    next_deg<<<cdiv(n, 256), 256, 0, stream>>>(csroL[i], csrsL[i], knid, degcnt, n);
    fin_deg<<<cdiv(k, 256), 256, 0, stream>>>(degcnt, dinvL[i + 1], dgiL[i + 1], k);
    scan_excl<<<1, 1024, 0, stream>>>(degcnt, csroL[i + 1], k);
    next_fill<<<cdiv(n, 256), 256, 0, stream>>>(csroL[i], csrsL[i], knid,
        csroL[i + 1], dinvL[i + 1], csrsL[i + 1], csrwL[i + 1], n);
  };

  // ---- level 0 CSR (from raw edge list) ----
  hipMemsetAsync(degcnt, 0, (size_t)N0_ * 4, stream);
  count_deg<<<cdiv(EDG, 256), 256, 0, stream>>>(ei + EDG, EDG, degcnt);
  fin_deg<<<cdiv(N0_, 256), 256, 0, stream>>>(degcnt, dinv0, dgi0, N0_);
  scan_excl<<<1, 1024, 0, stream>>>(degcnt, csro0, N0_);
  hipMemsetAsync(cursor, 0, (size_t)N0_ * 4, stream);
  csr_fill<<<cdiv(EDG, 256), 256, 0, stream>>>(ei, ei + EDG, EDG, csro0, cursor,
                                               csrs0, csrw0, dinv0);

  // ---- initial conv (agg-first: agg(x W)+b = (agg x) W + b) ----
  agg_conv<float, float, false><<<cdiv(N0_, 2), 256, 0, stream>>>(
      x_in, csro0, csrs0, csrw0, dinv0, dgi0, nullptr, bufB, N0_);
  matmul128<float, float, double><<<cdiv(N0_, 64), 256, 0, stream>>>(bufB, in_W, in_b, bufA, N0_);

  // ---- down level 0: x in A, h in B, y back to A; snap -> xs0f; x1 -> B ----
  matmul128<float, float, double><<<cdiv(N0_, 64), 256, 0, stream>>>(bufA, dn_W, nullptr, bufB, N0_);
  agg_conv<float, float, false><<<cdiv(N0_, 2), 256, 0, stream>>>(
      bufB, csro0, csrs0, csrw0, dinv0, dgi0, dn_b, bufA, N0_);
  bn_f(bufA, N0_, dn_g, dn_bt, xs0f);
  pool(0, bufA, bufB);

  // ---- down level 1: x in B, h in A, y back to B; snap -> xs1f; x2 -> A ----
  matmul128<float, float, double><<<cdiv(N1_, 64), 256, 0, stream>>>(bufB, dn_W + 16384, nullptr, bufA, N1_);
  agg_conv<float, float, false><<<cdiv(N1_, 2), 256, 0, stream>>>(
      bufA, csro1, csrs1, csrw1, dinv1, dgi1, dn_b + 128, bufB, N1_);
  bn_f(bufB, N1_, dn_g + 128, dn_bt + 128, xs1f);
  pool(1, bufB, bufA);

  // ---- down level 2: x in A, h in B, y back to A; snap -> xs2f; x3 -> B ----
  matmul128<float, float, double><<<cdiv(N2_, 64), 256, 0, stream>>>(bufA, dn_W + 32768, nullptr, bufB, N2_);
  agg_conv<float, float, false><<<cdiv(N2_, 2), 256, 0, stream>>>(
      bufB, csro2, csrs2, csrw2, dinv2, dgi2, dn_b + 256, bufA, N2_);
  bn_f(bufA, N2_, dn_g + 256, dn_bt + 256, xs2f);
  pool(2, bufA, bufB);

  // ---- bottom: x3 in B, h3 -> A, z3 (relu) -> B ----
  matmul128<float, float, double><<<cdiv(N3_, 64), 256, 0, stream>>>(bufB, bot_W, nullptr, bufA, N3_);
  float* zf = bufB;
  float* hf = bufA;
  float* tf = outp;  // d_out as scratch until final write (fully overwritten)
  agg_conv<float, float, true><<<cdiv(N3_, 2), 256, 0, stream>>>(
      bufA, csro3, csrs3, csrw3, dinv3, dgi3, bot_b, zf, N3_);

  // ---- up path (fp32 data + fp32 accumulate): z in B, hf in A ----
  for (int u = 0; u < 3; ++u) {
    int l = 2 - u;
    int nl = nL[l], nz = nL[l + 1];
    const float* Wt = up_W + u * 32768;          // rows [0:128)  -> unpooled part
    const float* Wb = up_W + u * 32768 + 16384;  // rows [128:256)-> skip part
    const float* xsf = (u == 0) ? xs2f : (u == 1) ? xs1f : xs0f;
    matmul128<float, float, float><<<cdiv(nz, 64), 256, 0, stream>>>(zf, Wt, nullptr, tf, nz);
    matmul128<float, float, float><<<cdiv(nl, 64), 256, 0, stream>>>(xsf, Wb, nullptr, hf, nl);
    scatter_add_rows<<<cdiv(nz * 128, 256), 256, 0, stream>>>(hf, tf, idxL[l], nz);
    agg_conv<float, float, false><<<cdiv(nl, 2), 256, 0, stream>>>(
        hf, csroL[l], csrsL[l], csrwL[l], dinvL[l], dgiL[l], up_b + u * 128, zf, nl);
    bn_f(zf, nl, up_g + u * 128, up_bt + u * 128, nullptr);
  }

  // ---- final conv -> d_out ----
  matmul128<float, float, float><<<cdiv(N0_, 64), 256, 0, stream>>>(zf, out_W, nullptr, hf, N0_);
  agg_conv<float, float, false><<<cdiv(N0_, 2), 256, 0, stream>>>(
      hf, csro0, csrs0, csrw0, dinv0, dgi0, out_b, outp, N0_);
}

// Round 2
// 2888.514 us; speedup vs baseline: 1.3915x; 1.3107x over previous
//
#include <hip/hip_runtime.h>

typedef unsigned long long ull;

#define N0_ 100000
#define N1_ 50000
#define N2_ 25000
#define N3_ 12500
#define EDG 1600000
#define CAP1 600000
#define CAP2 200000
#define CAP3 80000

struct Sel { ull prefix; int remaining; };

// ---------------- kernels ----------------

__global__ void sentinel_k(float* o, float v) { if (threadIdx.x == 0) o[0] = v; }

// C[n,128] = A[n,128] @ W[128,128] (+bias), ACC-typed accumulate. 64 rows/block.
template <typename TA, typename TC, typename ACC>
__global__ __launch_bounds__(256) void matmul128(const TA* __restrict__ A,
    const float* __restrict__ W, const float* __restrict__ bias,
    TC* __restrict__ C, int n) {
  __shared__ ACC Al[64 * 33];
  __shared__ ACC Wl[32 * 128];
  int tid = threadIdx.x;
  int colb = tid & 31;        // cols colb, colb+32, colb+64, colb+96
  int rg = tid >> 5;          // 0..7 -> rows rg*8..rg*8+7
  int row0 = blockIdx.x * 64;
  ACC acc[8][4];
#pragma unroll
  for (int r = 0; r < 8; ++r)
#pragma unroll
    for (int j = 0; j < 4; ++j) acc[r][j] = (ACC)0;
  for (int kt = 0; kt < 128; kt += 32) {
    for (int i = tid; i < 64 * 32; i += 256) {
      int r = i >> 5, kk = i & 31;
      int row = row0 + r;
      Al[r * 33 + kk] = (row < n) ? (ACC)A[(size_t)row * 128 + kt + kk] : (ACC)0;
    }
    for (int i = tid; i < 32 * 128; i += 256) {
      int kk = i >> 7, c = i & 127;
      Wl[i] = (ACC)W[(size_t)(kt + kk) * 128 + c];
    }
    __syncthreads();
#pragma unroll 4
    for (int kk = 0; kk < 32; ++kk) {
      ACC b0 = Wl[kk * 128 + colb];
      ACC b1 = Wl[kk * 128 + colb + 32];
      ACC b2 = Wl[kk * 128 + colb + 64];
      ACC b3 = Wl[kk * 128 + colb + 96];
#pragma unroll
      for (int r = 0; r < 8; ++r) {
        ACC a = Al[(rg * 8 + r) * 33 + kk];
        acc[r][0] += a * b0; acc[r][1] += a * b1;
        acc[r][2] += a * b2; acc[r][3] += a * b3;
      }
    }
    __syncthreads();
  }
  ACC bb0 = 0, bb1 = 0, bb2 = 0, bb3 = 0;
  if (bias) {
    bb0 = (ACC)bias[colb]; bb1 = (ACC)bias[colb + 32];
    bb2 = (ACC)bias[colb + 64]; bb3 = (ACC)bias[colb + 96];
  }
  for (int r = 0; r < 8; ++r) {
    int row = row0 + rg * 8 + r;
    if (row < n) {
      size_t o = (size_t)row * 128 + colb;
      C[o] = (TC)(acc[r][0] + bb0); C[o + 32] = (TC)(acc[r][1] + bb1);
      C[o + 64] = (TC)(acc[r][2] + bb2); C[o + 96] = (TC)(acc[r][3] + bb3);
    }
  }
}

// y[i,c] = di * sum_p h[src_p,c]*csrw[p] + h[i,c]*dgi[i] + b[c]
// unroll-8 neighbor loop: 8 independent row-gathers in flight per wave.
// All accumulation in double; storage types are template params.
template <typename TH, typename TY, bool RELU>
__global__ __launch_bounds__(256) void agg_conv(const TH* __restrict__ h,
    const int* __restrict__ off, const int* __restrict__ csrc,
    const float* __restrict__ csrw,
    const double* __restrict__ dinv, const double* __restrict__ dgi,
    const float* __restrict__ bias, TY* __restrict__ y, int n) {
  int c = threadIdx.x & 127;
  int node = blockIdx.x * 2 + (threadIdx.x >> 7);
  if (node >= n) return;
  double di = dinv[node];
  double self = (double)h[(size_t)node * 128 + c] * dgi[node];
  double accA = 0.0, accB = 0.0;
  int p = off[node], p1 = off[node + 1];
  for (; p + 8 <= p1; p += 8) {
    int s0 = csrc[p + 0], s1 = csrc[p + 1], s2 = csrc[p + 2], s3 = csrc[p + 3];
    int s4 = csrc[p + 4], s5 = csrc[p + 5], s6 = csrc[p + 6], s7 = csrc[p + 7];
    double w0 = (double)csrw[p + 0], w1 = (double)csrw[p + 1];
    double w2 = (double)csrw[p + 2], w3 = (double)csrw[p + 3];
    double w4 = (double)csrw[p + 4], w5 = (double)csrw[p + 5];
    double w6 = (double)csrw[p + 6], w7 = (double)csrw[p + 7];
    double v0 = (double)h[(size_t)s0 * 128 + c];
    double v1 = (double)h[(size_t)s1 * 128 + c];
    double v2 = (double)h[(size_t)s2 * 128 + c];
    double v3 = (double)h[(size_t)s3 * 128 + c];
    double v4 = (double)h[(size_t)s4 * 128 + c];
    double v5 = (double)h[(size_t)s5 * 128 + c];
    double v6 = (double)h[(size_t)s6 * 128 + c];
    double v7 = (double)h[(size_t)s7 * 128 + c];
    accA += v0 * w0; accB += v1 * w1; accA += v2 * w2; accB += v3 * w3;
    accA += v4 * w4; accB += v5 * w5; accA += v6 * w6; accB += v7 * w7;
  }
  for (; p + 4 <= p1; p += 4) {
    int s0 = csrc[p + 0], s1 = csrc[p + 1], s2 = csrc[p + 2], s3 = csrc[p + 3];
    double w0 = (double)csrw[p + 0], w1 = (double)csrw[p + 1];
    double w2 = (double)csrw[p + 2], w3 = (double)csrw[p + 3];
    double v0 = (double)h[(size_t)s0 * 128 + c];
    double v1 = (double)h[(size_t)s1 * 128 + c];
    double v2 = (double)h[(size_t)s2 * 128 + c];
    double v3 = (double)h[(size_t)s3 * 128 + c];
    accA += v0 * w0; accB += v1 * w1; accA += v2 * w2; accB += v3 * w3;
  }
  for (; p < p1; ++p)
    accA += (double)h[(size_t)csrc[p] * 128 + c] * (double)csrw[p];
  double r = (accA + accB) * di + self + (bias ? (double)bias[c] : 0.0);
  if (RELU) r = r > 0.0 ? r : 0.0;
  y[(size_t)node * 128 + c] = (TY)r;
}

// level-0 CSR build only
__global__ void count_deg(const int* __restrict__ dst, int m, int* __restrict__ cnt) {
  int e = blockIdx.x * 256 + threadIdx.x;
  if (e < m) atomicAdd(&cnt[dst[e]], 1);
}

__global__ void fin_deg(const int* __restrict__ cnt, double* __restrict__ dinv,
                        double* __restrict__ dgi, int n) {
  int i = blockIdx.x * 256 + threadIdx.x;
  if (i < n) {
    double d = 1.0 + (double)cnt[i];
    dinv[i] = 1.0 / sqrt(d);
    dgi[i] = 1.0 / d;
  }
}

// ---- deterministic 3-phase multi-block exclusive scan ----
// phase 1: per-block (1024 elems) sums
__global__ __launch_bounds__(256) void scan_part(const int* __restrict__ in,
                                                 int* __restrict__ bsum, int n) {
  __shared__ int ts[256];
  int base = blockIdx.x * 1024 + threadIdx.x * 4;
  int s = 0;
#pragma unroll
  for (int j = 0; j < 4; ++j) { int i = base + j; if (i < n) s += in[i]; }
  ts[threadIdx.x] = s;
  __syncthreads();
  for (int d = 128; d > 0; d >>= 1) {
    if (threadIdx.x < d) ts[threadIdx.x] += ts[threadIdx.x + d];
    __syncthreads();
  }
  if (threadIdx.x == 0) bsum[blockIdx.x] = ts[0];
}

// phase 2: exclusive scan of block sums (nb <= 256 -> n <= 262144)
__global__ __launch_bounds__(256) void scan_bsum(int* __restrict__ bsum, int nb) {
  __shared__ int ls[256];
  int t = threadIdx.x;
  int v = (t < nb) ? bsum[t] : 0;
  ls[t] = v;
  __syncthreads();
  for (int d = 1; d < 256; d <<= 1) {
    int u = (t >= d) ? ls[t - d] : 0;
    __syncthreads();
    ls[t] += u;
    __syncthreads();
  }
  if (t < nb) bsum[t] = ls[t] - v;  // exclusive prefix
}

// phase 3: write exclusive prefix; last block writes out[n] = total
__global__ __launch_bounds__(256) void scan_out(const int* __restrict__ in,
    const int* __restrict__ bsum, int* __restrict__ out, int n, int nb) {
  __shared__ int ts[256];
  int base = blockIdx.x * 1024 + threadIdx.x * 4;
  int loc[4];
  int s = 0;
#pragma unroll
  for (int j = 0; j < 4; ++j) {
    int i = base + j;
    int v = (i < n) ? in[i] : 0;
    loc[j] = s; s += v;
  }
  ts[threadIdx.x] = s;
  __syncthreads();
  int mine = s;
  for (int d = 1; d < 256; d <<= 1) {
    int u = (threadIdx.x >= d) ? ts[threadIdx.x - d] : 0;
    __syncthreads();
    ts[threadIdx.x] += u;
    __syncthreads();
  }
  int toff = bsum[blockIdx.x] + ts[threadIdx.x] - mine;
#pragma unroll
  for (int j = 0; j < 4; ++j) {
    int i = base + j;
    if (i < n) out[i] = toff + loc[j];
  }
  if (blockIdx.x == nb - 1 && threadIdx.x == 255) out[n] = bsum[blockIdx.x] + ts[255];
}

__global__ void csr_fill(const int* __restrict__ src, const int* __restrict__ dst,
                         int m, const int* __restrict__ off,
                         int* __restrict__ cursor, int* __restrict__ csrs,
                         float* __restrict__ csrw, const double* __restrict__ dinv) {
  int e = blockIdx.x * 256 + threadIdx.x;
  if (e < m) {
    int d = dst[e];
    int s = src[e];
    int pos = off[d] + atomicAdd(&cursor[d], 1);
    csrs[pos] = s;
    csrw[pos] = (float)dinv[s];
  }
}

// ---- CSR-direct next-level build (no edge list, no atomics) ----
// knid[i] = new id if kept else -1.
__global__ void next_deg(const int* __restrict__ off, const int* __restrict__ csrs,
                         const int* __restrict__ knid, int* __restrict__ ndeg, int n) {
  int d = blockIdx.x * 256 + threadIdx.x;
  if (d >= n) return;
  int nd = knid[d];
  if (nd < 0) return;
  int cnt = 0;
  int p1 = off[d + 1];
  for (int p = off[d]; p < p1; ++p) cnt += (knid[csrs[p]] >= 0) ? 1 : 0;
  ndeg[nd] = cnt;
}

__global__ void next_fill(const int* __restrict__ off, const int* __restrict__ csrs,
                          const int* __restrict__ knid, const int* __restrict__ noff,
                          const double* __restrict__ ndinv,
                          int* __restrict__ ncsrs, float* __restrict__ ncsrw, int n) {
  int d = blockIdx.x * 256 + threadIdx.x;
  if (d >= n) return;
  int nd = knid[d];
  if (nd < 0) return;
  int pos = noff[nd];
  int p1 = off[d + 1];
  for (int p = off[d]; p < p1; ++p) {
    int s = knid[csrs[p]];
    if (s >= 0) { ncsrs[pos] = s; ncsrw[pos] = (float)ndinv[s]; ++pos; }
  }
}

// fixed grid of 256 blocks; deterministic per-block partials (no atomics).
template <typename T>
__global__ __launch_bounds__(256) void bn_stats(const T* __restrict__ x, int n,
                                                double* __restrict__ part) {
  __shared__ double lsum[256], lsq[256];
  int c = threadIdx.x & 127, half = threadIdx.x >> 7;
  double s = 0, q = 0;
  for (int row = blockIdx.x * 2 + half; row < n; row += 512) {
    double v = (double)x[(size_t)row * 128 + c];
    s += v; q += v * v;
  }
  lsum[threadIdx.x] = s; lsq[threadIdx.x] = q;
  __syncthreads();
  if (half == 0) {
    part[blockIdx.x * 256 + c] = lsum[c] + lsum[c + 128];
    part[blockIdx.x * 256 + 128 + c] = lsq[c] + lsq[c + 128];
  }
}

__global__ void bn_final(const double* __restrict__ part, const float* __restrict__ g,
                         const float* __restrict__ beta, double invn,
                         double* __restrict__ ss) {
  int c = threadIdx.x;  // 128
  double s = 0, q = 0;
  for (int b = 0; b < 256; ++b) {
    s += part[b * 256 + c];
    q += part[b * 256 + 128 + c];
  }
  double m = s * invn;
  double v = q * invn - m * m;
  double sc = (double)g[c] / sqrt(v + 1e-5);
  ss[c] = sc;
  ss[128 + c] = (double)beta[c] - m * sc;
}

// apply BN+ReLU in place; optionally write fp32 snapshot (skip connection).
template <typename T>
__global__ void bn_apply_relu(T* __restrict__ x, const double* __restrict__ ss,
                              float* __restrict__ snap, size_t total) {
  size_t i = (size_t)blockIdx.x * 256 + threadIdx.x;
  if (i < total) {
    int c = (int)(i & 127);
    double v = (double)x[i] * ss[c] + ss[128 + c];
    v = v > 0.0 ? v : 0.0;
    x[i] = (T)v;
    if (snap) snap[i] = (float)v;
  }
}

__global__ void wnorm_k(const float* __restrict__ w, double* __restrict__ wn) {
  __shared__ double red[128];
  int c = threadIdx.x;
  double v = (double)w[c];
  red[c] = v * v;
  __syncthreads();
  for (int s = 64; s > 0; s >>= 1) { if (c < s) red[c] += red[c + s]; __syncthreads(); }
  if (c == 0) wn[0] = sqrt(red[0]);
}

__global__ __launch_bounds__(256) void score_key_k(const float* __restrict__ x,
    const float* __restrict__ w, const double* __restrict__ wn,
    ull* __restrict__ keys, int n) {
  __shared__ double red[256];
  int c = threadIdx.x & 127;
  int node = blockIdx.x * 2 + (threadIdx.x >> 7);
  double p = 0.0;
  if (node < n) p = (double)x[(size_t)node * 128 + c] * (double)w[c];
  red[threadIdx.x] = p;
  __syncthreads();
  for (int s = 64; s > 0; s >>= 1) {
    if (c < s) red[threadIdx.x] += red[threadIdx.x + s];
    __syncthreads();
  }
  if (c == 0 && node < n) {
    double sc = tanh(red[threadIdx.x] / wn[0]);
    ull u = (ull)__double_as_longlong(sc);
    u = (u >> 63) ? ~u : (u | 0x8000000000000000ULL);
    keys[node] = u;
  }
}

__global__ void sel_init(Sel* sel, int k) {
  if (threadIdx.x == 0) { sel->prefix = 0ULL; sel->remaining = k; }
}

__global__ void rs_hist(const ull* __restrict__ keys, int n, const Sel* __restrict__ sel,
                        int shift, int pass, int* __restrict__ hist) {
  __shared__ int lh[256];
  lh[threadIdx.x] = 0;
  __syncthreads();
  int i = blockIdx.x * 256 + threadIdx.x;
  if (i < n) {
    ull k = keys[i];
    bool ok = (pass == 0) || (((k ^ sel->prefix) >> (shift + 8)) == 0);
    if (ok) atomicAdd(&lh[(int)((k >> shift) & 255)], 1);
  }
  __syncthreads();
  if (lh[threadIdx.x]) atomicAdd(&hist[threadIdx.x], lh[threadIdx.x]);
}

__global__ void rs_pick(const int* __restrict__ hist, Sel* sel, int shift) {
  __shared__ int lh[256];
  lh[threadIdx.x] = hist[threadIdx.x];
  __syncthreads();
  if (threadIdx.x == 0) {
    int rem = sel->remaining;
    for (int b = 255; b >= 0; --b) {
      int c = lh[b];
      if (c >= rem) { sel->prefix |= ((ull)b) << shift; break; }
      rem -= c;
    }
    sel->remaining = rem;
  }
}

__global__ void eq_flags(const ull* __restrict__ keys, const Sel* __restrict__ sel,
                         int* __restrict__ eqf, int n) {
  int i = blockIdx.x * 256 + threadIdx.x;
  if (i < n) eqf[i] = (keys[i] == sel->prefix) ? 1 : 0;
}

__global__ void kept_flags(const ull* __restrict__ keys, const Sel* __restrict__ sel,
                           const int* __restrict__ eqpre, int* __restrict__ kept, int n) {
  int i = blockIdx.x * 256 + threadIdx.x;
  if (i < n) {
    ull u = keys[i], p = sel->prefix;
    kept[i] = (u > p || (u == p && eqpre[i] < sel->remaining)) ? 1 : 0;
  }
}

// knid = new id if kept else -1; idx[newid] = old id.
__global__ void build_idx(const int* __restrict__ kept, const int* __restrict__ npre,
                          int* __restrict__ knid, int* __restrict__ idx, int n) {
  int i = blockIdx.x * 256 + threadIdx.x;
  if (i < n) {
    if (kept[i]) {
      int nid = npre[i];
      knid[i] = nid;
      idx[nid] = i;
    } else {
      knid[i] = -1;
    }
  }
}

__global__ void gather_rows(const float* __restrict__ xs, const int* __restrict__ idx,
                            float* __restrict__ xo, int k) {
  int i = blockIdx.x * 256 + threadIdx.x;
  if (i < k * 128) xo[i] = xs[(size_t)idx[i >> 7] * 128 + (i & 127)];
}

__global__ void scatter_add_rows(float* __restrict__ h, const float* __restrict__ t,
                                 const int* __restrict__ idx, int k) {
  int i = blockIdx.x * 256 + threadIdx.x;
  if (i < k * 128) h[(size_t)idx[i >> 7] * 128 + (i & 127)] += t[i];
}

// ---------------- host ----------------

extern "C" void kernel_launch(void* const* d_in, const int* in_sizes, int n_in,
                              void* d_out, int out_size, void* d_ws, size_t ws_size,
                              hipStream_t stream) {
  (void)in_sizes; (void)out_size;
  if (n_in < 17) return;
  const float* x_in   = (const float*)d_in[0];
  const int*   ei     = (const int*)  d_in[1];
  const float* in_W   = (const float*)d_in[2];
  const float* in_b   = (const float*)d_in[3];
  const float* dn_W   = (const float*)d_in[4];
  const float* dn_b   = (const float*)d_in[5];
  const float* dn_g   = (const float*)d_in[6];
  const float* dn_bt  = (const float*)d_in[7];
  const float* pool_w = (const float*)d_in[8];
  const float* bot_W  = (const float*)d_in[9];
  const float* bot_b  = (const float*)d_in[10];
  const float* up_W   = (const float*)d_in[11];
  const float* up_b   = (const float*)d_in[12];
  const float* up_g   = (const float*)d_in[13];
  const float* up_bt  = (const float*)d_in[14];
  const float* out_W  = (const float*)d_in[15];
  const float* out_b  = (const float*)d_in[16];
  float* outp = (float*)d_out;

  char* base = (char*)d_ws;
  size_t off = 0;
  auto alloc = [&](size_t b) -> void* {
    void* r = base + off;
    off = (off + b + 255) & ~(size_t)255;
    return r;
  };
  // fp32 storage everywhere; double accumulation inside kernels.
  float* bufA = (float*)alloc((size_t)N0_ * 128 * 4);   // 51.2 MB
  float* bufB = (float*)alloc((size_t)N0_ * 128 * 4);   // 51.2 MB
  float* xs0f = (float*)alloc((size_t)N0_ * 128 * 4);   // 51.2 MB
  float* xs1f = (float*)alloc((size_t)N1_ * 128 * 4);   // 25.6 MB
  float* xs2f = (float*)alloc((size_t)N2_ * 128 * 4);   // 12.8 MB

  int* csrs0 = (int*)alloc((size_t)EDG * 4);
  int* csrs1 = (int*)alloc((size_t)CAP1 * 4);
  int* csrs2 = (int*)alloc((size_t)CAP2 * 4);
  int* csrs3 = (int*)alloc((size_t)CAP3 * 4);
  float* csrw0 = (float*)alloc((size_t)EDG * 4);
  float* csrw1 = (float*)alloc((size_t)CAP1 * 4);
  float* csrw2 = (float*)alloc((size_t)CAP2 * 4);
  float* csrw3 = (float*)alloc((size_t)CAP3 * 4);
  int* csro0 = (int*)alloc((size_t)(N0_ + 1) * 4);
  int* csro1 = (int*)alloc((size_t)(N1_ + 1) * 4);
  int* csro2 = (int*)alloc((size_t)(N2_ + 1) * 4);
  int* csro3 = (int*)alloc((size_t)(N3_ + 1) * 4);
  double* dinv0 = (double*)alloc((size_t)N0_ * 8); double* dgi0 = (double*)alloc((size_t)N0_ * 8);
  double* dinv1 = (double*)alloc((size_t)N1_ * 8); double* dgi1 = (double*)alloc((size_t)N1_ * 8);
  double* dinv2 = (double*)alloc((size_t)N2_ * 8); double* dgi2 = (double*)alloc((size_t)N2_ * 8);
  double* dinv3 = (double*)alloc((size_t)N3_ * 8); double* dgi3 = (double*)alloc((size_t)N3_ * 8);
  ull* keys = (ull*)alloc((size_t)N0_ * 8);
  int* eqf   = (int*)alloc((size_t)N0_ * 4);
  int* eqpre = (int*)alloc((size_t)(N0_ + 1) * 4);
  int* kept  = (int*)alloc((size_t)N0_ * 4);
  int* npre  = (int*)alloc((size_t)(N0_ + 1) * 4);
  int* knid  = (int*)alloc((size_t)N0_ * 4);
  int* degcnt = (int*)alloc((size_t)N0_ * 4);
  int* cursor = (int*)alloc((size_t)N0_ * 4);
  int* idx0 = (int*)alloc((size_t)N1_ * 4);
  int* idx1 = (int*)alloc((size_t)N2_ * 4);
  int* idx2 = (int*)alloc((size_t)N3_ * 4);
  int* hist = (int*)alloc(8 * 256 * 4);
  Sel* sel  = (Sel*)alloc(256);
  int* bscan = (int*)alloc(256 * 4);               // block sums for 3-phase scan
  double* bns = (double*)alloc((size_t)256 * 256 * 8);  // per-block BN partials
  double* ssb = (double*)alloc(256 * 8);
  double* wn  = (double*)alloc(256);
  if (off > ws_size) {  // signal: absmax will be ~ws_size
    sentinel_k<<<1, 64, 0, stream>>>(outp, (float)ws_size);
    return;
  }

  const int nL[4]   = {N0_, N1_, N2_, N3_};
  int* csrsL[4] = {csrs0, csrs1, csrs2, csrs3};
  float* csrwL[4] = {csrw0, csrw1, csrw2, csrw3};
  int* csroL[4] = {csro0, csro1, csro2, csro3};
  double* dinvL[4] = {dinv0, dinv1, dinv2, dinv3};
  double* dgiL[4]  = {dgi0, dgi1, dgi2, dgi3};
  int* idxL[3] = {idx0, idx1, idx2};

  auto cdiv = [](int a, int b) { return (a + b - 1) / b; };

  // deterministic 3-phase exclusive scan (n <= 262144)
  auto scan = [&](const int* in, int* out, int n) {
    int nb = cdiv(n, 1024);
    scan_part<<<nb, 256, 0, stream>>>(in, bscan, n);
    scan_bsum<<<1, 256, 0, stream>>>(bscan, nb);
    scan_out<<<nb, 256, 0, stream>>>(in, bscan, out, n, nb);
  };

  auto bn_f = [&](float* xp, int n, const float* g, const float* b, float* snap) {
    bn_stats<float><<<256, 256, 0, stream>>>(xp, n, bns);
    bn_final<<<1, 128, 0, stream>>>(bns, g, b, 1.0 / (double)n, ssb);
    bn_apply_relu<float><<<cdiv(n * 128, 256), 256, 0, stream>>>(xp, ssb, snap,
                                                                 (size_t)n * 128);
  };

  // pool level i: top-k on xcur; gather kept rows into xnext; build level i+1
  // CSR directly from level-i CSR (no edge list, no atomics).
  auto pool = [&](int i, const float* xcur, float* xnext) {
    int n = nL[i], k = nL[i + 1];
    wnorm_k<<<1, 128, 0, stream>>>(pool_w + i * 128, wn);
    score_key_k<<<cdiv(n, 2), 256, 0, stream>>>(xcur, pool_w + i * 128, wn, keys, n);
    sel_init<<<1, 64, 0, stream>>>(sel, k);
    hipMemsetAsync(hist, 0, 8 * 256 * 4, stream);
    for (int p = 0; p < 8; ++p) {
      int shift = 56 - 8 * p;
      rs_hist<<<cdiv(n, 256), 256, 0, stream>>>(keys, n, sel, shift, p, hist + p * 256);
      rs_pick<<<1, 256, 0, stream>>>(hist + p * 256, sel, shift);
    }
    eq_flags<<<cdiv(n, 256), 256, 0, stream>>>(keys, sel, eqf, n);
    scan(eqf, eqpre, n);
    kept_flags<<<cdiv(n, 256), 256, 0, stream>>>(keys, sel, eqpre, kept, n);
    scan(kept, npre, n);
    build_idx<<<cdiv(n, 256), 256, 0, stream>>>(kept, npre, knid, idxL[i], n);
    gather_rows<<<cdiv(k * 128, 256), 256, 0, stream>>>(xcur, idxL[i], xnext, k);
    // next-level CSR: deg -> dinv/dgi -> offsets -> fill
    next_deg<<<cdiv(n, 256), 256, 0, stream>>>(csroL[i], csrsL[i], knid, degcnt, n);
    fin_deg<<<cdiv(k, 256), 256, 0, stream>>>(degcnt, dinvL[i + 1], dgiL[i + 1], k);
    scan(degcnt, csroL[i + 1], k);
    next_fill<<<cdiv(n, 256), 256, 0, stream>>>(csroL[i], csrsL[i], knid,
        csroL[i + 1], dinvL[i + 1], csrsL[i + 1], csrwL[i + 1], n);
  };

  // ---- level 0 CSR (from raw edge list) ----
  hipMemsetAsync(degcnt, 0, (size_t)N0_ * 4, stream);
  count_deg<<<cdiv(EDG, 256), 256, 0, stream>>>(ei + EDG, EDG, degcnt);
  fin_deg<<<cdiv(N0_, 256), 256, 0, stream>>>(degcnt, dinv0, dgi0, N0_);
  scan(degcnt, csro0, N0_);
  hipMemsetAsync(cursor, 0, (size_t)N0_ * 4, stream);
  csr_fill<<<cdiv(EDG, 256), 256, 0, stream>>>(ei, ei + EDG, EDG, csro0, cursor,
                                               csrs0, csrw0, dinv0);

  // ---- initial conv (agg-first: agg(x W)+b = (agg x) W + b) ----
  agg_conv<float, float, false><<<cdiv(N0_, 2), 256, 0, stream>>>(
      x_in, csro0, csrs0, csrw0, dinv0, dgi0, nullptr, bufB, N0_);
  matmul128<float, float, double><<<cdiv(N0_, 64), 256, 0, stream>>>(bufB, in_W, in_b, bufA, N0_);

  // ---- down level 0: x in A, h in B, y back to A; snap -> xs0f; x1 -> B ----
  matmul128<float, float, double><<<cdiv(N0_, 64), 256, 0, stream>>>(bufA, dn_W, nullptr, bufB, N0_);
  agg_conv<float, float, false><<<cdiv(N0_, 2), 256, 0, stream>>>(
      bufB, csro0, csrs0, csrw0, dinv0, dgi0, dn_b, bufA, N0_);
  bn_f(bufA, N0_, dn_g, dn_bt, xs0f);
  pool(0, bufA, bufB);

  // ---- down level 1: x in B, h in A, y back to B; snap -> xs1f; x2 -> A ----
  matmul128<float, float, double><<<cdiv(N1_, 64), 256, 0, stream>>>(bufB, dn_W + 16384, nullptr, bufA, N1_);
  agg_conv<float, float, false><<<cdiv(N1_, 2), 256, 0, stream>>>(
      bufA, csro1, csrs1, csrw1, dinv1, dgi1, dn_b + 128, bufB, N1_);
  bn_f(bufB, N1_, dn_g + 128, dn_bt + 128, xs1f);
  pool(1, bufB, bufA);

  // ---- down level 2: x in A, h in B, y back to A; snap -> xs2f; x3 -> B ----
  matmul128<float, float, double><<<cdiv(N2_, 64), 256, 0, stream>>>(bufA, dn_W + 32768, nullptr, bufB, N2_);
  agg_conv<float, float, false><<<cdiv(N2_, 2), 256, 0, stream>>>(
      bufB, csro2, csrs2, csrw2, dinv2, dgi2, dn_b + 256, bufA, N2_);
  bn_f(bufA, N2_, dn_g + 256, dn_bt + 256, xs2f);
  pool(2, bufA, bufB);

  // ---- bottom: x3 in B, h3 -> A, z3 (relu) -> B ----
  matmul128<float, float, double><<<cdiv(N3_, 64), 256, 0, stream>>>(bufB, bot_W, nullptr, bufA, N3_);
  float* zf = bufB;
  float* hf = bufA;
  float* tf = outp;  // d_out as scratch until final write (fully overwritten)
  agg_conv<float, float, true><<<cdiv(N3_, 2), 256, 0, stream>>>(
      bufA, csro3, csrs3, csrw3, dinv3, dgi3, bot_b, zf, N3_);

  // ---- up path (fp32 data + fp32 accumulate): z in B, hf in A ----
  for (int u = 0; u < 3; ++u) {
    int l = 2 - u;
    int nl = nL[l], nz = nL[l + 1];
    const float* Wt = up_W + u * 32768;          // rows [0:128)  -> unpooled part
    const float* Wb = up_W + u * 32768 + 16384;  // rows [128:256)-> skip part
    const float* xsf = (u == 0) ? xs2f : (u == 1) ? xs1f : xs0f;
    matmul128<float, float, float><<<cdiv(nz, 64), 256, 0, stream>>>(zf, Wt, nullptr, tf, nz);
    matmul128<float, float, float><<<cdiv(nl, 64), 256, 0, stream>>>(xsf, Wb, nullptr, hf, nl);
    scatter_add_rows<<<cdiv(nz * 128, 256), 256, 0, stream>>>(hf, tf, idxL[l], nz);
    agg_conv<float, float, false><<<cdiv(nl, 2), 256, 0, stream>>>(
        hf, csroL[l], csrsL[l], csrwL[l], dinvL[l], dgiL[l], up_b + u * 128, zf, nl);
    bn_f(zf, nl, up_g + u * 128, up_bt + u * 128, nullptr);
  }

  // ---- final conv -> d_out ----
  matmul128<float, float, float><<<cdiv(N0_, 64), 256, 0, stream>>>(zf, out_W, nullptr, hf, N0_);
  agg_conv<float, float, false><<<cdiv(N0_, 2), 256, 0, stream>>>(
      hf, csro0, csrs0, csrw0, dinv0, dgi0, out_b, outp, N0_);
}

// Round 3
// 2804.208 us; speedup vs baseline: 1.4333x; 1.0301x over previous
//
#include <hip/hip_runtime.h>

typedef unsigned long long ull;

#define N0_ 100000
#define N1_ 50000
#define N2_ 25000
#define N3_ 12500
#define EDG 1600000
#define CAP1 600000
#define CAP2 200000
#define CAP3 80000

struct Sel { ull prefix; int remaining; };

// ---------------- kernels ----------------

__global__ void sentinel_k(float* o, float v) { if (threadIdx.x == 0) o[0] = v; }

// C[n,128] = A[n,128] @ W[128,128] (+bias), ACC-typed accumulate. 64 rows/block.
// LDS staging is ALWAYS fp32 (source data is fp32); converted to ACC on read.
// Halves LDS for the double-ACC variant -> 3x occupancy.
template <typename TA, typename TC, typename ACC>
__global__ __launch_bounds__(256) void matmul128(const TA* __restrict__ A,
    const float* __restrict__ W, const float* __restrict__ bias,
    TC* __restrict__ C, int n) {
  __shared__ float Al[64 * 33];
  __shared__ float Wl[32 * 128];
  int tid = threadIdx.x;
  int colb = tid & 31;        // cols colb, colb+32, colb+64, colb+96
  int rg = tid >> 5;          // 0..7 -> rows rg*8..rg*8+7
  int row0 = blockIdx.x * 64;
  ACC acc[8][4];
#pragma unroll
  for (int r = 0; r < 8; ++r)
#pragma unroll
    for (int j = 0; j < 4; ++j) acc[r][j] = (ACC)0;
  for (int kt = 0; kt < 128; kt += 32) {
    for (int i = tid; i < 64 * 32; i += 256) {
      int r = i >> 5, kk = i & 31;
      int row = row0 + r;
      Al[r * 33 + kk] = (row < n) ? (float)A[(size_t)row * 128 + kt + kk] : 0.0f;
    }
    for (int i = tid; i < 32 * 128; i += 256) {
      int kk = i >> 7, c = i & 127;
      Wl[i] = W[(size_t)(kt + kk) * 128 + c];
    }
    __syncthreads();
#pragma unroll 4
    for (int kk = 0; kk < 32; ++kk) {
      ACC b0 = (ACC)Wl[kk * 128 + colb];
      ACC b1 = (ACC)Wl[kk * 128 + colb + 32];
      ACC b2 = (ACC)Wl[kk * 128 + colb + 64];
      ACC b3 = (ACC)Wl[kk * 128 + colb + 96];
#pragma unroll
      for (int r = 0; r < 8; ++r) {
        ACC a = (ACC)Al[(rg * 8 + r) * 33 + kk];
        acc[r][0] += a * b0; acc[r][1] += a * b1;
        acc[r][2] += a * b2; acc[r][3] += a * b3;
      }
    }
    __syncthreads();
  }
  ACC bb0 = 0, bb1 = 0, bb2 = 0, bb3 = 0;
  if (bias) {
    bb0 = (ACC)bias[colb]; bb1 = (ACC)bias[colb + 32];
    bb2 = (ACC)bias[colb + 64]; bb3 = (ACC)bias[colb + 96];
  }
  for (int r = 0; r < 8; ++r) {
    int row = row0 + rg * 8 + r;
    if (row < n) {
      size_t o = (size_t)row * 128 + colb;
      C[o] = (TC)(acc[r][0] + bb0); C[o + 32] = (TC)(acc[r][1] + bb1);
      C[o + 64] = (TC)(acc[r][2] + bb2); C[o + 96] = (TC)(acc[r][3] + bb3);
    }
  }
}

// y[i,c] = di * sum_p h[src_p,c]*csrw[p] + h[i,c]*dgi[i] + b[c]
// unroll-8 neighbor loop: 8 independent row-gathers in flight per wave.
// All accumulation in double; storage types are template params.
template <typename TH, typename TY, bool RELU>
__global__ __launch_bounds__(256) void agg_conv(const TH* __restrict__ h,
    const int* __restrict__ off, const int* __restrict__ csrc,
    const float* __restrict__ csrw,
    const double* __restrict__ dinv, const double* __restrict__ dgi,
    const float* __restrict__ bias, TY* __restrict__ y, int n) {
  int c = threadIdx.x & 127;
  int node = blockIdx.x * 2 + (threadIdx.x >> 7);
  if (node >= n) return;
  double di = dinv[node];
  double self = (double)h[(size_t)node * 128 + c] * dgi[node];
  double accA = 0.0, accB = 0.0;
  int p = off[node], p1 = off[node + 1];
  for (; p + 8 <= p1; p += 8) {
    int s0 = csrc[p + 0], s1 = csrc[p + 1], s2 = csrc[p + 2], s3 = csrc[p + 3];
    int s4 = csrc[p + 4], s5 = csrc[p + 5], s6 = csrc[p + 6], s7 = csrc[p + 7];
    double w0 = (double)csrw[p + 0], w1 = (double)csrw[p + 1];
    double w2 = (double)csrw[p + 2], w3 = (double)csrw[p + 3];
    double w4 = (double)csrw[p + 4], w5 = (double)csrw[p + 5];
    double w6 = (double)csrw[p + 6], w7 = (double)csrw[p + 7];
    double v0 = (double)h[(size_t)s0 * 128 + c];
    double v1 = (double)h[(size_t)s1 * 128 + c];
    double v2 = (double)h[(size_t)s2 * 128 + c];
    double v3 = (double)h[(size_t)s3 * 128 + c];
    double v4 = (double)h[(size_t)s4 * 128 + c];
    double v5 = (double)h[(size_t)s5 * 128 + c];
    double v6 = (double)h[(size_t)s6 * 128 + c];
    double v7 = (double)h[(size_t)s7 * 128 + c];
    accA += v0 * w0; accB += v1 * w1; accA += v2 * w2; accB += v3 * w3;
    accA += v4 * w4; accB += v5 * w5; accA += v6 * w6; accB += v7 * w7;
  }
  for (; p + 4 <= p1; p += 4) {
    int s0 = csrc[p + 0], s1 = csrc[p + 1], s2 = csrc[p + 2], s3 = csrc[p + 3];
    double w0 = (double)csrw[p + 0], w1 = (double)csrw[p + 1];
    double w2 = (double)csrw[p + 2], w3 = (double)csrw[p + 3];
    double v0 = (double)h[(size_t)s0 * 128 + c];
    double v1 = (double)h[(size_t)s1 * 128 + c];
    double v2 = (double)h[(size_t)s2 * 128 + c];
    double v3 = (double)h[(size_t)s3 * 128 + c];
    accA += v0 * w0; accB += v1 * w1; accA += v2 * w2; accB += v3 * w3;
  }
  for (; p < p1; ++p)
    accA += (double)h[(size_t)csrc[p] * 128 + c] * (double)csrw[p];
  double r = (accA + accB) * di + self + (bias ? (double)bias[c] : 0.0);
  if (RELU) r = r > 0.0 ? r : 0.0;
  y[(size_t)node * 128 + c] = (TY)r;
}

// level-0 CSR build only
__global__ void count_deg(const int* __restrict__ dst, int m, int* __restrict__ cnt) {
  int e = blockIdx.x * 256 + threadIdx.x;
  if (e < m) atomicAdd(&cnt[dst[e]], 1);
}

__global__ void fin_deg(const int* __restrict__ cnt, double* __restrict__ dinv,
                        double* __restrict__ dgi, int n) {
  int i = blockIdx.x * 256 + threadIdx.x;
  if (i < n) {
    double d = 1.0 + (double)cnt[i];
    dinv[i] = 1.0 / sqrt(d);
    dgi[i] = 1.0 / d;
  }
}

// ---- deterministic 3-phase multi-block exclusive scan ----
// phase 1: per-block (1024 elems) sums
__global__ __launch_bounds__(256) void scan_part(const int* __restrict__ in,
                                                 int* __restrict__ bsum, int n) {
  __shared__ int ts[256];
  int base = blockIdx.x * 1024 + threadIdx.x * 4;
  int s = 0;
#pragma unroll
  for (int j = 0; j < 4; ++j) { int i = base + j; if (i < n) s += in[i]; }
  ts[threadIdx.x] = s;
  __syncthreads();
  for (int d = 128; d > 0; d >>= 1) {
    if (threadIdx.x < d) ts[threadIdx.x] += ts[threadIdx.x + d];
    __syncthreads();
  }
  if (threadIdx.x == 0) bsum[blockIdx.x] = ts[0];
}

// phase 2: exclusive scan of block sums (nb <= 256 -> n <= 262144)
__global__ __launch_bounds__(256) void scan_bsum(int* __restrict__ bsum, int nb) {
  __shared__ int ls[256];
  int t = threadIdx.x;
  int v = (t < nb) ? bsum[t] : 0;
  ls[t] = v;
  __syncthreads();
  for (int d = 1; d < 256; d <<= 1) {
    int u = (t >= d) ? ls[t - d] : 0;
    __syncthreads();
    ls[t] += u;
    __syncthreads();
  }
  if (t < nb) bsum[t] = ls[t] - v;  // exclusive prefix
}

// phase 3: write exclusive prefix; last block writes out[n] = total
__global__ __launch_bounds__(256) void scan_out(const int* __restrict__ in,
    const int* __restrict__ bsum, int* __restrict__ out, int n, int nb) {
  __shared__ int ts[256];
  int base = blockIdx.x * 1024 + threadIdx.x * 4;
  int loc[4];
  int s = 0;
#pragma unroll
  for (int j = 0; j < 4; ++j) {
    int i = base + j;
    int v = (i < n) ? in[i] : 0;
    loc[j] = s; s += v;
  }
  ts[threadIdx.x] = s;
  __syncthreads();
  int mine = s;
  for (int d = 1; d < 256; d <<= 1) {
    int u = (threadIdx.x >= d) ? ts[threadIdx.x - d] : 0;
    __syncthreads();
    ts[threadIdx.x] += u;
    __syncthreads();
  }
  int toff = bsum[blockIdx.x] + ts[threadIdx.x] - mine;
#pragma unroll
  for (int j = 0; j < 4; ++j) {
    int i = base + j;
    if (i < n) out[i] = toff + loc[j];
  }
  if (blockIdx.x == nb - 1 && threadIdx.x == 255) out[n] = bsum[blockIdx.x] + ts[255];
}

__global__ void csr_fill(const int* __restrict__ src, const int* __restrict__ dst,
                         int m, const int* __restrict__ off,
                         int* __restrict__ cursor, int* __restrict__ csrs,
                         float* __restrict__ csrw, const double* __restrict__ dinv) {
  int e = blockIdx.x * 256 + threadIdx.x;
  if (e < m) {
    int d = dst[e];
    int s = src[e];
    int pos = off[d] + atomicAdd(&cursor[d], 1);
    csrs[pos] = s;
    csrw[pos] = (float)dinv[s];
  }
}

// ---- CSR-direct next-level build (no edge list, no atomics) ----
// knid[i] = new id if kept else -1.
__global__ void next_deg(const int* __restrict__ off, const int* __restrict__ csrs,
                         const int* __restrict__ knid, int* __restrict__ ndeg, int n) {
  int d = blockIdx.x * 256 + threadIdx.x;
  if (d >= n) return;
  int nd = knid[d];
  if (nd < 0) return;
  int cnt = 0;
  int p1 = off[d + 1];
  for (int p = off[d]; p < p1; ++p) cnt += (knid[csrs[p]] >= 0) ? 1 : 0;
  ndeg[nd] = cnt;
}

__global__ void next_fill(const int* __restrict__ off, const int* __restrict__ csrs,
                          const int* __restrict__ knid, const int* __restrict__ noff,
                          const double* __restrict__ ndinv,
                          int* __restrict__ ncsrs, float* __restrict__ ncsrw, int n) {
  int d = blockIdx.x * 256 + threadIdx.x;
  if (d >= n) return;
  int nd = knid[d];
  if (nd < 0) return;
  int pos = noff[nd];
  int p1 = off[d + 1];
  for (int p = off[d]; p < p1; ++p) {
    int s = knid[csrs[p]];
    if (s >= 0) { ncsrs[pos] = s; ncsrw[pos] = (float)ndinv[s]; ++pos; }
  }
}

// fixed grid of 256 blocks; deterministic per-block partials (no atomics).
template <typename T>
__global__ __launch_bounds__(256) void bn_stats(const T* __restrict__ x, int n,
                                                double* __restrict__ part) {
  __shared__ double lsum[256], lsq[256];
  int c = threadIdx.x & 127, half = threadIdx.x >> 7;
  double s = 0, q = 0;
  for (int row = blockIdx.x * 2 + half; row < n; row += 512) {
    double v = (double)x[(size_t)row * 128 + c];
    s += v; q += v * v;
  }
  lsum[threadIdx.x] = s; lsq[threadIdx.x] = q;
  __syncthreads();
  if (half == 0) {
    part[blockIdx.x * 256 + c] = lsum[c] + lsum[c + 128];
    part[blockIdx.x * 256 + 128 + c] = lsq[c] + lsq[c + 128];
  }
}

__global__ void bn_final(const double* __restrict__ part, const float* __restrict__ g,
                         const float* __restrict__ beta, double invn,
                         double* __restrict__ ss) {
  int c = threadIdx.x;  // 128
  double s = 0, q = 0;
  for (int b = 0; b < 256; ++b) {
    s += part[b * 256 + c];
    q += part[b * 256 + 128 + c];
  }
  double m = s * invn;
  double v = q * invn - m * m;
  double sc = (double)g[c] / sqrt(v + 1e-5);
  ss[c] = sc;
  ss[128 + c] = (double)beta[c] - m * sc;
}

// apply BN+ReLU in place; optionally write fp32 snapshot (skip connection).
template <typename T>
__global__ void bn_apply_relu(T* __restrict__ x, const double* __restrict__ ss,
                              float* __restrict__ snap, size_t total) {
  size_t i = (size_t)blockIdx.x * 256 + threadIdx.x;
  if (i < total) {
    int c = (int)(i & 127);
    double v = (double)x[i] * ss[c] + ss[128 + c];
    v = v > 0.0 ? v : 0.0;
    x[i] = (T)v;
    if (snap) snap[i] = (float)v;
  }
}

__global__ void wnorm_k(const float* __restrict__ w, double* __restrict__ wn) {
  __shared__ double red[128];
  int c = threadIdx.x;
  double v = (double)w[c];
  red[c] = v * v;
  __syncthreads();
  for (int s = 64; s > 0; s >>= 1) { if (c < s) red[c] += red[c + s]; __syncthreads(); }
  if (c == 0) wn[0] = sqrt(red[0]);
}

__global__ __launch_bounds__(256) void score_key_k(const float* __restrict__ x,
    const float* __restrict__ w, const double* __restrict__ wn,
    ull* __restrict__ keys, int n) {
  __shared__ double red[256];
  int c = threadIdx.x & 127;
  int node = blockIdx.x * 2 + (threadIdx.x >> 7);
  double p = 0.0;
  if (node < n) p = (double)x[(size_t)node * 128 + c] * (double)w[c];
  red[threadIdx.x] = p;
  __syncthreads();
  for (int s = 64; s > 0; s >>= 1) {
    if (c < s) red[threadIdx.x] += red[threadIdx.x + s];
    __syncthreads();
  }
  if (c == 0 && node < n) {
    double sc = tanh(red[threadIdx.x] / wn[0]);
    ull u = (ull)__double_as_longlong(sc);
    u = (u >> 63) ? ~u : (u | 0x8000000000000000ULL);
    keys[node] = u;
  }
}

__global__ void sel_init(Sel* sel, int k) {
  if (threadIdx.x == 0) { sel->prefix = 0ULL; sel->remaining = k; }
}

__global__ void rs_hist(const ull* __restrict__ keys, int n, const Sel* __restrict__ sel,
                        int shift, int pass, int* __restrict__ hist) {
  __shared__ int lh[256];
  lh[threadIdx.x] = 0;
  __syncthreads();
  int i = blockIdx.x * 256 + threadIdx.x;
  if (i < n) {
    ull k = keys[i];
    bool ok = (pass == 0) || (((k ^ sel->prefix) >> (shift + 8)) == 0);
    if (ok) atomicAdd(&lh[(int)((k >> shift) & 255)], 1);
  }
  __syncthreads();
  if (lh[threadIdx.x]) atomicAdd(&hist[threadIdx.x], lh[threadIdx.x]);
}

__global__ void rs_pick(const int* __restrict__ hist, Sel* sel, int shift) {
  __shared__ int lh[256];
  lh[threadIdx.x] = hist[threadIdx.x];
  __syncthreads();
  if (threadIdx.x == 0) {
    int rem = sel->remaining;
    for (int b = 255; b >= 0; --b) {
      int c = lh[b];
      if (c >= rem) { sel->prefix |= ((ull)b) << shift; break; }
      rem -= c;
    }
    sel->remaining = rem;
  }
}

__global__ void eq_flags(const ull* __restrict__ keys, const Sel* __restrict__ sel,
                         int* __restrict__ eqf, int n) {
  int i = blockIdx.x * 256 + threadIdx.x;
  if (i < n) eqf[i] = (keys[i] == sel->prefix) ? 1 : 0;
}

__global__ void kept_flags(const ull* __restrict__ keys, const Sel* __restrict__ sel,
                           const int* __restrict__ eqpre, int* __restrict__ kept, int n) {
  int i = blockIdx.x * 256 + threadIdx.x;
  if (i < n) {
    ull u = keys[i], p = sel->prefix;
    kept[i] = (u > p || (u == p && eqpre[i] < sel->remaining)) ? 1 : 0;
  }
}

// knid = new id if kept else -1; idx[newid] = old id.
__global__ void build_idx(const int* __restrict__ kept, const int* __restrict__ npre,
                          int* __restrict__ knid, int* __restrict__ idx, int n) {
  int i = blockIdx.x * 256 + threadIdx.x;
  if (i < n) {
    if (kept[i]) {
      int nid = npre[i];
      knid[i] = nid;
      idx[nid] = i;
    } else {
      knid[i] = -1;
    }
  }
}

__global__ void gather_rows(const float* __restrict__ xs, const int* __restrict__ idx,
                            float* __restrict__ xo, int k) {
  int i = blockIdx.x * 256 + threadIdx.x;
  if (i < k * 128) xo[i] = xs[(size_t)idx[i >> 7] * 128 + (i & 127)];
}

__global__ void scatter_add_rows(float* __restrict__ h, const float* __restrict__ t,
                                 const int* __restrict__ idx, int k) {
  int i = blockIdx.x * 256 + threadIdx.x;
  if (i < k * 128) h[(size_t)idx[i >> 7] * 128 + (i & 127)] += t[i];
}

// ---------------- host ----------------

extern "C" void kernel_launch(void* const* d_in, const int* in_sizes, int n_in,
                              void* d_out, int out_size, void* d_ws, size_t ws_size,
                              hipStream_t stream) {
  (void)in_sizes; (void)out_size;
  if (n_in < 17) return;
  const float* x_in   = (const float*)d_in[0];
  const int*   ei     = (const int*)  d_in[1];
  const float* in_W   = (const float*)d_in[2];
  const float* in_b   = (const float*)d_in[3];
  const float* dn_W   = (const float*)d_in[4];
  const float* dn_b   = (const float*)d_in[5];
  const float* dn_g   = (const float*)d_in[6];
  const float* dn_bt  = (const float*)d_in[7];
  const float* pool_w = (const float*)d_in[8];
  const float* bot_W  = (const float*)d_in[9];
  const float* bot_b  = (const float*)d_in[10];
  const float* up_W   = (const float*)d_in[11];
  const float* up_b   = (const float*)d_in[12];
  const float* up_g   = (const float*)d_in[13];
  const float* up_bt  = (const float*)d_in[14];
  const float* out_W  = (const float*)d_in[15];
  const float* out_b  = (const float*)d_in[16];
  float* outp = (float*)d_out;

  char* base = (char*)d_ws;
  size_t off = 0;
  auto alloc = [&](size_t b) -> void* {
    void* r = base + off;
    off = (off + b + 255) & ~(size_t)255;
    return r;
  };
  // fp32 storage everywhere; double accumulation inside kernels.
  float* bufA = (float*)alloc((size_t)N0_ * 128 * 4);   // 51.2 MB
  float* bufB = (float*)alloc((size_t)N0_ * 128 * 4);   // 51.2 MB
  float* xs0f = (float*)alloc((size_t)N0_ * 128 * 4);   // 51.2 MB
  float* xs1f = (float*)alloc((size_t)N1_ * 128 * 4);   // 25.6 MB
  float* xs2f = (float*)alloc((size_t)N2_ * 128 * 4);   // 12.8 MB

  int* csrs0 = (int*)alloc((size_t)EDG * 4);
  int* csrs1 = (int*)alloc((size_t)CAP1 * 4);
  int* csrs2 = (int*)alloc((size_t)CAP2 * 4);
  int* csrs3 = (int*)alloc((size_t)CAP3 * 4);
  float* csrw0 = (float*)alloc((size_t)EDG * 4);
  float* csrw1 = (float*)alloc((size_t)CAP1 * 4);
  float* csrw2 = (float*)alloc((size_t)CAP2 * 4);
  float* csrw3 = (float*)alloc((size_t)CAP3 * 4);
  int* csro0 = (int*)alloc((size_t)(N0_ + 1) * 4);
  int* csro1 = (int*)alloc((size_t)(N1_ + 1) * 4);
  int* csro2 = (int*)alloc((size_t)(N2_ + 1) * 4);
  int* csro3 = (int*)alloc((size_t)(N3_ + 1) * 4);
  double* dinv0 = (double*)alloc((size_t)N0_ * 8); double* dgi0 = (double*)alloc((size_t)N0_ * 8);
  double* dinv1 = (double*)alloc((size_t)N1_ * 8); double* dgi1 = (double*)alloc((size_t)N1_ * 8);
  double* dinv2 = (double*)alloc((size_t)N2_ * 8); double* dgi2 = (double*)alloc((size_t)N2_ * 8);
  double* dinv3 = (double*)alloc((size_t)N3_ * 8); double* dgi3 = (double*)alloc((size_t)N3_ * 8);
  ull* keys = (ull*)alloc((size_t)N0_ * 8);
  int* eqf   = (int*)alloc((size_t)N0_ * 4);
  int* eqpre = (int*)alloc((size_t)(N0_ + 1) * 4);
  int* kept  = (int*)alloc((size_t)N0_ * 4);
  int* npre  = (int*)alloc((size_t)(N0_ + 1) * 4);
  int* knid  = (int*)alloc((size_t)N0_ * 4);
  int* degcnt = (int*)alloc((size_t)N0_ * 4);
  int* cursor = (int*)alloc((size_t)N0_ * 4);
  int* idx0 = (int*)alloc((size_t)N1_ * 4);
  int* idx1 = (int*)alloc((size_t)N2_ * 4);
  int* idx2 = (int*)alloc((size_t)N3_ * 4);
  int* hist = (int*)alloc(8 * 256 * 4);
  Sel* sel  = (Sel*)alloc(256);
  int* bscan = (int*)alloc(256 * 4);               // block sums for 3-phase scan
  double* bns = (double*)alloc((size_t)256 * 256 * 8);  // per-block BN partials
  double* ssb = (double*)alloc(256 * 8);
  double* wn  = (double*)alloc(256);
  if (off > ws_size) {  // signal: absmax will be ~ws_size
    sentinel_k<<<1, 64, 0, stream>>>(outp, (float)ws_size);
    return;
  }

  const int nL[4]   = {N0_, N1_, N2_, N3_};
  int* csrsL[4] = {csrs0, csrs1, csrs2, csrs3};
  float* csrwL[4] = {csrw0, csrw1, csrw2, csrw3};
  int* csroL[4] = {csro0, csro1, csro2, csro3};
  double* dinvL[4] = {dinv0, dinv1, dinv2, dinv3};
  double* dgiL[4]  = {dgi0, dgi1, dgi2, dgi3};
  int* idxL[3] = {idx0, idx1, idx2};

  auto cdiv = [](int a, int b) { return (a + b - 1) / b; };

  // deterministic 3-phase exclusive scan (n <= 262144)
  auto scan = [&](const int* in, int* out, int n) {
    int nb = cdiv(n, 1024);
    scan_part<<<nb, 256, 0, stream>>>(in, bscan, n);
    scan_bsum<<<1, 256, 0, stream>>>(bscan, nb);
    scan_out<<<nb, 256, 0, stream>>>(in, bscan, out, n, nb);
  };

  auto bn_f = [&](float* xp, int n, const float* g, const float* b, float* snap) {
    bn_stats<float><<<256, 256, 0, stream>>>(xp, n, bns);
    bn_final<<<1, 128, 0, stream>>>(bns, g, b, 1.0 / (double)n, ssb);
    bn_apply_relu<float><<<cdiv(n * 128, 256), 256, 0, stream>>>(xp, ssb, snap,
                                                                 (size_t)n * 128);
  };

  // pool level i: top-k on xcur; gather kept rows into xnext; build level i+1
  // CSR directly from level-i CSR (no edge list, no atomics).
  auto pool = [&](int i, const float* xcur, float* xnext) {
    int n = nL[i], k = nL[i + 1];
    wnorm_k<<<1, 128, 0, stream>>>(pool_w + i * 128, wn);
    score_key_k<<<cdiv(n, 2), 256, 0, stream>>>(xcur, pool_w + i * 128, wn, keys, n);
    sel_init<<<1, 64, 0, stream>>>(sel, k);
    hipMemsetAsync(hist, 0, 8 * 256 * 4, stream);
    for (int p = 0; p < 8; ++p) {
      int shift = 56 - 8 * p;
      rs_hist<<<cdiv(n, 256), 256, 0, stream>>>(keys, n, sel, shift, p, hist + p * 256);
      rs_pick<<<1, 256, 0, stream>>>(hist + p * 256, sel, shift);
    }
    eq_flags<<<cdiv(n, 256), 256, 0, stream>>>(keys, sel, eqf, n);
    scan(eqf, eqpre, n);
    kept_flags<<<cdiv(n, 256), 256, 0, stream>>>(keys, sel, eqpre, kept, n);
    scan(kept, npre, n);
    build_idx<<<cdiv(n, 256), 256, 0, stream>>>(kept, npre, knid, idxL[i], n);
    gather_rows<<<cdiv(k * 128, 256), 256, 0, stream>>>(xcur, idxL[i], xnext, k);
    // next-level CSR: deg -> dinv/dgi -> offsets -> fill
    next_deg<<<cdiv(n, 256), 256, 0, stream>>>(csroL[i], csrsL[i], knid, degcnt, n);
    fin_deg<<<cdiv(k, 256), 256, 0, stream>>>(degcnt, dinvL[i + 1], dgiL[i + 1], k);
    scan(degcnt, csroL[i + 1], k);
    next_fill<<<cdiv(n, 256), 256, 0, stream>>>(csroL[i], csrsL[i], knid,
        csroL[i + 1], dinvL[i + 1], csrsL[i + 1], csrwL[i + 1], n);
  };

  // ---- level 0 CSR (from raw edge list) ----
  hipMemsetAsync(degcnt, 0, (size_t)N0_ * 4, stream);
  count_deg<<<cdiv(EDG, 256), 256, 0, stream>>>(ei + EDG, EDG, degcnt);
  fin_deg<<<cdiv(N0_, 256), 256, 0, stream>>>(degcnt, dinv0, dgi0, N0_);
  scan(degcnt, csro0, N0_);
  hipMemsetAsync(cursor, 0, (size_t)N0_ * 4, stream);
  csr_fill<<<cdiv(EDG, 256), 256, 0, stream>>>(ei, ei + EDG, EDG, csro0, cursor,
                                               csrs0, csrw0, dinv0);

  // ---- initial conv (agg-first: agg(x W)+b = (agg x) W + b) ----
  agg_conv<float, float, false><<<cdiv(N0_, 2), 256, 0, stream>>>(
      x_in, csro0, csrs0, csrw0, dinv0, dgi0, nullptr, bufB, N0_);
  matmul128<float, float, double><<<cdiv(N0_, 64), 256, 0, stream>>>(bufB, in_W, in_b, bufA, N0_);

  // ---- down level 0: x in A, h in B, y back to A; snap -> xs0f; x1 -> B ----
  matmul128<float, float, double><<<cdiv(N0_, 64), 256, 0, stream>>>(bufA, dn_W, nullptr, bufB, N0_);
  agg_conv<float, float, false><<<cdiv(N0_, 2), 256, 0, stream>>>(
      bufB, csro0, csrs0, csrw0, dinv0, dgi0, dn_b, bufA, N0_);
  bn_f(bufA, N0_, dn_g, dn_bt, xs0f);
  pool(0, bufA, bufB);

  // ---- down level 1: x in B, h in A, y back to B; snap -> xs1f; x2 -> A ----
  matmul128<float, float, double><<<cdiv(N1_, 64), 256, 0, stream>>>(bufB, dn_W + 16384, nullptr, bufA, N1_);
  agg_conv<float, float, false><<<cdiv(N1_, 2), 256, 0, stream>>>(
      bufA, csro1, csrs1, csrw1, dinv1, dgi1, dn_b + 128, bufB, N1_);
  bn_f(bufB, N1_, dn_g + 128, dn_bt + 128, xs1f);
  pool(1, bufB, bufA);

  // ---- down level 2: x in A, h in B, y back to A; snap -> xs2f; x3 -> B ----
  matmul128<float, float, double><<<cdiv(N2_, 64), 256, 0, stream>>>(bufA, dn_W + 32768, nullptr, bufB, N2_);
  agg_conv<float, float, false><<<cdiv(N2_, 2), 256, 0, stream>>>(
      bufB, csro2, csrs2, csrw2, dinv2, dgi2, dn_b + 256, bufA, N2_);
  bn_f(bufA, N2_, dn_g + 256, dn_bt + 256, xs2f);
  pool(2, bufA, bufB);

  // ---- bottom: x3 in B, h3 -> A, z3 (relu) -> B ----
  matmul128<float, float, double><<<cdiv(N3_, 64), 256, 0, stream>>>(bufB, bot_W, nullptr, bufA, N3_);
  float* zf = bufB;
  float* hf = bufA;
  float* tf = outp;  // d_out as scratch until final write (fully overwritten)
  agg_conv<float, float, true><<<cdiv(N3_, 2), 256, 0, stream>>>(
      bufA, csro3, csrs3, csrw3, dinv3, dgi3, bot_b, zf, N3_);

  // ---- up path (fp32 data + fp32 accumulate): z in B, hf in A ----
  for (int u = 0; u < 3; ++u) {
    int l = 2 - u;
    int nl = nL[l], nz = nL[l + 1];
    const float* Wt = up_W + u * 32768;          // rows [0:128)  -> unpooled part
    const float* Wb = up_W + u * 32768 + 16384;  // rows [128:256)-> skip part
    const float* xsf = (u == 0) ? xs2f : (u == 1) ? xs1f : xs0f;
    matmul128<float, float, float><<<cdiv(nz, 64), 256, 0, stream>>>(zf, Wt, nullptr, tf, nz);
    matmul128<float, float, float><<<cdiv(nl, 64), 256, 0, stream>>>(xsf, Wb, nullptr, hf, nl);
    scatter_add_rows<<<cdiv(nz * 128, 256), 256, 0, stream>>>(hf, tf, idxL[l], nz);
    agg_conv<float, float, false><<<cdiv(nl, 2), 256, 0, stream>>>(
        hf, csroL[l], csrsL[l], csrwL[l], dinvL[l], dgiL[l], up_b + u * 128, zf, nl);
    bn_f(zf, nl, up_g + u * 128, up_bt + u * 128, nullptr);
  }

  // ---- final conv -> d_out ----
  matmul128<float, float, float><<<cdiv(N0_, 64), 256, 0, stream>>>(zf, out_W, nullptr, hf, N0_);
  agg_conv<float, float, false><<<cdiv(N0_, 2), 256, 0, stream>>>(
      hf, csro0, csrs0, csrw0, dinv0, dgi0, out_b, outp, N0_);
}

// Round 4
// 2723.951 us; speedup vs baseline: 1.4756x; 1.0295x over previous
//
#include <hip/hip_runtime.h>

typedef unsigned long long ull;

#define N0_ 100000
#define N1_ 50000
#define N2_ 25000
#define N3_ 12500
#define EDG 1600000
#define CAP1 600000
#define CAP2 200000
#define CAP3 80000

struct Sel { ull prefix; int remaining; };

// ---------------- kernels ----------------

__global__ void sentinel_k(float* o, float v) { if (threadIdx.x == 0) o[0] = v; }

// C[n,128] = A[n,128] @ W[128,128] (+bias), ACC-typed accumulate. 64 rows/block.
// LDS staging is ALWAYS fp32 (source data is fp32); converted to ACC on read.
template <typename TA, typename TC, typename ACC>
__global__ __launch_bounds__(256) void matmul128(const TA* __restrict__ A,
    const float* __restrict__ W, const float* __restrict__ bias,
    TC* __restrict__ C, int n) {
  __shared__ float Al[64 * 33];
  __shared__ float Wl[32 * 128];
  int tid = threadIdx.x;
  int colb = tid & 31;        // cols colb, colb+32, colb+64, colb+96
  int rg = tid >> 5;          // 0..7 -> rows rg*8..rg*8+7
  int row0 = blockIdx.x * 64;
  ACC acc[8][4];
#pragma unroll
  for (int r = 0; r < 8; ++r)
#pragma unroll
    for (int j = 0; j < 4; ++j) acc[r][j] = (ACC)0;
  for (int kt = 0; kt < 128; kt += 32) {
    for (int i = tid; i < 64 * 32; i += 256) {
      int r = i >> 5, kk = i & 31;
      int row = row0 + r;
      Al[r * 33 + kk] = (row < n) ? (float)A[(size_t)row * 128 + kt + kk] : 0.0f;
    }
    for (int i = tid; i < 32 * 128; i += 256) {
      int kk = i >> 7, c = i & 127;
      Wl[i] = W[(size_t)(kt + kk) * 128 + c];
    }
    __syncthreads();
#pragma unroll 4
    for (int kk = 0; kk < 32; ++kk) {
      ACC b0 = (ACC)Wl[kk * 128 + colb];
      ACC b1 = (ACC)Wl[kk * 128 + colb + 32];
      ACC b2 = (ACC)Wl[kk * 128 + colb + 64];
      ACC b3 = (ACC)Wl[kk * 128 + colb + 96];
#pragma unroll
      for (int r = 0; r < 8; ++r) {
        ACC a = (ACC)Al[(rg * 8 + r) * 33 + kk];
        acc[r][0] += a * b0; acc[r][1] += a * b1;
        acc[r][2] += a * b2; acc[r][3] += a * b3;
      }
    }
    __syncthreads();
  }
  ACC bb0 = 0, bb1 = 0, bb2 = 0, bb3 = 0;
  if (bias) {
    bb0 = (ACC)bias[colb]; bb1 = (ACC)bias[colb + 32];
    bb2 = (ACC)bias[colb + 64]; bb3 = (ACC)bias[colb + 96];
  }
  for (int r = 0; r < 8; ++r) {
    int row = row0 + rg * 8 + r;
    if (row < n) {
      size_t o = (size_t)row * 128 + colb;
      C[o] = (TC)(acc[r][0] + bb0); C[o + 32] = (TC)(acc[r][1] + bb1);
      C[o + 64] = (TC)(acc[r][2] + bb2); C[o + 96] = (TC)(acc[r][3] + bb3);
    }
  }
}

// y[i,c] = di * sum_p h[src_p,c]*csrw[p] + h[i,c]*dgi[i] + b[c]
// float2 layout: 64 lanes per node (1 wave), each lane owns a column pair.
// One dwordx2 load per wave fetches a full 512B row. Double accumulate;
// per-column accA/accB interleave preserved -> bit-identical to scalar.
template <bool RELU>
__global__ __launch_bounds__(256) void agg_conv(const float* __restrict__ hp,
    const int* __restrict__ off, const int* __restrict__ csrc,
    const float* __restrict__ csrw,
    const double* __restrict__ dinv, const double* __restrict__ dgi,
    const float* __restrict__ bias, float* __restrict__ yp, int n) {
  const float2* __restrict__ h = (const float2*)hp;
  float2* __restrict__ y = (float2*)yp;
  int c2 = threadIdx.x & 63;                       // column pair
  int node = blockIdx.x * 4 + (threadIdx.x >> 6);  // 1 wave per node
  if (node >= n) return;
  double di = dinv[node];
  double dg = dgi[node];
  float2 hv = h[(size_t)node * 64 + c2];
  double selfx = (double)hv.x * dg;
  double selfy = (double)hv.y * dg;
  double accAx = 0.0, accBx = 0.0, accAy = 0.0, accBy = 0.0;
  int p = off[node], p1 = off[node + 1];
  for (; p + 8 <= p1; p += 8) {
    int s0 = csrc[p + 0], s1 = csrc[p + 1], s2 = csrc[p + 2], s3 = csrc[p + 3];
    int s4 = csrc[p + 4], s5 = csrc[p + 5], s6 = csrc[p + 6], s7 = csrc[p + 7];
    double w0 = (double)csrw[p + 0], w1 = (double)csrw[p + 1];
    double w2 = (double)csrw[p + 2], w3 = (double)csrw[p + 3];
    double w4 = (double)csrw[p + 4], w5 = (double)csrw[p + 5];
    double w6 = (double)csrw[p + 6], w7 = (double)csrw[p + 7];
    float2 v0 = h[(size_t)s0 * 64 + c2];
    float2 v1 = h[(size_t)s1 * 64 + c2];
    float2 v2 = h[(size_t)s2 * 64 + c2];
    float2 v3 = h[(size_t)s3 * 64 + c2];
    float2 v4 = h[(size_t)s4 * 64 + c2];
    float2 v5 = h[(size_t)s5 * 64 + c2];
    float2 v6 = h[(size_t)s6 * 64 + c2];
    float2 v7 = h[(size_t)s7 * 64 + c2];
    accAx += (double)v0.x * w0; accAy += (double)v0.y * w0;
    accBx += (double)v1.x * w1; accBy += (double)v1.y * w1;
    accAx += (double)v2.x * w2; accAy += (double)v2.y * w2;
    accBx += (double)v3.x * w3; accBy += (double)v3.y * w3;
    accAx += (double)v4.x * w4; accAy += (double)v4.y * w4;
    accBx += (double)v5.x * w5; accBy += (double)v5.y * w5;
    accAx += (double)v6.x * w6; accAy += (double)v6.y * w6;
    accBx += (double)v7.x * w7; accBy += (double)v7.y * w7;
  }
  for (; p + 4 <= p1; p += 4) {
    int s0 = csrc[p + 0], s1 = csrc[p + 1], s2 = csrc[p + 2], s3 = csrc[p + 3];
    double w0 = (double)csrw[p + 0], w1 = (double)csrw[p + 1];
    double w2 = (double)csrw[p + 2], w3 = (double)csrw[p + 3];
    float2 v0 = h[(size_t)s0 * 64 + c2];
    float2 v1 = h[(size_t)s1 * 64 + c2];
    float2 v2 = h[(size_t)s2 * 64 + c2];
    float2 v3 = h[(size_t)s3 * 64 + c2];
    accAx += (double)v0.x * w0; accAy += (double)v0.y * w0;
    accBx += (double)v1.x * w1; accBy += (double)v1.y * w1;
    accAx += (double)v2.x * w2; accAy += (double)v2.y * w2;
    accBx += (double)v3.x * w3; accBy += (double)v3.y * w3;
  }
  for (; p < p1; ++p) {
    double w = (double)csrw[p];
    float2 v = h[(size_t)csrc[p] * 64 + c2];
    accAx += (double)v.x * w; accAy += (double)v.y * w;
  }
  double bx = 0.0, by = 0.0;
  if (bias) { bx = (double)bias[c2 * 2]; by = (double)bias[c2 * 2 + 1]; }
  double rx = (accAx + accBx) * di + selfx + bx;
  double ry = (accAy + accBy) * di + selfy + by;
  if (RELU) { rx = rx > 0.0 ? rx : 0.0; ry = ry > 0.0 ? ry : 0.0; }
  y[(size_t)node * 64 + c2] = make_float2((float)rx, (float)ry);
}

// level-0 CSR build only
__global__ void count_deg(const int* __restrict__ dst, int m, int* __restrict__ cnt) {
  int e = blockIdx.x * 256 + threadIdx.x;
  if (e < m) atomicAdd(&cnt[dst[e]], 1);
}

__global__ void fin_deg(const int* __restrict__ cnt, double* __restrict__ dinv,
                        double* __restrict__ dgi, int n) {
  int i = blockIdx.x * 256 + threadIdx.x;
  if (i < n) {
    double d = 1.0 + (double)cnt[i];
    dinv[i] = 1.0 / sqrt(d);
    dgi[i] = 1.0 / d;
  }
}

// ---- deterministic 3-phase multi-block exclusive scan ----
__global__ __launch_bounds__(256) void scan_part(const int* __restrict__ in,
                                                 int* __restrict__ bsum, int n) {
  __shared__ int ts[256];
  int base = blockIdx.x * 1024 + threadIdx.x * 4;
  int s = 0;
#pragma unroll
  for (int j = 0; j < 4; ++j) { int i = base + j; if (i < n) s += in[i]; }
  ts[threadIdx.x] = s;
  __syncthreads();
  for (int d = 128; d > 0; d >>= 1) {
    if (threadIdx.x < d) ts[threadIdx.x] += ts[threadIdx.x + d];
    __syncthreads();
  }
  if (threadIdx.x == 0) bsum[blockIdx.x] = ts[0];
}

__global__ __launch_bounds__(256) void scan_bsum(int* __restrict__ bsum, int nb) {
  __shared__ int ls[256];
  int t = threadIdx.x;
  int v = (t < nb) ? bsum[t] : 0;
  ls[t] = v;
  __syncthreads();
  for (int d = 1; d < 256; d <<= 1) {
    int u = (t >= d) ? ls[t - d] : 0;
    __syncthreads();
    ls[t] += u;
    __syncthreads();
  }
  if (t < nb) bsum[t] = ls[t] - v;  // exclusive prefix
}

__global__ __launch_bounds__(256) void scan_out(const int* __restrict__ in,
    const int* __restrict__ bsum, int* __restrict__ out, int n, int nb) {
  __shared__ int ts[256];
  int base = blockIdx.x * 1024 + threadIdx.x * 4;
  int loc[4];
  int s = 0;
#pragma unroll
  for (int j = 0; j < 4; ++j) {
    int i = base + j;
    int v = (i < n) ? in[i] : 0;
    loc[j] = s; s += v;
  }
  ts[threadIdx.x] = s;
  __syncthreads();
  int mine = s;
  for (int d = 1; d < 256; d <<= 1) {
    int u = (threadIdx.x >= d) ? ts[threadIdx.x - d] : 0;
    __syncthreads();
    ts[threadIdx.x] += u;
    __syncthreads();
  }
  int toff = bsum[blockIdx.x] + ts[threadIdx.x] - mine;
#pragma unroll
  for (int j = 0; j < 4; ++j) {
    int i = base + j;
    if (i < n) out[i] = toff + loc[j];
  }
  if (blockIdx.x == nb - 1 && threadIdx.x == 255) out[n] = bsum[blockIdx.x] + ts[255];
}

__global__ void csr_fill(const int* __restrict__ src, const int* __restrict__ dst,
                         int m, const int* __restrict__ off,
                         int* __restrict__ cursor, int* __restrict__ csrs,
                         float* __restrict__ csrw, const double* __restrict__ dinv) {
  int e = blockIdx.x * 256 + threadIdx.x;
  if (e < m) {
    int d = dst[e];
    int s = src[e];
    int pos = off[d] + atomicAdd(&cursor[d], 1);
    csrs[pos] = s;
    csrw[pos] = (float)dinv[s];
  }
}

// ---- CSR-direct next-level build (no edge list, no atomics) ----
__global__ void next_deg(const int* __restrict__ off, const int* __restrict__ csrs,
                         const int* __restrict__ knid, int* __restrict__ ndeg, int n) {
  int d = blockIdx.x * 256 + threadIdx.x;
  if (d >= n) return;
  int nd = knid[d];
  if (nd < 0) return;
  int cnt = 0;
  int p1 = off[d + 1];
  for (int p = off[d]; p < p1; ++p) cnt += (knid[csrs[p]] >= 0) ? 1 : 0;
  ndeg[nd] = cnt;
}

__global__ void next_fill(const int* __restrict__ off, const int* __restrict__ csrs,
                          const int* __restrict__ knid, const int* __restrict__ noff,
                          const double* __restrict__ ndinv,
                          int* __restrict__ ncsrs, float* __restrict__ ncsrw, int n) {
  int d = blockIdx.x * 256 + threadIdx.x;
  if (d >= n) return;
  int nd = knid[d];
  if (nd < 0) return;
  int pos = noff[nd];
  int p1 = off[d + 1];
  for (int p = off[d]; p < p1; ++p) {
    int s = knid[csrs[p]];
    if (s >= 0) { ncsrs[pos] = s; ncsrw[pos] = (float)ndinv[s]; ++pos; }
  }
}

// fixed grid of 256 blocks; deterministic per-block partials (no atomics).
template <typename T>
__global__ __launch_bounds__(256) void bn_stats(const T* __restrict__ x, int n,
                                                double* __restrict__ part) {
  __shared__ double lsum[256], lsq[256];
  int c = threadIdx.x & 127, half = threadIdx.x >> 7;
  double s = 0, q = 0;
  for (int row = blockIdx.x * 2 + half; row < n; row += 512) {
    double v = (double)x[(size_t)row * 128 + c];
    s += v; q += v * v;
  }
  lsum[threadIdx.x] = s; lsq[threadIdx.x] = q;
  __syncthreads();
  if (half == 0) {
    part[blockIdx.x * 256 + c] = lsum[c] + lsum[c + 128];
    part[blockIdx.x * 256 + 128 + c] = lsq[c] + lsq[c + 128];
  }
}

__global__ void bn_final(const double* __restrict__ part, const float* __restrict__ g,
                         const float* __restrict__ beta, double invn,
                         double* __restrict__ ss) {
  int c = threadIdx.x;  // 128
  double s = 0, q = 0;
  for (int b = 0; b < 256; ++b) {
    s += part[b * 256 + c];
    q += part[b * 256 + 128 + c];
  }
  double m = s * invn;
  double v = q * invn - m * m;
  double sc = (double)g[c] / sqrt(v + 1e-5);
  ss[c] = sc;
  ss[128 + c] = (double)beta[c] - m * sc;
}

// apply BN+ReLU in place; optionally write fp32 snapshot (skip connection).
template <typename T>
__global__ void bn_apply_relu(T* __restrict__ x, const double* __restrict__ ss,
                              float* __restrict__ snap, size_t total) {
  size_t i = (size_t)blockIdx.x * 256 + threadIdx.x;
  if (i < total) {
    int c = (int)(i & 127);
    double v = (double)x[i] * ss[c] + ss[128 + c];
    v = v > 0.0 ? v : 0.0;
    x[i] = (T)v;
    if (snap) snap[i] = (float)v;
  }
}

__global__ void wnorm_k(const float* __restrict__ w, double* __restrict__ wn) {
  __shared__ double red[128];
  int c = threadIdx.x;
  double v = (double)w[c];
  red[c] = v * v;
  __syncthreads();
  for (int s = 64; s > 0; s >>= 1) { if (c < s) red[c] += red[c + s]; __syncthreads(); }
  if (c == 0) wn[0] = sqrt(red[0]);
}

__global__ __launch_bounds__(256) void score_key_k(const float* __restrict__ x,
    const float* __restrict__ w, const double* __restrict__ wn,
    ull* __restrict__ keys, int n) {
  __shared__ double red[256];
  int c = threadIdx.x & 127;
  int node = blockIdx.x * 2 + (threadIdx.x >> 7);
  double p = 0.0;
  if (node < n) p = (double)x[(size_t)node * 128 + c] * (double)w[c];
  red[threadIdx.x] = p;
  __syncthreads();
  for (int s = 64; s > 0; s >>= 1) {
    if (c < s) red[threadIdx.x] += red[threadIdx.x + s];
    __syncthreads();
  }
  if (c == 0 && node < n) {
    double sc = tanh(red[threadIdx.x] / wn[0]);
    ull u = (ull)__double_as_longlong(sc);
    u = (u >> 63) ? ~u : (u | 0x8000000000000000ULL);
    keys[node] = u;
  }
}

__global__ void sel_init(Sel* sel, int k) {
  if (threadIdx.x == 0) { sel->prefix = 0ULL; sel->remaining = k; }
}

__global__ void rs_hist(const ull* __restrict__ keys, int n, const Sel* __restrict__ sel,
                        int shift, int pass, int* __restrict__ hist) {
  __shared__ int lh[256];
  lh[threadIdx.x] = 0;
  __syncthreads();
  int i = blockIdx.x * 256 + threadIdx.x;
  if (i < n) {
    ull k = keys[i];
    bool ok = (pass == 0) || (((k ^ sel->prefix) >> (shift + 8)) == 0);
    if (ok) atomicAdd(&lh[(int)((k >> shift) & 255)], 1);
  }
  __syncthreads();
  if (lh[threadIdx.x]) atomicAdd(&hist[threadIdx.x], lh[threadIdx.x]);
}

__global__ void rs_pick(const int* __restrict__ hist, Sel* sel, int shift) {
  __shared__ int lh[256];
  lh[threadIdx.x] = hist[threadIdx.x];
  __syncthreads();
  if (threadIdx.x == 0) {
    int rem = sel->remaining;
    for (int b = 255; b >= 0; --b) {
      int c = lh[b];
      if (c >= rem) { sel->prefix |= ((ull)b) << shift; break; }
      rem -= c;
    }
    sel->remaining = rem;
  }
}

__global__ void eq_flags(const ull* __restrict__ keys, const Sel* __restrict__ sel,
                         int* __restrict__ eqf, int n) {
  int i = blockIdx.x * 256 + threadIdx.x;
  if (i < n) eqf[i] = (keys[i] == sel->prefix) ? 1 : 0;
}

__global__ void kept_flags(const ull* __restrict__ keys, const Sel* __restrict__ sel,
                           const int* __restrict__ eqpre, int* __restrict__ kept, int n) {
  int i = blockIdx.x * 256 + threadIdx.x;
  if (i < n) {
    ull u = keys[i], p = sel->prefix;
    kept[i] = (u > p || (u == p && eqpre[i] < sel->remaining)) ? 1 : 0;
  }
}

// knid = new id if kept else -1; idx[newid] = old id.
__global__ void build_idx(const int* __restrict__ kept, const int* __restrict__ npre,
                          int* __restrict__ knid, int* __restrict__ idx, int n) {
  int i = blockIdx.x * 256 + threadIdx.x;
  if (i < n) {
    if (kept[i]) {
      int nid = npre[i];
      knid[i] = nid;
      idx[nid] = i;
    } else {
      knid[i] = -1;
    }
  }
}

__global__ void gather_rows(const float* __restrict__ xs, const int* __restrict__ idx,
                            float* __restrict__ xo, int k) {
  int i = blockIdx.x * 256 + threadIdx.x;
  if (i < k * 128) xo[i] = xs[(size_t)idx[i >> 7] * 128 + (i & 127)];
}

__global__ void scatter_add_rows(float* __restrict__ h, const float* __restrict__ t,
                                 const int* __restrict__ idx, int k) {
  int i = blockIdx.x * 256 + threadIdx.x;
  if (i < k * 128) h[(size_t)idx[i >> 7] * 128 + (i & 127)] += t[i];
}

// ---------------- host ----------------

extern "C" void kernel_launch(void* const* d_in, const int* in_sizes, int n_in,
                              void* d_out, int out_size, void* d_ws, size_t ws_size,
                              hipStream_t stream) {
  (void)in_sizes; (void)out_size;
  if (n_in < 17) return;
  const float* x_in   = (const float*)d_in[0];
  const int*   ei     = (const int*)  d_in[1];
  const float* in_W   = (const float*)d_in[2];
  const float* in_b   = (const float*)d_in[3];
  const float* dn_W   = (const float*)d_in[4];
  const float* dn_b   = (const float*)d_in[5];
  const float* dn_g   = (const float*)d_in[6];
  const float* dn_bt  = (const float*)d_in[7];
  const float* pool_w = (const float*)d_in[8];
  const float* bot_W  = (const float*)d_in[9];
  const float* bot_b  = (const float*)d_in[10];
  const float* up_W   = (const float*)d_in[11];
  const float* up_b   = (const float*)d_in[12];
  const float* up_g   = (const float*)d_in[13];
  const float* up_bt  = (const float*)d_in[14];
  const float* out_W  = (const float*)d_in[15];
  const float* out_b  = (const float*)d_in[16];
  float* outp = (float*)d_out;

  char* base = (char*)d_ws;
  size_t off = 0;
  auto alloc = [&](size_t b) -> void* {
    void* r = base + off;
    off = (off + b + 255) & ~(size_t)255;
    return r;
  };
  // fp32 storage everywhere; double accumulation inside kernels.
  float* bufA = (float*)alloc((size_t)N0_ * 128 * 4);   // 51.2 MB
  float* bufB = (float*)alloc((size_t)N0_ * 128 * 4);   // 51.2 MB
  float* xs0f = (float*)alloc((size_t)N0_ * 128 * 4);   // 51.2 MB
  float* xs1f = (float*)alloc((size_t)N1_ * 128 * 4);   // 25.6 MB
  float* xs2f = (float*)alloc((size_t)N2_ * 128 * 4);   // 12.8 MB

  int* csrs0 = (int*)alloc((size_t)EDG * 4);
  int* csrs1 = (int*)alloc((size_t)CAP1 * 4);
  int* csrs2 = (int*)alloc((size_t)CAP2 * 4);
  int* csrs3 = (int*)alloc((size_t)CAP3 * 4);
  float* csrw0 = (float*)alloc((size_t)EDG * 4);
  float* csrw1 = (float*)alloc((size_t)CAP1 * 4);
  float* csrw2 = (float*)alloc((size_t)CAP2 * 4);
  float* csrw3 = (float*)alloc((size_t)CAP3 * 4);
  int* csro0 = (int*)alloc((size_t)(N0_ + 1) * 4);
  int* csro1 = (int*)alloc((size_t)(N1_ + 1) * 4);
  int* csro2 = (int*)alloc((size_t)(N2_ + 1) * 4);
  int* csro3 = (int*)alloc((size_t)(N3_ + 1) * 4);
  double* dinv0 = (double*)alloc((size_t)N0_ * 8); double* dgi0 = (double*)alloc((size_t)N0_ * 8);
  double* dinv1 = (double*)alloc((size_t)N1_ * 8); double* dgi1 = (double*)alloc((size_t)N1_ * 8);
  double* dinv2 = (double*)alloc((size_t)N2_ * 8); double* dgi2 = (double*)alloc((size_t)N2_ * 8);
  double* dinv3 = (double*)alloc((size_t)N3_ * 8); double* dgi3 = (double*)alloc((size_t)N3_ * 8);
  ull* keys = (ull*)alloc((size_t)N0_ * 8);
  int* eqf   = (int*)alloc((size_t)N0_ * 4);
  int* eqpre = (int*)alloc((size_t)(N0_ + 1) * 4);
  int* kept  = (int*)alloc((size_t)N0_ * 4);
  int* npre  = (int*)alloc((size_t)(N0_ + 1) * 4);
  int* knid  = (int*)alloc((size_t)N0_ * 4);
  int* degcnt = (int*)alloc((size_t)N0_ * 4);
  int* cursor = (int*)alloc((size_t)N0_ * 4);
  int* idx0 = (int*)alloc((size_t)N1_ * 4);
  int* idx1 = (int*)alloc((size_t)N2_ * 4);
  int* idx2 = (int*)alloc((size_t)N3_ * 4);
  int* hist = (int*)alloc(8 * 256 * 4);
  Sel* sel  = (Sel*)alloc(256);
  int* bscan = (int*)alloc(256 * 4);               // block sums for 3-phase scan
  double* bns = (double*)alloc((size_t)256 * 256 * 8);  // per-block BN partials
  double* ssb = (double*)alloc(256 * 8);
  double* wn  = (double*)alloc(256);
  if (off > ws_size) {  // signal: absmax will be ~ws_size
    sentinel_k<<<1, 64, 0, stream>>>(outp, (float)ws_size);
    return;
  }

  const int nL[4]   = {N0_, N1_, N2_, N3_};
  int* csrsL[4] = {csrs0, csrs1, csrs2, csrs3};
  float* csrwL[4] = {csrw0, csrw1, csrw2, csrw3};
  int* csroL[4] = {csro0, csro1, csro2, csro3};
  double* dinvL[4] = {dinv0, dinv1, dinv2, dinv3};
  double* dgiL[4]  = {dgi0, dgi1, dgi2, dgi3};
  int* idxL[3] = {idx0, idx1, idx2};

  auto cdiv = [](int a, int b) { return (a + b - 1) / b; };

  // deterministic 3-phase exclusive scan (n <= 262144)
  auto scan = [&](const int* in, int* out, int n) {
    int nb = cdiv(n, 1024);
    scan_part<<<nb, 256, 0, stream>>>(in, bscan, n);
    scan_bsum<<<1, 256, 0, stream>>>(bscan, nb);
    scan_out<<<nb, 256, 0, stream>>>(in, bscan, out, n, nb);
  };

  auto bn_f = [&](float* xp, int n, const float* g, const float* b, float* snap) {
    bn_stats<float><<<256, 256, 0, stream>>>(xp, n, bns);
    bn_final<<<1, 128, 0, stream>>>(bns, g, b, 1.0 / (double)n, ssb);
    bn_apply_relu<float><<<cdiv(n * 128, 256), 256, 0, stream>>>(xp, ssb, snap,
                                                                 (size_t)n * 128);
  };

  // pool level i: top-k on xcur; gather kept rows into xnext; build level i+1
  // CSR directly from level-i CSR (no edge list, no atomics).
  auto pool = [&](int i, const float* xcur, float* xnext) {
    int n = nL[i], k = nL[i + 1];
    wnorm_k<<<1, 128, 0, stream>>>(pool_w + i * 128, wn);
    score_key_k<<<cdiv(n, 2), 256, 0, stream>>>(xcur, pool_w + i * 128, wn, keys, n);
    sel_init<<<1, 64, 0, stream>>>(sel, k);
    hipMemsetAsync(hist, 0, 8 * 256 * 4, stream);
    for (int p = 0; p < 8; ++p) {
      int shift = 56 - 8 * p;
      rs_hist<<<cdiv(n, 256), 256, 0, stream>>>(keys, n, sel, shift, p, hist + p * 256);
      rs_pick<<<1, 256, 0, stream>>>(hist + p * 256, sel, shift);
    }
    eq_flags<<<cdiv(n, 256), 256, 0, stream>>>(keys, sel, eqf, n);
    scan(eqf, eqpre, n);
    kept_flags<<<cdiv(n, 256), 256, 0, stream>>>(keys, sel, eqpre, kept, n);
    scan(kept, npre, n);
    build_idx<<<cdiv(n, 256), 256, 0, stream>>>(kept, npre, knid, idxL[i], n);
    gather_rows<<<cdiv(k * 128, 256), 256, 0, stream>>>(xcur, idxL[i], xnext, k);
    // next-level CSR: deg -> dinv/dgi -> offsets -> fill
    next_deg<<<cdiv(n, 256), 256, 0, stream>>>(csroL[i], csrsL[i], knid, degcnt, n);
    fin_deg<<<cdiv(k, 256), 256, 0, stream>>>(degcnt, dinvL[i + 1], dgiL[i + 1], k);
    scan(degcnt, csroL[i + 1], k);
    next_fill<<<cdiv(n, 256), 256, 0, stream>>>(csroL[i], csrsL[i], knid,
        csroL[i + 1], dinvL[i + 1], csrsL[i + 1], csrwL[i + 1], n);
  };

  // ---- level 0 CSR (from raw edge list) ----
  hipMemsetAsync(degcnt, 0, (size_t)N0_ * 4, stream);
  count_deg<<<cdiv(EDG, 256), 256, 0, stream>>>(ei + EDG, EDG, degcnt);
  fin_deg<<<cdiv(N0_, 256), 256, 0, stream>>>(degcnt, dinv0, dgi0, N0_);
  scan(degcnt, csro0, N0_);
  hipMemsetAsync(cursor, 0, (size_t)N0_ * 4, stream);
  csr_fill<<<cdiv(EDG, 256), 256, 0, stream>>>(ei, ei + EDG, EDG, csro0, cursor,
                                               csrs0, csrw0, dinv0);

  // ---- initial conv (agg-first: agg(x W)+b = (agg x) W + b) ----
  agg_conv<false><<<cdiv(N0_, 4), 256, 0, stream>>>(
      x_in, csro0, csrs0, csrw0, dinv0, dgi0, nullptr, bufB, N0_);
  matmul128<float, float, double><<<cdiv(N0_, 64), 256, 0, stream>>>(bufB, in_W, in_b, bufA, N0_);

  // ---- down level 0: x in A, h in B, y back to A; snap -> xs0f; x1 -> B ----
  matmul128<float, float, double><<<cdiv(N0_, 64), 256, 0, stream>>>(bufA, dn_W, nullptr, bufB, N0_);
  agg_conv<false><<<cdiv(N0_, 4), 256, 0, stream>>>(
      bufB, csro0, csrs0, csrw0, dinv0, dgi0, dn_b, bufA, N0_);
  bn_f(bufA, N0_, dn_g, dn_bt, xs0f);
  pool(0, bufA, bufB);

  // ---- down level 1: x in B, h in A, y back to B; snap -> xs1f; x2 -> A ----
  matmul128<float, float, double><<<cdiv(N1_, 64), 256, 0, stream>>>(bufB, dn_W + 16384, nullptr, bufA, N1_);
  agg_conv<false><<<cdiv(N1_, 4), 256, 0, stream>>>(
      bufA, csro1, csrs1, csrw1, dinv1, dgi1, dn_b + 128, bufB, N1_);
  bn_f(bufB, N1_, dn_g + 128, dn_bt + 128, xs1f);
  pool(1, bufB, bufA);

  // ---- down level 2: x in A, h in B, y back to A; snap -> xs2f; x3 -> B ----
  matmul128<float, float, double><<<cdiv(N2_, 64), 256, 0, stream>>>(bufA, dn_W + 32768, nullptr, bufB, N2_);
  agg_conv<false><<<cdiv(N2_, 4), 256, 0, stream>>>(
      bufB, csro2, csrs2, csrw2, dinv2, dgi2, dn_b + 256, bufA, N2_);
  bn_f(bufA, N2_, dn_g + 256, dn_bt + 256, xs2f);
  pool(2, bufA, bufB);

  // ---- bottom: x3 in B, h3 -> A, z3 (relu) -> B ----
  matmul128<float, float, double><<<cdiv(N3_, 64), 256, 0, stream>>>(bufB, bot_W, nullptr, bufA, N3_);
  float* zf = bufB;
  float* hf = bufA;
  float* tf = outp;  // d_out as scratch until final write (fully overwritten)
  agg_conv<true><<<cdiv(N3_, 4), 256, 0, stream>>>(
      bufA, csro3, csrs3, csrw3, dinv3, dgi3, bot_b, zf, N3_);

  // ---- up path: z in B, hf in A ----
  for (int u = 0; u < 3; ++u) {
    int l = 2 - u;
    int nl = nL[l], nz = nL[l + 1];
    const float* Wt = up_W + u * 32768;          // rows [0:128)  -> unpooled part
    const float* Wb = up_W + u * 32768 + 16384;  // rows [128:256)-> skip part
    const float* xsf = (u == 0) ? xs2f : (u == 1) ? xs1f : xs0f;
    matmul128<float, float, float><<<cdiv(nz, 64), 256, 0, stream>>>(zf, Wt, nullptr, tf, nz);
    matmul128<float, float, float><<<cdiv(nl, 64), 256, 0, stream>>>(xsf, Wb, nullptr, hf, nl);
    scatter_add_rows<<<cdiv(nz * 128, 256), 256, 0, stream>>>(hf, tf, idxL[l], nz);
    agg_conv<false><<<cdiv(nl, 4), 256, 0, stream>>>(
        hf, csroL[l], csrsL[l], csrwL[l], dinvL[l], dgiL[l], up_b + u * 128, zf, nl);
    bn_f(zf, nl, up_g + u * 128, up_bt + u * 128, nullptr);
  }

  // ---- final conv -> d_out ----
  matmul128<float, float, float><<<cdiv(N0_, 64), 256, 0, stream>>>(zf, out_W, nullptr, hf, N0_);
  agg_conv<false><<<cdiv(N0_, 4), 256, 0, stream>>>(
      hf, csro0, csrs0, csrw0, dinv0, dgi0, out_b, outp, N0_);
}

// Round 5
// 2714.020 us; speedup vs baseline: 1.4810x; 1.0037x over previous
//
#include <hip/hip_runtime.h>

typedef unsigned long long ull;

#define N0_ 100000
#define N1_ 50000
#define N2_ 25000
#define N3_ 12500
#define EDG 1600000
#define CAP1 600000
#define CAP2 200000
#define CAP3 80000

struct Sel { ull prefix; int remaining; };

// ---------------- kernels ----------------

__global__ void sentinel_k(float* o, float v) { if (threadIdx.x == 0) o[0] = v; }

// C[n,128] = A[n,128] @ W[128,128] (+bias), ACC-typed accumulate. 64 rows/block.
// LDS staging is ALWAYS fp32 (source data is fp32); converted to ACC on read.
template <typename TA, typename TC, typename ACC>
__global__ __launch_bounds__(256) void matmul128(const TA* __restrict__ A,
    const float* __restrict__ W, const float* __restrict__ bias,
    TC* __restrict__ C, int n) {
  __shared__ float Al[64 * 33];
  __shared__ float Wl[32 * 128];
  int tid = threadIdx.x;
  int colb = tid & 31;        // cols colb, colb+32, colb+64, colb+96
  int rg = tid >> 5;          // 0..7 -> rows rg*8..rg*8+7
  int row0 = blockIdx.x * 64;
  ACC acc[8][4];
#pragma unroll
  for (int r = 0; r < 8; ++r)
#pragma unroll
    for (int j = 0; j < 4; ++j) acc[r][j] = (ACC)0;
  for (int kt = 0; kt < 128; kt += 32) {
    for (int i = tid; i < 64 * 32; i += 256) {
      int r = i >> 5, kk = i & 31;
      int row = row0 + r;
      Al[r * 33 + kk] = (row < n) ? (float)A[(size_t)row * 128 + kt + kk] : 0.0f;
    }
    for (int i = tid; i < 32 * 128; i += 256) {
      int kk = i >> 7, c = i & 127;
      Wl[i] = W[(size_t)(kt + kk) * 128 + c];
    }
    __syncthreads();
#pragma unroll 4
    for (int kk = 0; kk < 32; ++kk) {
      ACC b0 = (ACC)Wl[kk * 128 + colb];
      ACC b1 = (ACC)Wl[kk * 128 + colb + 32];
      ACC b2 = (ACC)Wl[kk * 128 + colb + 64];
      ACC b3 = (ACC)Wl[kk * 128 + colb + 96];
#pragma unroll
      for (int r = 0; r < 8; ++r) {
        ACC a = (ACC)Al[(rg * 8 + r) * 33 + kk];
        acc[r][0] += a * b0; acc[r][1] += a * b1;
        acc[r][2] += a * b2; acc[r][3] += a * b3;
      }
    }
    __syncthreads();
  }
  ACC bb0 = 0, bb1 = 0, bb2 = 0, bb3 = 0;
  if (bias) {
    bb0 = (ACC)bias[colb]; bb1 = (ACC)bias[colb + 32];
    bb2 = (ACC)bias[colb + 64]; bb3 = (ACC)bias[colb + 96];
  }
  for (int r = 0; r < 8; ++r) {
    int row = row0 + rg * 8 + r;
    if (row < n) {
      size_t o = (size_t)row * 128 + colb;
      C[o] = (TC)(acc[r][0] + bb0); C[o + 32] = (TC)(acc[r][1] + bb1);
      C[o + 64] = (TC)(acc[r][2] + bb2); C[o + 96] = (TC)(acc[r][3] + bb3);
    }
  }
}

// y[i,c] = di * sum_p h[src_p,c]*csrw[p] + h[i,c]*dgi[i] + b[c]
// float4 layout: 32 lanes per node, 8 nodes per 256-block. One dwordx4 per
// wave moves 1KB (2 rows). Double accumulate; even-edge->accA / odd->accB /
// tail->accA structure preserved exactly -> bit-identical to prior rounds.
template <bool RELU>
__global__ __launch_bounds__(256) void agg_conv(const float* __restrict__ hp,
    const int* __restrict__ off, const int* __restrict__ csrc,
    const float* __restrict__ csrw,
    const double* __restrict__ dinv, const double* __restrict__ dgi,
    const float* __restrict__ bias, float* __restrict__ yp, int n) {
  const float4* __restrict__ h = (const float4*)hp;
  float4* __restrict__ y = (float4*)yp;
  int c4 = threadIdx.x & 31;                       // column quad
  int node = blockIdx.x * 8 + (threadIdx.x >> 5);  // 32 lanes per node
  if (node >= n) return;
  double di = dinv[node];
  double dg = dgi[node];
  float4 hv = h[(size_t)node * 32 + c4];
  double sfx = (double)hv.x * dg, sfy = (double)hv.y * dg;
  double sfz = (double)hv.z * dg, sfw = (double)hv.w * dg;
  double aAx = 0, aAy = 0, aAz = 0, aAw = 0;
  double aBx = 0, aBy = 0, aBz = 0, aBw = 0;
  int p = off[node], p1 = off[node + 1];
  for (; p + 8 <= p1; p += 8) {
    int s0 = csrc[p + 0], s1 = csrc[p + 1], s2 = csrc[p + 2], s3 = csrc[p + 3];
    int s4 = csrc[p + 4], s5 = csrc[p + 5], s6 = csrc[p + 6], s7 = csrc[p + 7];
    double w0 = (double)csrw[p + 0], w1 = (double)csrw[p + 1];
    double w2 = (double)csrw[p + 2], w3 = (double)csrw[p + 3];
    double w4 = (double)csrw[p + 4], w5 = (double)csrw[p + 5];
    double w6 = (double)csrw[p + 6], w7 = (double)csrw[p + 7];
    float4 v0 = h[(size_t)s0 * 32 + c4];
    float4 v1 = h[(size_t)s1 * 32 + c4];
    float4 v2 = h[(size_t)s2 * 32 + c4];
    float4 v3 = h[(size_t)s3 * 32 + c4];
    float4 v4 = h[(size_t)s4 * 32 + c4];
    float4 v5 = h[(size_t)s5 * 32 + c4];
    float4 v6 = h[(size_t)s6 * 32 + c4];
    float4 v7 = h[(size_t)s7 * 32 + c4];
    aAx += (double)v0.x * w0; aAy += (double)v0.y * w0;
    aAz += (double)v0.z * w0; aAw += (double)v0.w * w0;
    aBx += (double)v1.x * w1; aBy += (double)v1.y * w1;
    aBz += (double)v1.z * w1; aBw += (double)v1.w * w1;
    aAx += (double)v2.x * w2; aAy += (double)v2.y * w2;
    aAz += (double)v2.z * w2; aAw += (double)v2.w * w2;
    aBx += (double)v3.x * w3; aBy += (double)v3.y * w3;
    aBz += (double)v3.z * w3; aBw += (double)v3.w * w3;
    aAx += (double)v4.x * w4; aAy += (double)v4.y * w4;
    aAz += (double)v4.z * w4; aAw += (double)v4.w * w4;
    aBx += (double)v5.x * w5; aBy += (double)v5.y * w5;
    aBz += (double)v5.z * w5; aBw += (double)v5.w * w5;
    aAx += (double)v6.x * w6; aAy += (double)v6.y * w6;
    aAz += (double)v6.z * w6; aAw += (double)v6.w * w6;
    aBx += (double)v7.x * w7; aBy += (double)v7.y * w7;
    aBz += (double)v7.z * w7; aBw += (double)v7.w * w7;
  }
  for (; p + 4 <= p1; p += 4) {
    int s0 = csrc[p + 0], s1 = csrc[p + 1], s2 = csrc[p + 2], s3 = csrc[p + 3];
    double w0 = (double)csrw[p + 0], w1 = (double)csrw[p + 1];
    double w2 = (double)csrw[p + 2], w3 = (double)csrw[p + 3];
    float4 v0 = h[(size_t)s0 * 32 + c4];
    float4 v1 = h[(size_t)s1 * 32 + c4];
    float4 v2 = h[(size_t)s2 * 32 + c4];
    float4 v3 = h[(size_t)s3 * 32 + c4];
    aAx += (double)v0.x * w0; aAy += (double)v0.y * w0;
    aAz += (double)v0.z * w0; aAw += (double)v0.w * w0;
    aBx += (double)v1.x * w1; aBy += (double)v1.y * w1;
    aBz += (double)v1.z * w1; aBw += (double)v1.w * w1;
    aAx += (double)v2.x * w2; aAy += (double)v2.y * w2;
    aAz += (double)v2.z * w2; aAw += (double)v2.w * w2;
    aBx += (double)v3.x * w3; aBy += (double)v3.y * w3;
    aBz += (double)v3.z * w3; aBw += (double)v3.w * w3;
  }
  for (; p < p1; ++p) {
    double w = (double)csrw[p];
    float4 v = h[(size_t)csrc[p] * 32 + c4];
    aAx += (double)v.x * w; aAy += (double)v.y * w;
    aAz += (double)v.z * w; aAw += (double)v.w * w;
  }
  double bx = 0, by = 0, bz = 0, bw = 0;
  if (bias) {
    bx = (double)bias[c4 * 4 + 0]; by = (double)bias[c4 * 4 + 1];
    bz = (double)bias[c4 * 4 + 2]; bw = (double)bias[c4 * 4 + 3];
  }
  double rx = (aAx + aBx) * di + sfx + bx;
  double ry = (aAy + aBy) * di + sfy + by;
  double rz = (aAz + aBz) * di + sfz + bz;
  double rw = (aAw + aBw) * di + sfw + bw;
  if (RELU) {
    rx = rx > 0.0 ? rx : 0.0; ry = ry > 0.0 ? ry : 0.0;
    rz = rz > 0.0 ? rz : 0.0; rw = rw > 0.0 ? rw : 0.0;
  }
  y[(size_t)node * 32 + c4] = make_float4((float)rx, (float)ry, (float)rz, (float)rw);
}

// level-0 CSR build only
__global__ void count_deg(const int* __restrict__ dst, int m, int* __restrict__ cnt) {
  int e = blockIdx.x * 256 + threadIdx.x;
  if (e < m) atomicAdd(&cnt[dst[e]], 1);
}

__global__ void fin_deg(const int* __restrict__ cnt, double* __restrict__ dinv,
                        double* __restrict__ dgi, int n) {
  int i = blockIdx.x * 256 + threadIdx.x;
  if (i < n) {
    double d = 1.0 + (double)cnt[i];
    dinv[i] = 1.0 / sqrt(d);
    dgi[i] = 1.0 / d;
  }
}

// ---- deterministic 3-phase multi-block exclusive scan ----
__global__ __launch_bounds__(256) void scan_part(const int* __restrict__ in,
                                                 int* __restrict__ bsum, int n) {
  __shared__ int ts[256];
  int base = blockIdx.x * 1024 + threadIdx.x * 4;
  int s = 0;
#pragma unroll
  for (int j = 0; j < 4; ++j) { int i = base + j; if (i < n) s += in[i]; }
  ts[threadIdx.x] = s;
  __syncthreads();
  for (int d = 128; d > 0; d >>= 1) {
    if (threadIdx.x < d) ts[threadIdx.x] += ts[threadIdx.x + d];
    __syncthreads();
  }
  if (threadIdx.x == 0) bsum[blockIdx.x] = ts[0];
}

__global__ __launch_bounds__(256) void scan_bsum(int* __restrict__ bsum, int nb) {
  __shared__ int ls[256];
  int t = threadIdx.x;
  int v = (t < nb) ? bsum[t] : 0;
  ls[t] = v;
  __syncthreads();
  for (int d = 1; d < 256; d <<= 1) {
    int u = (t >= d) ? ls[t - d] : 0;
    __syncthreads();
    ls[t] += u;
    __syncthreads();
  }
  if (t < nb) bsum[t] = ls[t] - v;  // exclusive prefix
}

__global__ __launch_bounds__(256) void scan_out(const int* __restrict__ in,
    const int* __restrict__ bsum, int* __restrict__ out, int n, int nb) {
  __shared__ int ts[256];
  int base = blockIdx.x * 1024 + threadIdx.x * 4;
  int loc[4];
  int s = 0;
#pragma unroll
  for (int j = 0; j < 4; ++j) {
    int i = base + j;
    int v = (i < n) ? in[i] : 0;
    loc[j] = s; s += v;
  }
  ts[threadIdx.x] = s;
  __syncthreads();
  int mine = s;
  for (int d = 1; d < 256; d <<= 1) {
    int u = (threadIdx.x >= d) ? ts[threadIdx.x - d] : 0;
    __syncthreads();
    ts[threadIdx.x] += u;
    __syncthreads();
  }
  int toff = bsum[blockIdx.x] + ts[threadIdx.x] - mine;
#pragma unroll
  for (int j = 0; j < 4; ++j) {
    int i = base + j;
    if (i < n) out[i] = toff + loc[j];
  }
  if (blockIdx.x == nb - 1 && threadIdx.x == 255) out[n] = bsum[blockIdx.x] + ts[255];
}

__global__ void csr_fill(const int* __restrict__ src, const int* __restrict__ dst,
                         int m, const int* __restrict__ off,
                         int* __restrict__ cursor, int* __restrict__ csrs,
                         float* __restrict__ csrw, const double* __restrict__ dinv) {
  int e = blockIdx.x * 256 + threadIdx.x;
  if (e < m) {
    int d = dst[e];
    int s = src[e];
    int pos = off[d] + atomicAdd(&cursor[d], 1);
    csrs[pos] = s;
    csrw[pos] = (float)dinv[s];
  }
}

// ---- CSR-direct next-level build (no edge list, no atomics) ----
__global__ void next_deg(const int* __restrict__ off, const int* __restrict__ csrs,
                         const int* __restrict__ knid, int* __restrict__ ndeg, int n) {
  int d = blockIdx.x * 256 + threadIdx.x;
  if (d >= n) return;
  int nd = knid[d];
  if (nd < 0) return;
  int cnt = 0;
  int p1 = off[d + 1];
  for (int p = off[d]; p < p1; ++p) cnt += (knid[csrs[p]] >= 0) ? 1 : 0;
  ndeg[nd] = cnt;
}

__global__ void next_fill(const int* __restrict__ off, const int* __restrict__ csrs,
                          const int* __restrict__ knid, const int* __restrict__ noff,
                          const double* __restrict__ ndinv,
                          int* __restrict__ ncsrs, float* __restrict__ ncsrw, int n) {
  int d = blockIdx.x * 256 + threadIdx.x;
  if (d >= n) return;
  int nd = knid[d];
  if (nd < 0) return;
  int pos = noff[nd];
  int p1 = off[d + 1];
  for (int p = off[d]; p < p1; ++p) {
    int s = knid[csrs[p]];
    if (s >= 0) { ncsrs[pos] = s; ncsrw[pos] = (float)ndinv[s]; ++pos; }
  }
}

// fixed grid of 256 blocks; deterministic per-block partials (no atomics).
template <typename T>
__global__ __launch_bounds__(256) void bn_stats(const T* __restrict__ x, int n,
                                                double* __restrict__ part) {
  __shared__ double lsum[256], lsq[256];
  int c = threadIdx.x & 127, half = threadIdx.x >> 7;
  double s = 0, q = 0;
  for (int row = blockIdx.x * 2 + half; row < n; row += 512) {
    double v = (double)x[(size_t)row * 128 + c];
    s += v; q += v * v;
  }
  lsum[threadIdx.x] = s; lsq[threadIdx.x] = q;
  __syncthreads();
  if (half == 0) {
    part[blockIdx.x * 256 + c] = lsum[c] + lsum[c + 128];
    part[blockIdx.x * 256 + 128 + c] = lsq[c] + lsq[c + 128];
  }
}

__global__ void bn_final(const double* __restrict__ part, const float* __restrict__ g,
                         const float* __restrict__ beta, double invn,
                         double* __restrict__ ss) {
  int c = threadIdx.x;  // 128
  double s = 0, q = 0;
  for (int b = 0; b < 256; ++b) {
    s += part[b * 256 + c];
    q += part[b * 256 + 128 + c];
  }
  double m = s * invn;
  double v = q * invn - m * m;
  double sc = (double)g[c] / sqrt(v + 1e-5);
  ss[c] = sc;
  ss[128 + c] = (double)beta[c] - m * sc;
}

// apply BN+ReLU in place, float4; optionally write fp32 snapshot.
__global__ void bn_apply_relu4(float4* __restrict__ x, const double* __restrict__ ss,
                               float4* __restrict__ snap, size_t total4) {
  size_t i = (size_t)blockIdx.x * 256 + threadIdx.x;
  if (i < total4) {
    int c0 = (int)((i & 31) * 4);
    float4 v = x[i];
    double r0 = (double)v.x * ss[c0 + 0] + ss[128 + c0 + 0];
    double r1 = (double)v.y * ss[c0 + 1] + ss[128 + c0 + 1];
    double r2 = (double)v.z * ss[c0 + 2] + ss[128 + c0 + 2];
    double r3 = (double)v.w * ss[c0 + 3] + ss[128 + c0 + 3];
    r0 = r0 > 0.0 ? r0 : 0.0; r1 = r1 > 0.0 ? r1 : 0.0;
    r2 = r2 > 0.0 ? r2 : 0.0; r3 = r3 > 0.0 ? r3 : 0.0;
    float4 o = make_float4((float)r0, (float)r1, (float)r2, (float)r3);
    x[i] = o;
    if (snap) snap[i] = o;
  }
}

__global__ void wnorm_k(const float* __restrict__ w, double* __restrict__ wn) {
  __shared__ double red[128];
  int c = threadIdx.x;
  double v = (double)w[c];
  red[c] = v * v;
  __syncthreads();
  for (int s = 64; s > 0; s >>= 1) { if (c < s) red[c] += red[c + s]; __syncthreads(); }
  if (c == 0) wn[0] = sqrt(red[0]);
}

__global__ __launch_bounds__(256) void score_key_k(const float* __restrict__ x,
    const float* __restrict__ w, const double* __restrict__ wn,
    ull* __restrict__ keys, int n) {
  __shared__ double red[256];
  int c = threadIdx.x & 127;
  int node = blockIdx.x * 2 + (threadIdx.x >> 7);
  double p = 0.0;
  if (node < n) p = (double)x[(size_t)node * 128 + c] * (double)w[c];
  red[threadIdx.x] = p;
  __syncthreads();
  for (int s = 64; s > 0; s >>= 1) {
    if (c < s) red[threadIdx.x] += red[threadIdx.x + s];
    __syncthreads();
  }
  if (c == 0 && node < n) {
    double sc = tanh(red[threadIdx.x] / wn[0]);
    ull u = (ull)__double_as_longlong(sc);
    u = (u >> 63) ? ~u : (u | 0x8000000000000000ULL);
    keys[node] = u;
  }
}

__global__ void sel_init(Sel* sel, int k) {
  if (threadIdx.x == 0) { sel->prefix = 0ULL; sel->remaining = k; }
}

__global__ void rs_hist(const ull* __restrict__ keys, int n, const Sel* __restrict__ sel,
                        int shift, int pass, int* __restrict__ hist) {
  __shared__ int lh[256];
  lh[threadIdx.x] = 0;
  __syncthreads();
  int i = blockIdx.x * 256 + threadIdx.x;
  if (i < n) {
    ull k = keys[i];
    bool ok = (pass == 0) || (((k ^ sel->prefix) >> (shift + 8)) == 0);
    if (ok) atomicAdd(&lh[(int)((k >> shift) & 255)], 1);
  }
  __syncthreads();
  if (lh[threadIdx.x]) atomicAdd(&hist[threadIdx.x], lh[threadIdx.x]);
}

__global__ void rs_pick(const int* __restrict__ hist, Sel* sel, int shift) {
  __shared__ int lh[256];
  lh[threadIdx.x] = hist[threadIdx.x];
  __syncthreads();
  if (threadIdx.x == 0) {
    int rem = sel->remaining;
    for (int b = 255; b >= 0; --b) {
      int c = lh[b];
      if (c >= rem) { sel->prefix |= ((ull)b) << shift; break; }
      rem -= c;
    }
    sel->remaining = rem;
  }
}

__global__ void eq_flags(const ull* __restrict__ keys, const Sel* __restrict__ sel,
                         int* __restrict__ eqf, int n) {
  int i = blockIdx.x * 256 + threadIdx.x;
  if (i < n) eqf[i] = (keys[i] == sel->prefix) ? 1 : 0;
}

__global__ void kept_flags(const ull* __restrict__ keys, const Sel* __restrict__ sel,
                           const int* __restrict__ eqpre, int* __restrict__ kept, int n) {
  int i = blockIdx.x * 256 + threadIdx.x;
  if (i < n) {
    ull u = keys[i], p = sel->prefix;
    kept[i] = (u > p || (u == p && eqpre[i] < sel->remaining)) ? 1 : 0;
  }
}

// knid = new id if kept else -1; idx[newid] = old id.
__global__ void build_idx(const int* __restrict__ kept, const int* __restrict__ npre,
                          int* __restrict__ knid, int* __restrict__ idx, int n) {
  int i = blockIdx.x * 256 + threadIdx.x;
  if (i < n) {
    if (kept[i]) {
      int nid = npre[i];
      knid[i] = nid;
      idx[nid] = i;
    } else {
      knid[i] = -1;
    }
  }
}

__global__ void gather_rows4(const float4* __restrict__ xs, const int* __restrict__ idx,
                             float4* __restrict__ xo, int k) {
  int i = blockIdx.x * 256 + threadIdx.x;
  if (i < k * 32) xo[i] = xs[(size_t)idx[i >> 5] * 32 + (i & 31)];
}

__global__ void scatter_add_rows4(float4* __restrict__ h, const float4* __restrict__ t,
                                  const int* __restrict__ idx, int k) {
  int i = blockIdx.x * 256 + threadIdx.x;
  if (i < k * 32) {
    float4 a = h[(size_t)idx[i >> 5] * 32 + (i & 31)];
    float4 b = t[i];
    a.x += b.x; a.y += b.y; a.z += b.z; a.w += b.w;
    h[(size_t)idx[i >> 5] * 32 + (i & 31)] = a;
  }
}

// ---------------- host ----------------

extern "C" void kernel_launch(void* const* d_in, const int* in_sizes, int n_in,
                              void* d_out, int out_size, void* d_ws, size_t ws_size,
                              hipStream_t stream) {
  (void)in_sizes; (void)out_size;
  if (n_in < 17) return;
  const float* x_in   = (const float*)d_in[0];
  const int*   ei     = (const int*)  d_in[1];
  const float* in_W   = (const float*)d_in[2];
  const float* in_b   = (const float*)d_in[3];
  const float* dn_W   = (const float*)d_in[4];
  const float* dn_b   = (const float*)d_in[5];
  const float* dn_g   = (const float*)d_in[6];
  const float* dn_bt  = (const float*)d_in[7];
  const float* pool_w = (const float*)d_in[8];
  const float* bot_W  = (const float*)d_in[9];
  const float* bot_b  = (const float*)d_in[10];
  const float* up_W   = (const float*)d_in[11];
  const float* up_b   = (const float*)d_in[12];
  const float* up_g   = (const float*)d_in[13];
  const float* up_bt  = (const float*)d_in[14];
  const float* out_W  = (const float*)d_in[15];
  const float* out_b  = (const float*)d_in[16];
  float* outp = (float*)d_out;

  char* base = (char*)d_ws;
  size_t off = 0;
  auto alloc = [&](size_t b) -> void* {
    void* r = base + off;
    off = (off + b + 255) & ~(size_t)255;
    return r;
  };
  // fp32 storage everywhere; double accumulation inside kernels.
  float* bufA = (float*)alloc((size_t)N0_ * 128 * 4);   // 51.2 MB
  float* bufB = (float*)alloc((size_t)N0_ * 128 * 4);   // 51.2 MB
  float* xs0f = (float*)alloc((size_t)N0_ * 128 * 4);   // 51.2 MB
  float* xs1f = (float*)alloc((size_t)N1_ * 128 * 4);   // 25.6 MB
  float* xs2f = (float*)alloc((size_t)N2_ * 128 * 4);   // 12.8 MB

  int* csrs0 = (int*)alloc((size_t)EDG * 4);
  int* csrs1 = (int*)alloc((size_t)CAP1 * 4);
  int* csrs2 = (int*)alloc((size_t)CAP2 * 4);
  int* csrs3 = (int*)alloc((size_t)CAP3 * 4);
  float* csrw0 = (float*)alloc((size_t)EDG * 4);
  float* csrw1 = (float*)alloc((size_t)CAP1 * 4);
  float* csrw2 = (float*)alloc((size_t)CAP2 * 4);
  float* csrw3 = (float*)alloc((size_t)CAP3 * 4);
  int* csro0 = (int*)alloc((size_t)(N0_ + 1) * 4);
  int* csro1 = (int*)alloc((size_t)(N1_ + 1) * 4);
  int* csro2 = (int*)alloc((size_t)(N2_ + 1) * 4);
  int* csro3 = (int*)alloc((size_t)(N3_ + 1) * 4);
  double* dinv0 = (double*)alloc((size_t)N0_ * 8); double* dgi0 = (double*)alloc((size_t)N0_ * 8);
  double* dinv1 = (double*)alloc((size_t)N1_ * 8); double* dgi1 = (double*)alloc((size_t)N1_ * 8);
  double* dinv2 = (double*)alloc((size_t)N2_ * 8); double* dgi2 = (double*)alloc((size_t)N2_ * 8);
  double* dinv3 = (double*)alloc((size_t)N3_ * 8); double* dgi3 = (double*)alloc((size_t)N3_ * 8);
  ull* keys = (ull*)alloc((size_t)N0_ * 8);
  int* eqf   = (int*)alloc((size_t)N0_ * 4);
  int* eqpre = (int*)alloc((size_t)(N0_ + 1) * 4);
  int* kept  = (int*)alloc((size_t)N0_ * 4);
  int* npre  = (int*)alloc((size_t)(N0_ + 1) * 4);
  int* knid  = (int*)alloc((size_t)N0_ * 4);
  int* degcnt = (int*)alloc((size_t)N0_ * 4);
  int* cursor = (int*)alloc((size_t)N0_ * 4);
  int* idx0 = (int*)alloc((size_t)N1_ * 4);
  int* idx1 = (int*)alloc((size_t)N2_ * 4);
  int* idx2 = (int*)alloc((size_t)N3_ * 4);
  int* hist = (int*)alloc(8 * 256 * 4);
  Sel* sel  = (Sel*)alloc(256);
  int* bscan = (int*)alloc(256 * 4);               // block sums for 3-phase scan
  double* bns = (double*)alloc((size_t)256 * 256 * 8);  // per-block BN partials
  double* ssb = (double*)alloc(256 * 8);
  double* wn  = (double*)alloc(256);
  if (off > ws_size) {  // signal: absmax will be ~ws_size
    sentinel_k<<<1, 64, 0, stream>>>(outp, (float)ws_size);
    return;
  }

  const int nL[4]   = {N0_, N1_, N2_, N3_};
  int* csrsL[4] = {csrs0, csrs1, csrs2, csrs3};
  float* csrwL[4] = {csrw0, csrw1, csrw2, csrw3};
  int* csroL[4] = {csro0, csro1, csro2, csro3};
  double* dinvL[4] = {dinv0, dinv1, dinv2, dinv3};
  double* dgiL[4]  = {dgi0, dgi1, dgi2, dgi3};
  int* idxL[3] = {idx0, idx1, idx2};

  auto cdiv = [](int a, int b) { return (a + b - 1) / b; };

  // deterministic 3-phase exclusive scan (n <= 262144)
  auto scan = [&](const int* in, int* out, int n) {
    int nb = cdiv(n, 1024);
    scan_part<<<nb, 256, 0, stream>>>(in, bscan, n);
    scan_bsum<<<1, 256, 0, stream>>>(bscan, nb);
    scan_out<<<nb, 256, 0, stream>>>(in, bscan, out, n, nb);
  };

  auto bn_f = [&](float* xp, int n, const float* g, const float* b, float* snap) {
    bn_stats<float><<<256, 256, 0, stream>>>(xp, n, bns);
    bn_final<<<1, 128, 0, stream>>>(bns, g, b, 1.0 / (double)n, ssb);
    bn_apply_relu4<<<cdiv(n * 32, 256), 256, 0, stream>>>(
        (float4*)xp, ssb, (float4*)snap, (size_t)n * 32);
  };

  // pool level i: top-k on xcur; gather kept rows into xnext; build level i+1
  // CSR directly from level-i CSR (no edge list, no atomics).
  auto pool = [&](int i, const float* xcur, float* xnext) {
    int n = nL[i], k = nL[i + 1];
    wnorm_k<<<1, 128, 0, stream>>>(pool_w + i * 128, wn);
    score_key_k<<<cdiv(n, 2), 256, 0, stream>>>(xcur, pool_w + i * 128, wn, keys, n);
    sel_init<<<1, 64, 0, stream>>>(sel, k);
    hipMemsetAsync(hist, 0, 8 * 256 * 4, stream);
    for (int p = 0; p < 8; ++p) {
      int shift = 56 - 8 * p;
      rs_hist<<<cdiv(n, 256), 256, 0, stream>>>(keys, n, sel, shift, p, hist + p * 256);
      rs_pick<<<1, 256, 0, stream>>>(hist + p * 256, sel, shift);
    }
    eq_flags<<<cdiv(n, 256), 256, 0, stream>>>(keys, sel, eqf, n);
    scan(eqf, eqpre, n);
    kept_flags<<<cdiv(n, 256), 256, 0, stream>>>(keys, sel, eqpre, kept, n);
    scan(kept, npre, n);
    build_idx<<<cdiv(n, 256), 256, 0, stream>>>(kept, npre, knid, idxL[i], n);
    gather_rows4<<<cdiv(k * 32, 256), 256, 0, stream>>>(
        (const float4*)xcur, idxL[i], (float4*)xnext, k);
    // next-level CSR: deg -> dinv/dgi -> offsets -> fill
    next_deg<<<cdiv(n, 256), 256, 0, stream>>>(csroL[i], csrsL[i], knid, degcnt, n);
    fin_deg<<<cdiv(k, 256), 256, 0, stream>>>(degcnt, dinvL[i + 1], dgiL[i + 1], k);
    scan(degcnt, csroL[i + 1], k);
    next_fill<<<cdiv(n, 256), 256, 0, stream>>>(csroL[i], csrsL[i], knid,
        csroL[i + 1], dinvL[i + 1], csrsL[i + 1], csrwL[i + 1], n);
  };

  // ---- level 0 CSR (from raw edge list) ----
  hipMemsetAsync(degcnt, 0, (size_t)N0_ * 4, stream);
  count_deg<<<cdiv(EDG, 256), 256, 0, stream>>>(ei + EDG, EDG, degcnt);
  fin_deg<<<cdiv(N0_, 256), 256, 0, stream>>>(degcnt, dinv0, dgi0, N0_);
  scan(degcnt, csro0, N0_);
  hipMemsetAsync(cursor, 0, (size_t)N0_ * 4, stream);
  csr_fill<<<cdiv(EDG, 256), 256, 0, stream>>>(ei, ei + EDG, EDG, csro0, cursor,
                                               csrs0, csrw0, dinv0);

  // ---- initial conv (agg-first: agg(x W)+b = (agg x) W + b) ----
  agg_conv<false><<<cdiv(N0_, 8), 256, 0, stream>>>(
      x_in, csro0, csrs0, csrw0, dinv0, dgi0, nullptr, bufB, N0_);
  matmul128<float, float, double><<<cdiv(N0_, 64), 256, 0, stream>>>(bufB, in_W, in_b, bufA, N0_);

  // ---- down level 0: x in A, h in B, y back to A; snap -> xs0f; x1 -> B ----
  matmul128<float, float, double><<<cdiv(N0_, 64), 256, 0, stream>>>(bufA, dn_W, nullptr, bufB, N0_);
  agg_conv<false><<<cdiv(N0_, 8), 256, 0, stream>>>(
      bufB, csro0, csrs0, csrw0, dinv0, dgi0, dn_b, bufA, N0_);
  bn_f(bufA, N0_, dn_g, dn_bt, xs0f);
  pool(0, bufA, bufB);

  // ---- down level 1: x in B, h in A, y back to B; snap -> xs1f; x2 -> A ----
  matmul128<float, float, double><<<cdiv(N1_, 64), 256, 0, stream>>>(bufB, dn_W + 16384, nullptr, bufA, N1_);
  agg_conv<false><<<cdiv(N1_, 8), 256, 0, stream>>>(
      bufA, csro1, csrs1, csrw1, dinv1, dgi1, dn_b + 128, bufB, N1_);
  bn_f(bufB, N1_, dn_g + 128, dn_bt + 128, xs1f);
  pool(1, bufB, bufA);

  // ---- down level 2: x in A, h in B, y back to A; snap -> xs2f; x3 -> B ----
  matmul128<float, float, double><<<cdiv(N2_, 64), 256, 0, stream>>>(bufA, dn_W + 32768, nullptr, bufB, N2_);
  agg_conv<false><<<cdiv(N2_, 8), 256, 0, stream>>>(
      bufB, csro2, csrs2, csrw2, dinv2, dgi2, dn_b + 256, bufA, N2_);
  bn_f(bufA, N2_, dn_g + 256, dn_bt + 256, xs2f);
  pool(2, bufA, bufB);

  // ---- bottom: x3 in B, h3 -> A, z3 (relu) -> B ----
  matmul128<float, float, double><<<cdiv(N3_, 64), 256, 0, stream>>>(bufB, bot_W, nullptr, bufA, N3_);
  float* zf = bufB;
  float* hf = bufA;
  float* tf = outp;  // d_out as scratch until final write (fully overwritten)
  agg_conv<true><<<cdiv(N3_, 8), 256, 0, stream>>>(
      bufA, csro3, csrs3, csrw3, dinv3, dgi3, bot_b, zf, N3_);

  // ---- up path: z in B, hf in A ----
  for (int u = 0; u < 3; ++u) {
    int l = 2 - u;
    int nl = nL[l], nz = nL[l + 1];
    const float* Wt = up_W + u * 32768;          // rows [0:128)  -> unpooled part
    const float* Wb = up_W + u * 32768 + 16384;  // rows [128:256)-> skip part
    const float* xsf = (u == 0) ? xs2f : (u == 1) ? xs1f : xs0f;
    matmul128<float, float, float><<<cdiv(nz, 64), 256, 0, stream>>>(zf, Wt, nullptr, tf, nz);
    matmul128<float, float, float><<<cdiv(nl, 64), 256, 0, stream>>>(xsf, Wb, nullptr, hf, nl);
    scatter_add_rows4<<<cdiv(nz * 32, 256), 256, 0, stream>>>(
        (float4*)hf, (const float4*)tf, idxL[l], nz);
    agg_conv<false><<<cdiv(nl, 8), 256, 0, stream>>>(
        hf, csroL[l], csrsL[l], csrwL[l], dinvL[l], dgiL[l], up_b + u * 128, zf, nl);
    bn_f(zf, nl, up_g + u * 128, up_bt + u * 128, nullptr);
  }

  // ---- final conv -> d_out ----
  matmul128<float, float, float><<<cdiv(N0_, 64), 256, 0, stream>>>(zf, out_W, nullptr, hf, N0_);
  agg_conv<false><<<cdiv(N0_, 8), 256, 0, stream>>>(
      hf, csro0, csrs0, csrw0, dinv0, dgi0, out_b, outp, N0_);
}

// Round 7
// 2678.243 us; speedup vs baseline: 1.5008x; 1.0134x over previous
//
#include <hip/hip_runtime.h>

typedef unsigned long long ull;

#define N0_ 100000
#define N1_ 50000
#define N2_ 25000
#define N3_ 12500
#define EDG 1600000
#define CAP1 600000
#define CAP2 200000
#define CAP3 80000

struct Sel { ull prefix; int remaining; };

// ---------------- kernels ----------------

__global__ void sentinel_k(float* o, float v) { if (threadIdx.x == 0) o[0] = v; }

// C[n,128] = A[n,128] @ W[128,128] (+bias), ACC-typed accumulate. 64 rows/block.
// LDS staging is ALWAYS fp32 (source data is fp32); converted to ACC on read.
template <typename TA, typename TC, typename ACC>
__global__ __launch_bounds__(256) void matmul128(const TA* __restrict__ A,
    const float* __restrict__ W, const float* __restrict__ bias,
    TC* __restrict__ C, int n) {
  __shared__ float Al[64 * 33];
  __shared__ float Wl[32 * 128];
  int tid = threadIdx.x;
  int colb = tid & 31;        // cols colb, colb+32, colb+64, colb+96
  int rg = tid >> 5;          // 0..7 -> rows rg*8..rg*8+7
  int row0 = blockIdx.x * 64;
  ACC acc[8][4];
#pragma unroll
  for (int r = 0; r < 8; ++r)
#pragma unroll
    for (int j = 0; j < 4; ++j) acc[r][j] = (ACC)0;
  for (int kt = 0; kt < 128; kt += 32) {
    for (int i = tid; i < 64 * 32; i += 256) {
      int r = i >> 5, kk = i & 31;
      int row = row0 + r;
      Al[r * 33 + kk] = (row < n) ? (float)A[(size_t)row * 128 + kt + kk] : 0.0f;
    }
    for (int i = tid; i < 32 * 128; i += 256) {
      int kk = i >> 7, c = i & 127;
      Wl[i] = W[(size_t)(kt + kk) * 128 + c];
    }
    __syncthreads();
#pragma unroll 4
    for (int kk = 0; kk < 32; ++kk) {
      ACC b0 = (ACC)Wl[kk * 128 + colb];
      ACC b1 = (ACC)Wl[kk * 128 + colb + 32];
      ACC b2 = (ACC)Wl[kk * 128 + colb + 64];
      ACC b3 = (ACC)Wl[kk * 128 + colb + 96];
#pragma unroll
      for (int r = 0; r < 8; ++r) {
        ACC a = (ACC)Al[(rg * 8 + r) * 33 + kk];
        acc[r][0] += a * b0; acc[r][1] += a * b1;
        acc[r][2] += a * b2; acc[r][3] += a * b3;
      }
    }
    __syncthreads();
  }
  ACC bb0 = 0, bb1 = 0, bb2 = 0, bb3 = 0;
  if (bias) {
    bb0 = (ACC)bias[colb]; bb1 = (ACC)bias[colb + 32];
    bb2 = (ACC)bias[colb + 64]; bb3 = (ACC)bias[colb + 96];
  }
  for (int r = 0; r < 8; ++r) {
    int row = row0 + rg * 8 + r;
    if (row < n) {
      size_t o = (size_t)row * 128 + colb;
      C[o] = (TC)(acc[r][0] + bb0); C[o + 32] = (TC)(acc[r][1] + bb1);
      C[o + 64] = (TC)(acc[r][2] + bb2); C[o + 96] = (TC)(acc[r][3] + bb3);
    }
  }
}

// y[i,c] = di * sum_p h[src_p,c]*csrw[p] + h[i,c]*dgi[i] + b[c]
// Full-wave float4: 1 wave per node (4 nodes per 256-block). Lanes 0-31
// (half=0) take even-relative edges, lanes 32-63 odd ones -> uniform loop
// bounds, zero divergence, 2 edges per wave memory instruction (1KB).
// Halves combine via shfl_xor(32). Double accumulation.
template <bool RELU>
__global__ __launch_bounds__(256) void agg_conv(const float* __restrict__ hp,
    const int* __restrict__ off, const int* __restrict__ csrc,
    const float* __restrict__ csrw,
    const double* __restrict__ dinv, const double* __restrict__ dgi,
    const float* __restrict__ bias, float* __restrict__ yp, int n) {
  const float4* __restrict__ h = (const float4*)hp;
  float4* __restrict__ y = (float4*)yp;
  int lane = threadIdx.x & 63;
  int c4 = lane & 31;                              // column quad
  int half = lane >> 5;                            // 0: even edges, 1: odd
  int node = blockIdx.x * 4 + (threadIdx.x >> 6);  // 1 wave per node
  if (node >= n) return;
  double di = dinv[node];
  double dg = dgi[node];
  double aX = 0, aY = 0, aZ = 0, aW = 0;  // this half's partial
  int p0 = off[node], p1 = off[node + 1];
  int m = p1 - p0;
  int npair = m >> 1;  // full (even,odd) pairs
  int j = 0;
  // unroll: 4 pairs = 8 edges per iteration, 4 float4 gathers in flight/lane
  for (; j + 4 <= npair; j += 4) {
    int e0 = p0 + 2 * j + half;
    int s0 = csrc[e0], s1 = csrc[e0 + 2], s2 = csrc[e0 + 4], s3 = csrc[e0 + 6];
    double w0 = (double)csrw[e0],     w1 = (double)csrw[e0 + 2];
    double w2 = (double)csrw[e0 + 4], w3 = (double)csrw[e0 + 6];
    float4 v0 = h[(size_t)s0 * 32 + c4];
    float4 v1 = h[(size_t)s1 * 32 + c4];
    float4 v2 = h[(size_t)s2 * 32 + c4];
    float4 v3 = h[(size_t)s3 * 32 + c4];
    aX += (double)v0.x * w0; aY += (double)v0.y * w0;
    aZ += (double)v0.z * w0; aW += (double)v0.w * w0;
    aX += (double)v1.x * w1; aY += (double)v1.y * w1;
    aZ += (double)v1.z * w1; aW += (double)v1.w * w1;
    aX += (double)v2.x * w2; aY += (double)v2.y * w2;
    aZ += (double)v2.z * w2; aW += (double)v2.w * w2;
    aX += (double)v3.x * w3; aY += (double)v3.y * w3;
    aZ += (double)v3.z * w3; aW += (double)v3.w * w3;
  }
  for (; j < npair; ++j) {
    int e = p0 + 2 * j + half;
    double w = (double)csrw[e];
    float4 v = h[(size_t)csrc[e] * 32 + c4];
    aX += (double)v.x * w; aY += (double)v.y * w;
    aZ += (double)v.z * w; aW += (double)v.w * w;
  }
  if ((m & 1) && half == 0) {  // odd tail edge -> even-half accumulator
    int e = p1 - 1;
    double w = (double)csrw[e];
    float4 v = h[(size_t)csrc[e] * 32 + c4];
    aX += (double)v.x * w; aY += (double)v.y * w;
    aZ += (double)v.z * w; aW += (double)v.w * w;
  }
  // combine halves (addition is commutative -> both halves identical)
  double sX = aX + __shfl_xor(aX, 32);
  double sY = aY + __shfl_xor(aY, 32);
  double sZ = aZ + __shfl_xor(aZ, 32);
  double sW = aW + __shfl_xor(aW, 32);
  if (half == 0) {
    float4 hv = h[(size_t)node * 32 + c4];
    double bx = 0, by = 0, bz = 0, bw = 0;
    if (bias) {
      bx = (double)bias[c4 * 4 + 0]; by = (double)bias[c4 * 4 + 1];
      bz = (double)bias[c4 * 4 + 2]; bw = (double)bias[c4 * 4 + 3];
    }
    double rx = sX * di + (double)hv.x * dg + bx;
    double ry = sY * di + (double)hv.y * dg + by;
    double rz = sZ * di + (double)hv.z * dg + bz;
    double rw = sW * di + (double)hv.w * dg + bw;
    if (RELU) {
      rx = rx > 0.0 ? rx : 0.0; ry = ry > 0.0 ? ry : 0.0;
      rz = rz > 0.0 ? rz : 0.0; rw = rw > 0.0 ? rw : 0.0;
    }
    y[(size_t)node * 32 + c4] = make_float4((float)rx, (float)ry, (float)rz, (float)rw);
  }
}

// level-0 CSR build only
__global__ void count_deg(const int* __restrict__ dst, int m, int* __restrict__ cnt) {
  int e = blockIdx.x * 256 + threadIdx.x;
  if (e < m) atomicAdd(&cnt[dst[e]], 1);
}

__global__ void fin_deg(const int* __restrict__ cnt, double* __restrict__ dinv,
                        double* __restrict__ dgi, int n) {
  int i = blockIdx.x * 256 + threadIdx.x;
  if (i < n) {
    double d = 1.0 + (double)cnt[i];
    dinv[i] = 1.0 / sqrt(d);
    dgi[i] = 1.0 / d;
  }
}

// ---- deterministic 3-phase multi-block exclusive scan ----
__global__ __launch_bounds__(256) void scan_part(const int* __restrict__ in,
                                                 int* __restrict__ bsum, int n) {
  __shared__ int ts[256];
  int base = blockIdx.x * 1024 + threadIdx.x * 4;
  int s = 0;
#pragma unroll
  for (int j = 0; j < 4; ++j) { int i = base + j; if (i < n) s += in[i]; }
  ts[threadIdx.x] = s;
  __syncthreads();
  for (int d = 128; d > 0; d >>= 1) {
    if (threadIdx.x < d) ts[threadIdx.x] += ts[threadIdx.x + d];
    __syncthreads();
  }
  if (threadIdx.x == 0) bsum[blockIdx.x] = ts[0];
}

__global__ __launch_bounds__(256) void scan_bsum(int* __restrict__ bsum, int nb) {
  __shared__ int ls[256];
  int t = threadIdx.x;
  int v = (t < nb) ? bsum[t] : 0;
  ls[t] = v;
  __syncthreads();
  for (int d = 1; d < 256; d <<= 1) {
    int u = (t >= d) ? ls[t - d] : 0;
    __syncthreads();
    ls[t] += u;
    __syncthreads();
  }
  if (t < nb) bsum[t] = ls[t] - v;  // exclusive prefix
}

__global__ __launch_bounds__(256) void scan_out(const int* __restrict__ in,
    const int* __restrict__ bsum, int* __restrict__ out, int n, int nb) {
  __shared__ int ts[256];
  int base = blockIdx.x * 1024 + threadIdx.x * 4;
  int loc[4];
  int s = 0;
#pragma unroll
  for (int j = 0; j < 4; ++j) {
    int i = base + j;
    int v = (i < n) ? in[i] : 0;
    loc[j] = s; s += v;
  }
  ts[threadIdx.x] = s;
  __syncthreads();
  int mine = s;
  for (int d = 1; d < 256; d <<= 1) {
    int u = (threadIdx.x >= d) ? ts[threadIdx.x - d] : 0;
    __syncthreads();
    ts[threadIdx.x] += u;
    __syncthreads();
  }
  int toff = bsum[blockIdx.x] + ts[threadIdx.x] - mine;
#pragma unroll
  for (int j = 0; j < 4; ++j) {
    int i = base + j;
    if (i < n) out[i] = toff + loc[j];
  }
  if (blockIdx.x == nb - 1 && threadIdx.x == 255) out[n] = bsum[blockIdx.x] + ts[255];
}

__global__ void csr_fill(const int* __restrict__ src, const int* __restrict__ dst,
                         int m, const int* __restrict__ off,
                         int* __restrict__ cursor, int* __restrict__ csrs,
                         float* __restrict__ csrw, const double* __restrict__ dinv) {
  int e = blockIdx.x * 256 + threadIdx.x;
  if (e < m) {
    int d = dst[e];
    int s = src[e];
    int pos = off[d] + atomicAdd(&cursor[d], 1);
    csrs[pos] = s;
    csrw[pos] = (float)dinv[s];
  }
}

// ---- CSR-direct next-level build (no edge list, no atomics) ----
__global__ void next_deg(const int* __restrict__ off, const int* __restrict__ csrs,
                         const int* __restrict__ knid, int* __restrict__ ndeg, int n) {
  int d = blockIdx.x * 256 + threadIdx.x;
  if (d >= n) return;
  int nd = knid[d];
  if (nd < 0) return;
  int cnt = 0;
  int p1 = off[d + 1];
  for (int p = off[d]; p < p1; ++p) cnt += (knid[csrs[p]] >= 0) ? 1 : 0;
  ndeg[nd] = cnt;
}

__global__ void next_fill(const int* __restrict__ off, const int* __restrict__ csrs,
                          const int* __restrict__ knid, const int* __restrict__ noff,
                          const double* __restrict__ ndinv,
                          int* __restrict__ ncsrs, float* __restrict__ ncsrw, int n) {
  int d = blockIdx.x * 256 + threadIdx.x;
  if (d >= n) return;
  int nd = knid[d];
  if (nd < 0) return;
  int pos = noff[nd];
  int p1 = off[d + 1];
  for (int p = off[d]; p < p1; ++p) {
    int s = knid[csrs[p]];
    if (s >= 0) { ncsrs[pos] = s; ncsrw[pos] = (float)ndinv[s]; ++pos; }
  }
}

// fixed grid of 256 blocks; deterministic per-block partials (no atomics).
template <typename T>
__global__ __launch_bounds__(256) void bn_stats(const T* __restrict__ x, int n,
                                                double* __restrict__ part) {
  __shared__ double lsum[256], lsq[256];
  int c = threadIdx.x & 127, half = threadIdx.x >> 7;
  double s = 0, q = 0;
  for (int row = blockIdx.x * 2 + half; row < n; row += 512) {
    double v = (double)x[(size_t)row * 128 + c];
    s += v; q += v * v;
  }
  lsum[threadIdx.x] = s; lsq[threadIdx.x] = q;
  __syncthreads();
  if (half == 0) {
    part[blockIdx.x * 256 + c] = lsum[c] + lsum[c + 128];
    part[blockIdx.x * 256 + 128 + c] = lsq[c] + lsq[c + 128];
  }
}

__global__ void bn_final(const double* __restrict__ part, const float* __restrict__ g,
                         const float* __restrict__ beta, double invn,
                         double* __restrict__ ss) {
  int c = threadIdx.x;  // 128
  double s = 0, q = 0;
  for (int b = 0; b < 256; ++b) {
    s += part[b * 256 + c];
    q += part[b * 256 + 128 + c];
  }
  double m = s * invn;
  double v = q * invn - m * m;
  double sc = (double)g[c] / sqrt(v + 1e-5);
  ss[c] = sc;
  ss[128 + c] = (double)beta[c] - m * sc;
}

// apply BN+ReLU in place, float4; optionally write fp32 snapshot.
__global__ void bn_apply_relu4(float4* __restrict__ x, const double* __restrict__ ss,
                               float4* __restrict__ snap, size_t total4) {
  size_t i = (size_t)blockIdx.x * 256 + threadIdx.x;
  if (i < total4) {
    int c0 = (int)((i & 31) * 4);
    float4 v = x[i];
    double r0 = (double)v.x * ss[c0 + 0] + ss[128 + c0 + 0];
    double r1 = (double)v.y * ss[c0 + 1] + ss[128 + c0 + 1];
    double r2 = (double)v.z * ss[c0 + 2] + ss[128 + c0 + 2];
    double r3 = (double)v.w * ss[c0 + 3] + ss[128 + c0 + 3];
    r0 = r0 > 0.0 ? r0 : 0.0; r1 = r1 > 0.0 ? r1 : 0.0;
    r2 = r2 > 0.0 ? r2 : 0.0; r3 = r3 > 0.0 ? r3 : 0.0;
    float4 o = make_float4((float)r0, (float)r1, (float)r2, (float)r3);
    x[i] = o;
    if (snap) snap[i] = o;
  }
}

__global__ void wnorm_k(const float* __restrict__ w, double* __restrict__ wn) {
  __shared__ double red[128];
  int c = threadIdx.x;
  double v = (double)w[c];
  red[c] = v * v;
  __syncthreads();
  for (int s = 64; s > 0; s >>= 1) { if (c < s) red[c] += red[c + s]; __syncthreads(); }
  if (c == 0) wn[0] = sqrt(red[0]);
}

__global__ __launch_bounds__(256) void score_key_k(const float* __restrict__ x,
    const float* __restrict__ w, const double* __restrict__ wn,
    ull* __restrict__ keys, int n) {
  __shared__ double red[256];
  int c = threadIdx.x & 127;
  int node = blockIdx.x * 2 + (threadIdx.x >> 7);
  double p = 0.0;
  if (node < n) p = (double)x[(size_t)node * 128 + c] * (double)w[c];
  red[threadIdx.x] = p;
  __syncthreads();
  for (int s = 64; s > 0; s >>= 1) {
    if (c < s) red[threadIdx.x] += red[threadIdx.x + s];
    __syncthreads();
  }
  if (c == 0 && node < n) {
    double sc = tanh(red[threadIdx.x] / wn[0]);
    ull u = (ull)__double_as_longlong(sc);
    u = (u >> 63) ? ~u : (u | 0x8000000000000000ULL);
    keys[node] = u;
  }
}

__global__ void sel_init(Sel* sel, int k) {
  if (threadIdx.x == 0) { sel->prefix = 0ULL; sel->remaining = k; }
}

__global__ void rs_hist(const ull* __restrict__ keys, int n, const Sel* __restrict__ sel,
                        int shift, int pass, int* __restrict__ hist) {
  __shared__ int lh[256];
  lh[threadIdx.x] = 0;
  __syncthreads();
  int i = blockIdx.x * 256 + threadIdx.x;
  if (i < n) {
    ull k = keys[i];
    bool ok = (pass == 0) || (((k ^ sel->prefix) >> (shift + 8)) == 0);
    if (ok) atomicAdd(&lh[(int)((k >> shift) & 255)], 1);
  }
  __syncthreads();
  if (lh[threadIdx.x]) atomicAdd(&hist[threadIdx.x], lh[threadIdx.x]);
}

__global__ void rs_pick(const int* __restrict__ hist, Sel* sel, int shift) {
  __shared__ int lh[256];
  lh[threadIdx.x] = hist[threadIdx.x];
  __syncthreads();
  if (threadIdx.x == 0) {
    int rem = sel->remaining;
    for (int b = 255; b >= 0; --b) {
      int c = lh[b];
      if (c >= rem) { sel->prefix |= ((ull)b) << shift; break; }
      rem -= c;
    }
    sel->remaining = rem;
  }
}

__global__ void eq_flags(const ull* __restrict__ keys, const Sel* __restrict__ sel,
                         int* __restrict__ eqf, int n) {
  int i = blockIdx.x * 256 + threadIdx.x;
  if (i < n) eqf[i] = (keys[i] == sel->prefix) ? 1 : 0;
}

__global__ void kept_flags(const ull* __restrict__ keys, const Sel* __restrict__ sel,
                           const int* __restrict__ eqpre, int* __restrict__ kept, int n) {
  int i = blockIdx.x * 256 + threadIdx.x;
  if (i < n) {
    ull u = keys[i], p = sel->prefix;
    kept[i] = (u > p || (u == p && eqpre[i] < sel->remaining)) ? 1 : 0;
  }
}

// knid = new id if kept else -1; idx[newid] = old id.
__global__ void build_idx(const int* __restrict__ kept, const int* __restrict__ npre,
                          int* __restrict__ knid, int* __restrict__ idx, int n) {
  int i = blockIdx.x * 256 + threadIdx.x;
  if (i < n) {
    if (kept[i]) {
      int nid = npre[i];
      knid[i] = nid;
      idx[nid] = i;
    } else {
      knid[i] = -1;
    }
  }
}

__global__ void gather_rows4(const float4* __restrict__ xs, const int* __restrict__ idx,
                             float4* __restrict__ xo, int k) {
  int i = blockIdx.x * 256 + threadIdx.x;
  if (i < k * 32) xo[i] = xs[(size_t)idx[i >> 5] * 32 + (i & 31)];
}

__global__ void scatter_add_rows4(float4* __restrict__ h, const float4* __restrict__ t,
                                  const int* __restrict__ idx, int k) {
  int i = blockIdx.x * 256 + threadIdx.x;
  if (i < k * 32) {
    float4 a = h[(size_t)idx[i >> 5] * 32 + (i & 31)];
    float4 b = t[i];
    a.x += b.x; a.y += b.y; a.z += b.z; a.w += b.w;
    h[(size_t)idx[i >> 5] * 32 + (i & 31)] = a;
  }
}

// ---------------- host ----------------

extern "C" void kernel_launch(void* const* d_in, const int* in_sizes, int n_in,
                              void* d_out, int out_size, void* d_ws, size_t ws_size,
                              hipStream_t stream) {
  (void)in_sizes; (void)out_size;
  if (n_in < 17) return;
  const float* x_in   = (const float*)d_in[0];
  const int*   ei     = (const int*)  d_in[1];
  const float* in_W   = (const float*)d_in[2];
  const float* in_b   = (const float*)d_in[3];
  const float* dn_W   = (const float*)d_in[4];
  const float* dn_b   = (const float*)d_in[5];
  const float* dn_g   = (const float*)d_in[6];
  const float* dn_bt  = (const float*)d_in[7];
  const float* pool_w = (const float*)d_in[8];
  const float* bot_W  = (const float*)d_in[9];
  const float* bot_b  = (const float*)d_in[10];
  const float* up_W   = (const float*)d_in[11];
  const float* up_b   = (const float*)d_in[12];
  const float* up_g   = (const float*)d_in[13];
  const float* up_bt  = (const float*)d_in[14];
  const float* out_W  = (const float*)d_in[15];
  const float* out_b  = (const float*)d_in[16];
  float* outp = (float*)d_out;

  char* base = (char*)d_ws;
  size_t off = 0;
  auto alloc = [&](size_t b) -> void* {
    void* r = base + off;
    off = (off + b + 255) & ~(size_t)255;
    return r;
  };
  // fp32 storage everywhere; double accumulation inside kernels.
  float* bufA = (float*)alloc((size_t)N0_ * 128 * 4);   // 51.2 MB
  float* bufB = (float*)alloc((size_t)N0_ * 128 * 4);   // 51.2 MB
  float* xs0f = (float*)alloc((size_t)N0_ * 128 * 4);   // 51.2 MB
  float* xs1f = (float*)alloc((size_t)N1_ * 128 * 4);   // 25.6 MB
  float* xs2f = (float*)alloc((size_t)N2_ * 128 * 4);   // 12.8 MB

  int* csrs0 = (int*)alloc((size_t)EDG * 4);
  int* csrs1 = (int*)alloc((size_t)CAP1 * 4);
  int* csrs2 = (int*)alloc((size_t)CAP2 * 4);
  int* csrs3 = (int*)alloc((size_t)CAP3 * 4);
  float* csrw0 = (float*)alloc((size_t)EDG * 4);
  float* csrw1 = (float*)alloc((size_t)CAP1 * 4);
  float* csrw2 = (float*)alloc((size_t)CAP2 * 4);
  float* csrw3 = (float*)alloc((size_t)CAP3 * 4);
  int* csro0 = (int*)alloc((size_t)(N0_ + 1) * 4);
  int* csro1 = (int*)alloc((size_t)(N1_ + 1) * 4);
  int* csro2 = (int*)alloc((size_t)(N2_ + 1) * 4);
  int* csro3 = (int*)alloc((size_t)(N3_ + 1) * 4);
  double* dinv0 = (double*)alloc((size_t)N0_ * 8); double* dgi0 = (double*)alloc((size_t)N0_ * 8);
  double* dinv1 = (double*)alloc((size_t)N1_ * 8); double* dgi1 = (double*)alloc((size_t)N1_ * 8);
  double* dinv2 = (double*)alloc((size_t)N2_ * 8); double* dgi2 = (double*)alloc((size_t)N2_ * 8);
  double* dinv3 = (double*)alloc((size_t)N3_ * 8); double* dgi3 = (double*)alloc((size_t)N3_ * 8);
  ull* keys = (ull*)alloc((size_t)N0_ * 8);
  int* eqf   = (int*)alloc((size_t)N0_ * 4);
  int* eqpre = (int*)alloc((size_t)(N0_ + 1) * 4);
  int* kept  = (int*)alloc((size_t)N0_ * 4);
  int* npre  = (int*)alloc((size_t)(N0_ + 1) * 4);
  int* knid  = (int*)alloc((size_t)N0_ * 4);
  int* degcnt = (int*)alloc((size_t)N0_ * 4);
  int* cursor = (int*)alloc((size_t)N0_ * 4);
  int* idx0 = (int*)alloc((size_t)N1_ * 4);
  int* idx1 = (int*)alloc((size_t)N2_ * 4);
  int* idx2 = (int*)alloc((size_t)N3_ * 4);
  int* hist = (int*)alloc(8 * 256 * 4);
  Sel* sel  = (Sel*)alloc(256);
  int* bscan = (int*)alloc(256 * 4);               // block sums for 3-phase scan
  double* bns = (double*)alloc((size_t)256 * 256 * 8);  // per-block BN partials
  double* ssb = (double*)alloc(256 * 8);
  double* wn  = (double*)alloc(256);
  if (off > ws_size) {  // signal: absmax will be ~ws_size
    sentinel_k<<<1, 64, 0, stream>>>(outp, (float)ws_size);
    return;
  }

  const int nL[4]   = {N0_, N1_, N2_, N3_};
  int* csrsL[4] = {csrs0, csrs1, csrs2, csrs3};
  float* csrwL[4] = {csrw0, csrw1, csrw2, csrw3};
  int* csroL[4] = {csro0, csro1, csro2, csro3};
  double* dinvL[4] = {dinv0, dinv1, dinv2, dinv3};
  double* dgiL[4]  = {dgi0, dgi1, dgi2, dgi3};
  int* idxL[3] = {idx0, idx1, idx2};

  auto cdiv = [](int a, int b) { return (a + b - 1) / b; };

  // deterministic 3-phase exclusive scan (n <= 262144)
  auto scan = [&](const int* in, int* out, int n) {
    int nb = cdiv(n, 1024);
    scan_part<<<nb, 256, 0, stream>>>(in, bscan, n);
    scan_bsum<<<1, 256, 0, stream>>>(bscan, nb);
    scan_out<<<nb, 256, 0, stream>>>(in, bscan, out, n, nb);
  };

  auto bn_f = [&](float* xp, int n, const float* g, const float* b, float* snap) {
    bn_stats<float><<<256, 256, 0, stream>>>(xp, n, bns);
    bn_final<<<1, 128, 0, stream>>>(bns, g, b, 1.0 / (double)n, ssb);
    bn_apply_relu4<<<cdiv(n * 32, 256), 256, 0, stream>>>(
        (float4*)xp, ssb, (float4*)snap, (size_t)n * 32);
  };

  // pool level i: top-k on xcur; gather kept rows into xnext; build level i+1
  // CSR directly from level-i CSR (no edge list, no atomics).
  auto pool = [&](int i, const float* xcur, float* xnext) {
    int n = nL[i], k = nL[i + 1];
    wnorm_k<<<1, 128, 0, stream>>>(pool_w + i * 128, wn);
    score_key_k<<<cdiv(n, 2), 256, 0, stream>>>(xcur, pool_w + i * 128, wn, keys, n);
    sel_init<<<1, 64, 0, stream>>>(sel, k);
    hipMemsetAsync(hist, 0, 8 * 256 * 4, stream);
    for (int p = 0; p < 8; ++p) {
      int shift = 56 - 8 * p;
      rs_hist<<<cdiv(n, 256), 256, 0, stream>>>(keys, n, sel, shift, p, hist + p * 256);
      rs_pick<<<1, 256, 0, stream>>>(hist + p * 256, sel, shift);
    }
    eq_flags<<<cdiv(n, 256), 256, 0, stream>>>(keys, sel, eqf, n);
    scan(eqf, eqpre, n);
    kept_flags<<<cdiv(n, 256), 256, 0, stream>>>(keys, sel, eqpre, kept, n);
    scan(kept, npre, n);
    build_idx<<<cdiv(n, 256), 256, 0, stream>>>(kept, npre, knid, idxL[i], n);
    gather_rows4<<<cdiv(k * 32, 256), 256, 0, stream>>>(
        (const float4*)xcur, idxL[i], (float4*)xnext, k);
    // next-level CSR: deg -> dinv/dgi -> offsets -> fill
    next_deg<<<cdiv(n, 256), 256, 0, stream>>>(csroL[i], csrsL[i], knid, degcnt, n);
    fin_deg<<<cdiv(k, 256), 256, 0, stream>>>(degcnt, dinvL[i + 1], dgiL[i + 1], k);
    scan(degcnt, csroL[i + 1], k);
    next_fill<<<cdiv(n, 256), 256, 0, stream>>>(csroL[i], csrsL[i], knid,
        csroL[i + 1], dinvL[i + 1], csrsL[i + 1], csrwL[i + 1], n);
  };

  // ---- level 0 CSR (from raw edge list) ----
  hipMemsetAsync(degcnt, 0, (size_t)N0_ * 4, stream);
  count_deg<<<cdiv(EDG, 256), 256, 0, stream>>>(ei + EDG, EDG, degcnt);
  fin_deg<<<cdiv(N0_, 256), 256, 0, stream>>>(degcnt, dinv0, dgi0, N0_);
  scan(degcnt, csro0, N0_);
  hipMemsetAsync(cursor, 0, (size_t)N0_ * 4, stream);
  csr_fill<<<cdiv(EDG, 256), 256, 0, stream>>>(ei, ei + EDG, EDG, csro0, cursor,
                                               csrs0, csrw0, dinv0);

  // ---- initial conv (agg-first: agg(x W)+b = (agg x) W + b) ----
  agg_conv<false><<<cdiv(N0_, 4), 256, 0, stream>>>(
      x_in, csro0, csrs0, csrw0, dinv0, dgi0, nullptr, bufB, N0_);
  matmul128<float, float, double><<<cdiv(N0_, 64), 256, 0, stream>>>(bufB, in_W, in_b, bufA, N0_);

  // ---- down level 0: x in A, h in B, y back to A; snap -> xs0f; x1 -> B ----
  matmul128<float, float, double><<<cdiv(N0_, 64), 256, 0, stream>>>(bufA, dn_W, nullptr, bufB, N0_);
  agg_conv<false><<<cdiv(N0_, 4), 256, 0, stream>>>(
      bufB, csro0, csrs0, csrw0, dinv0, dgi0, dn_b, bufA, N0_);
  bn_f(bufA, N0_, dn_g, dn_bt, xs0f);
  pool(0, bufA, bufB);

  // ---- down level 1: x in B, h in A, y back to B; snap -> xs1f; x2 -> A ----
  matmul128<float, float, double><<<cdiv(N1_, 64), 256, 0, stream>>>(bufB, dn_W + 16384, nullptr, bufA, N1_);
  agg_conv<false><<<cdiv(N1_, 4), 256, 0, stream>>>(
      bufA, csro1, csrs1, csrw1, dinv1, dgi1, dn_b + 128, bufB, N1_);
  bn_f(bufB, N1_, dn_g + 128, dn_bt + 128, xs1f);
  pool(1, bufB, bufA);

  // ---- down level 2: x in A, h in B, y back to A; snap -> xs2f; x3 -> B ----
  matmul128<float, float, double><<<cdiv(N2_, 64), 256, 0, stream>>>(bufA, dn_W + 32768, nullptr, bufB, N2_);
  agg_conv<false><<<cdiv(N2_, 4), 256, 0, stream>>>(
      bufB, csro2, csrs2, csrw2, dinv2, dgi2, dn_b + 256, bufA, N2_);
  bn_f(bufA, N2_, dn_g + 256, dn_bt + 256, xs2f);
  pool(2, bufA, bufB);

  // ---- bottom: x3 in B, h3 -> A, z3 (relu) -> B ----
  matmul128<float, float, double><<<cdiv(N3_, 64), 256, 0, stream>>>(bufB, bot_W, nullptr, bufA, N3_);
  float* zf = bufB;
  float* hf = bufA;
  float* tf = outp;  // d_out as scratch until final write (fully overwritten)
  agg_conv<true><<<cdiv(N3_, 4), 256, 0, stream>>>(
      bufA, csro3, csrs3, csrw3, dinv3, dgi3, bot_b, zf, N3_);

  // ---- up path: z in B, hf in A ----
  for (int u = 0; u < 3; ++u) {
    int l = 2 - u;
    int nl = nL[l], nz = nL[l + 1];
    const float* Wt = up_W + u * 32768;          // rows [0:128)  -> unpooled part
    const float* Wb = up_W + u * 32768 + 16384;  // rows [128:256)-> skip part
    const float* xsf = (u == 0) ? xs2f : (u == 1) ? xs1f : xs0f;
    matmul128<float, float, float><<<cdiv(nz, 64), 256, 0, stream>>>(zf, Wt, nullptr, tf, nz);
    matmul128<float, float, float><<<cdiv(nl, 64), 256, 0, stream>>>(xsf, Wb, nullptr, hf, nl);
    scatter_add_rows4<<<cdiv(nz * 32, 256), 256, 0, stream>>>(
        (float4*)hf, (const float4*)tf, idxL[l], nz);
    agg_conv<false><<<cdiv(nl, 4), 256, 0, stream>>>(
        hf, csroL[l], csrsL[l], csrwL[l], dinvL[l], dgiL[l], up_b + u * 128, zf, nl);
    bn_f(zf, nl, up_g + u * 128, up_bt + u * 128, nullptr);
  }

  // ---- final conv -> d_out ----
  matmul128<float, float, float><<<cdiv(N0_, 64), 256, 0, stream>>>(zf, out_W, nullptr, hf, N0_);
  agg_conv<false><<<cdiv(N0_, 4), 256, 0, stream>>>(
      hf, csro0, csrs0, csrw0, dinv0, dgi0, out_b, outp, N0_);
}

// Round 8
// 2564.972 us; speedup vs baseline: 1.5670x; 1.0442x over previous
//
#include <hip/hip_runtime.h>

typedef unsigned long long ull;

#define N0_ 100000
#define N1_ 50000
#define N2_ 25000
#define N3_ 12500
#define EDG 1600000
#define CAP1 600000
#define CAP2 200000
#define CAP3 80000
#define RB 65536

struct Sel { ull prefix; int remaining; };

// ---------------- kernels ----------------

__global__ void sentinel_k(float* o, float v) { if (threadIdx.x == 0) o[0] = v; }

// C[n,128] = A[n,128] @ W[128,128] (+bias), ACC-typed accumulate. 64 rows/block.
template <typename TA, typename TC, typename ACC>
__global__ __launch_bounds__(256) void matmul128(const TA* __restrict__ A,
    const float* __restrict__ W, const float* __restrict__ bias,
    TC* __restrict__ C, int n) {
  __shared__ float Al[64 * 33];
  __shared__ float Wl[32 * 128];
  int tid = threadIdx.x;
  int colb = tid & 31;
  int rg = tid >> 5;
  int row0 = blockIdx.x * 64;
  ACC acc[8][4];
#pragma unroll
  for (int r = 0; r < 8; ++r)
#pragma unroll
    for (int j = 0; j < 4; ++j) acc[r][j] = (ACC)0;
  for (int kt = 0; kt < 128; kt += 32) {
    for (int i = tid; i < 64 * 32; i += 256) {
      int r = i >> 5, kk = i & 31;
      int row = row0 + r;
      Al[r * 33 + kk] = (row < n) ? (float)A[(size_t)row * 128 + kt + kk] : 0.0f;
    }
    for (int i = tid; i < 32 * 128; i += 256) {
      int kk = i >> 7, c = i & 127;
      Wl[i] = W[(size_t)(kt + kk) * 128 + c];
    }
    __syncthreads();
#pragma unroll 4
    for (int kk = 0; kk < 32; ++kk) {
      ACC b0 = (ACC)Wl[kk * 128 + colb];
      ACC b1 = (ACC)Wl[kk * 128 + colb + 32];
      ACC b2 = (ACC)Wl[kk * 128 + colb + 64];
      ACC b3 = (ACC)Wl[kk * 128 + colb + 96];
#pragma unroll
      for (int r = 0; r < 8; ++r) {
        ACC a = (ACC)Al[(rg * 8 + r) * 33 + kk];
        acc[r][0] += a * b0; acc[r][1] += a * b1;
        acc[r][2] += a * b2; acc[r][3] += a * b3;
      }
    }
    __syncthreads();
  }
  ACC bb0 = 0, bb1 = 0, bb2 = 0, bb3 = 0;
  if (bias) {
    bb0 = (ACC)bias[colb]; bb1 = (ACC)bias[colb + 32];
    bb2 = (ACC)bias[colb + 64]; bb3 = (ACC)bias[colb + 96];
  }
  for (int r = 0; r < 8; ++r) {
    int row = row0 + rg * 8 + r;
    if (row < n) {
      size_t o = (size_t)row * 128 + colb;
      C[o] = (TC)(acc[r][0] + bb0); C[o + 32] = (TC)(acc[r][1] + bb1);
      C[o + 64] = (TC)(acc[r][2] + bb2); C[o + 96] = (TC)(acc[r][3] + bb3);
    }
  }
}

// Full-wave float4 agg: 1 wave per node; lanes 0-31 even edges, 32-63 odd.
// unroll-8 pairs (16 edges, 8 gathers in flight/lane). Double accumulation;
// sequential edge order preserved -> bit-identical to prior rounds.
template <bool RELU>
__global__ __launch_bounds__(256) void agg_conv(const float* __restrict__ hp,
    const int* __restrict__ off, const int* __restrict__ csrc,
    const float* __restrict__ csrw,
    const double* __restrict__ dinv, const double* __restrict__ dgi,
    const float* __restrict__ bias, float* __restrict__ yp, int n) {
  const float4* __restrict__ h = (const float4*)hp;
  float4* __restrict__ y = (float4*)yp;
  int lane = threadIdx.x & 63;
  int c4 = lane & 31;
  int half = lane >> 5;
  int node = blockIdx.x * 4 + (threadIdx.x >> 6);
  if (node >= n) return;
  double di = dinv[node];
  double dg = dgi[node];
  double aX = 0, aY = 0, aZ = 0, aW = 0;
  int p0 = off[node], p1 = off[node + 1];
  int m = p1 - p0;
  int npair = m >> 1;
  int j = 0;
  for (; j + 8 <= npair; j += 8) {
    int e0 = p0 + 2 * j + half;
    int s0 = csrc[e0],      s1 = csrc[e0 + 2],  s2 = csrc[e0 + 4],  s3 = csrc[e0 + 6];
    int s4 = csrc[e0 + 8],  s5 = csrc[e0 + 10], s6 = csrc[e0 + 12], s7 = csrc[e0 + 14];
    double w0 = (double)csrw[e0],      w1 = (double)csrw[e0 + 2];
    double w2 = (double)csrw[e0 + 4],  w3 = (double)csrw[e0 + 6];
    double w4 = (double)csrw[e0 + 8],  w5 = (double)csrw[e0 + 10];
    double w6 = (double)csrw[e0 + 12], w7 = (double)csrw[e0 + 14];
    float4 v0 = h[(size_t)s0 * 32 + c4];
    float4 v1 = h[(size_t)s1 * 32 + c4];
    float4 v2 = h[(size_t)s2 * 32 + c4];
    float4 v3 = h[(size_t)s3 * 32 + c4];
    float4 v4 = h[(size_t)s4 * 32 + c4];
    float4 v5 = h[(size_t)s5 * 32 + c4];
    float4 v6 = h[(size_t)s6 * 32 + c4];
    float4 v7 = h[(size_t)s7 * 32 + c4];
    aX += (double)v0.x * w0; aY += (double)v0.y * w0;
    aZ += (double)v0.z * w0; aW += (double)v0.w * w0;
    aX += (double)v1.x * w1; aY += (double)v1.y * w1;
    aZ += (double)v1.z * w1; aW += (double)v1.w * w1;
    aX += (double)v2.x * w2; aY += (double)v2.y * w2;
    aZ += (double)v2.z * w2; aW += (double)v2.w * w2;
    aX += (double)v3.x * w3; aY += (double)v3.y * w3;
    aZ += (double)v3.z * w3; aW += (double)v3.w * w3;
    aX += (double)v4.x * w4; aY += (double)v4.y * w4;
    aZ += (double)v4.z * w4; aW += (double)v4.w * w4;
    aX += (double)v5.x * w5; aY += (double)v5.y * w5;
    aZ += (double)v5.z * w5; aW += (double)v5.w * w5;
    aX += (double)v6.x * w6; aY += (double)v6.y * w6;
    aZ += (double)v6.z * w6; aW += (double)v6.w * w6;
    aX += (double)v7.x * w7; aY += (double)v7.y * w7;
    aZ += (double)v7.z * w7; aW += (double)v7.w * w7;
  }
  for (; j + 4 <= npair; j += 4) {
    int e0 = p0 + 2 * j + half;
    int s0 = csrc[e0], s1 = csrc[e0 + 2], s2 = csrc[e0 + 4], s3 = csrc[e0 + 6];
    double w0 = (double)csrw[e0],     w1 = (double)csrw[e0 + 2];
    double w2 = (double)csrw[e0 + 4], w3 = (double)csrw[e0 + 6];
    float4 v0 = h[(size_t)s0 * 32 + c4];
    float4 v1 = h[(size_t)s1 * 32 + c4];
    float4 v2 = h[(size_t)s2 * 32 + c4];
    float4 v3 = h[(size_t)s3 * 32 + c4];
    aX += (double)v0.x * w0; aY += (double)v0.y * w0;
    aZ += (double)v0.z * w0; aW += (double)v0.w * w0;
    aX += (double)v1.x * w1; aY += (double)v1.y * w1;
    aZ += (double)v1.z * w1; aW += (double)v1.w * w1;
    aX += (double)v2.x * w2; aY += (double)v2.y * w2;
    aZ += (double)v2.z * w2; aW += (double)v2.w * w2;
    aX += (double)v3.x * w3; aY += (double)v3.y * w3;
    aZ += (double)v3.z * w3; aW += (double)v3.w * w3;
  }
  for (; j < npair; ++j) {
    int e = p0 + 2 * j + half;
    double w = (double)csrw[e];
    float4 v = h[(size_t)csrc[e] * 32 + c4];
    aX += (double)v.x * w; aY += (double)v.y * w;
    aZ += (double)v.z * w; aW += (double)v.w * w;
  }
  if ((m & 1) && half == 0) {
    int e = p1 - 1;
    double w = (double)csrw[e];
    float4 v = h[(size_t)csrc[e] * 32 + c4];
    aX += (double)v.x * w; aY += (double)v.y * w;
    aZ += (double)v.z * w; aW += (double)v.w * w;
  }
  double sX = aX + __shfl_xor(aX, 32);
  double sY = aY + __shfl_xor(aY, 32);
  double sZ = aZ + __shfl_xor(aZ, 32);
  double sW = aW + __shfl_xor(aW, 32);
  if (half == 0) {
    float4 hv = h[(size_t)node * 32 + c4];
    double bx = 0, by = 0, bz = 0, bw = 0;
    if (bias) {
      bx = (double)bias[c4 * 4 + 0]; by = (double)bias[c4 * 4 + 1];
      bz = (double)bias[c4 * 4 + 2]; bw = (double)bias[c4 * 4 + 3];
    }
    double rx = sX * di + (double)hv.x * dg + bx;
    double ry = sY * di + (double)hv.y * dg + by;
    double rz = sZ * di + (double)hv.z * dg + bz;
    double rw = sW * di + (double)hv.w * dg + bw;
    if (RELU) {
      rx = rx > 0.0 ? rx : 0.0; ry = ry > 0.0 ? ry : 0.0;
      rz = rz > 0.0 ? rz : 0.0; rw = rw > 0.0 ? rw : 0.0;
    }
    y[(size_t)node * 32 + c4] = make_float4((float)rx, (float)ry, (float)rz, (float)rw);
  }
}

// level-0 CSR build only
__global__ void count_deg(const int* __restrict__ dst, int m, int* __restrict__ cnt) {
  int e = blockIdx.x * 256 + threadIdx.x;
  if (e < m) atomicAdd(&cnt[dst[e]], 1);
}

__global__ void fin_deg(const int* __restrict__ cnt, double* __restrict__ dinv,
                        double* __restrict__ dgi, int n) {
  int i = blockIdx.x * 256 + threadIdx.x;
  if (i < n) {
    double d = 1.0 + (double)cnt[i];
    dinv[i] = 1.0 / sqrt(d);
    dgi[i] = 1.0 / d;
  }
}

// ---- deterministic 3-phase multi-block exclusive scan (int input) ----
__global__ __launch_bounds__(256) void scan_part(const int* __restrict__ in,
                                                 int* __restrict__ bsum, int n) {
  __shared__ int ts[256];
  int base = blockIdx.x * 1024 + threadIdx.x * 4;
  int s = 0;
#pragma unroll
  for (int j = 0; j < 4; ++j) { int i = base + j; if (i < n) s += in[i]; }
  ts[threadIdx.x] = s;
  __syncthreads();
  for (int d = 128; d > 0; d >>= 1) {
    if (threadIdx.x < d) ts[threadIdx.x] += ts[threadIdx.x + d];
    __syncthreads();
  }
  if (threadIdx.x == 0) bsum[blockIdx.x] = ts[0];
}

__global__ __launch_bounds__(256) void scan_bsum(int* __restrict__ bsum, int nb) {
  __shared__ int ls[256];
  int t = threadIdx.x;
  int v = (t < nb) ? bsum[t] : 0;
  ls[t] = v;
  __syncthreads();
  for (int d = 1; d < 256; d <<= 1) {
    int u = (t >= d) ? ls[t - d] : 0;
    __syncthreads();
    ls[t] += u;
    __syncthreads();
  }
  if (t < nb) bsum[t] = ls[t] - v;
}

__global__ __launch_bounds__(256) void scan_out(const int* __restrict__ in,
    const int* __restrict__ bsum, int* __restrict__ out, int n, int nb) {
  __shared__ int ts[256];
  int base = blockIdx.x * 1024 + threadIdx.x * 4;
  int loc[4];
  int s = 0;
#pragma unroll
  for (int j = 0; j < 4; ++j) {
    int i = base + j;
    int v = (i < n) ? in[i] : 0;
    loc[j] = s; s += v;
  }
  ts[threadIdx.x] = s;
  __syncthreads();
  int mine = s;
  for (int d = 1; d < 256; d <<= 1) {
    int u = (threadIdx.x >= d) ? ts[threadIdx.x - d] : 0;
    __syncthreads();
    ts[threadIdx.x] += u;
    __syncthreads();
  }
  int toff = bsum[blockIdx.x] + ts[threadIdx.x] - mine;
#pragma unroll
  for (int j = 0; j < 4; ++j) {
    int i = base + j;
    if (i < n) out[i] = toff + loc[j];
  }
  if (blockIdx.x == nb - 1 && threadIdx.x == 255) out[n] = bsum[blockIdx.x] + ts[255];
}

// ---- flag-fused scans (flag computed on the fly from keys/sel/eqpre) ----
// MODE 1: eq flag (key == prefix). MODE 2: kept flag.
template <int MODE>
__device__ __forceinline__ int sel_flag(ull u, ull pref, int epre, int rem) {
  if (MODE == 1) return (u == pref) ? 1 : 0;
  return (u > pref || (u == pref && epre < rem)) ? 1 : 0;
}

template <int MODE>
__global__ __launch_bounds__(256) void fscan_part(const ull* __restrict__ keys,
    const int* __restrict__ eqpre, const Sel* __restrict__ sel,
    int* __restrict__ bsum, int n) {
  __shared__ int ts[256];
  ull pref = sel->prefix;
  int rem = sel->remaining;
  int base = blockIdx.x * 1024 + threadIdx.x * 4;
  int s = 0;
#pragma unroll
  for (int j = 0; j < 4; ++j) {
    int i = base + j;
    if (i < n) s += sel_flag<MODE>(keys[i], pref, (MODE == 2) ? eqpre[i] : 0, rem);
  }
  ts[threadIdx.x] = s;
  __syncthreads();
  for (int d = 128; d > 0; d >>= 1) {
    if (threadIdx.x < d) ts[threadIdx.x] += ts[threadIdx.x + d];
    __syncthreads();
  }
  if (threadIdx.x == 0) bsum[blockIdx.x] = ts[0];
}

// MODE 1 output: eqpre_out[i] = exclusive prefix of eq flags.
__global__ __launch_bounds__(256) void fscan_out1(const ull* __restrict__ keys,
    const Sel* __restrict__ sel, const int* __restrict__ bsum,
    int* __restrict__ eqpre_out, int n) {
  __shared__ int ts[256];
  ull pref = sel->prefix;
  int base = blockIdx.x * 1024 + threadIdx.x * 4;
  int loc[4];
  int s = 0;
#pragma unroll
  for (int j = 0; j < 4; ++j) {
    int i = base + j;
    int v = (i < n) ? sel_flag<1>(keys[i], pref, 0, 0) : 0;
    loc[j] = s; s += v;
  }
  ts[threadIdx.x] = s;
  __syncthreads();
  int mine = s;
  for (int d = 1; d < 256; d <<= 1) {
    int u = (threadIdx.x >= d) ? ts[threadIdx.x - d] : 0;
    __syncthreads();
    ts[threadIdx.x] += u;
    __syncthreads();
  }
  int toff = bsum[blockIdx.x] + ts[threadIdx.x] - mine;
#pragma unroll
  for (int j = 0; j < 4; ++j) {
    int i = base + j;
    if (i < n) eqpre_out[i] = toff + loc[j];
  }
}

// MODE 2 output phase fused with build_idx: writes knid + idx directly.
__global__ __launch_bounds__(256) void fscan_out2(const ull* __restrict__ keys,
    const int* __restrict__ eqpre, const Sel* __restrict__ sel,
    const int* __restrict__ bsum, int* __restrict__ knid, int* __restrict__ idx,
    int n) {
  __shared__ int ts[256];
  ull pref = sel->prefix;
  int rem = sel->remaining;
  int base = blockIdx.x * 1024 + threadIdx.x * 4;
  int flg[4];
  int loc[4];
  int s = 0;
#pragma unroll
  for (int j = 0; j < 4; ++j) {
    int i = base + j;
    int v = (i < n) ? sel_flag<2>(keys[i], pref, eqpre[i], rem) : 0;
    flg[j] = v; loc[j] = s; s += v;
  }
  ts[threadIdx.x] = s;
  __syncthreads();
  int mine = s;
  for (int d = 1; d < 256; d <<= 1) {
    int u = (threadIdx.x >= d) ? ts[threadIdx.x - d] : 0;
    __syncthreads();
    ts[threadIdx.x] += u;
    __syncthreads();
  }
  int toff = bsum[blockIdx.x] + ts[threadIdx.x] - mine;
#pragma unroll
  for (int j = 0; j < 4; ++j) {
    int i = base + j;
    if (i < n) {
      if (flg[j]) {
        int nid = toff + loc[j];
        knid[i] = nid;
        idx[nid] = i;
      } else {
        knid[i] = -1;
      }
    }
  }
}

__global__ void csr_fill(const int* __restrict__ src, const int* __restrict__ dst,
                         int m, const int* __restrict__ off,
                         int* __restrict__ cursor, int* __restrict__ csrs,
                         float* __restrict__ csrw, const double* __restrict__ dinv) {
  int e = blockIdx.x * 256 + threadIdx.x;
  if (e < m) {
    int d = dst[e];
    int s = src[e];
    int pos = off[d] + atomicAdd(&cursor[d], 1);
    csrs[pos] = s;
    csrw[pos] = (float)dinv[s];
  }
}

// next_deg fused with fin_deg: writes ndeg + dinv/dgi for next level.
__global__ void next_deg_fin(const int* __restrict__ off, const int* __restrict__ csrs,
                             const int* __restrict__ knid, int* __restrict__ ndeg,
                             double* __restrict__ ndinv, double* __restrict__ ndgi,
                             int n) {
  int d = blockIdx.x * 256 + threadIdx.x;
  if (d >= n) return;
  int nd = knid[d];
  if (nd < 0) return;
  int cnt = 0;
  int p1 = off[d + 1];
  for (int p = off[d]; p < p1; ++p) cnt += (knid[csrs[p]] >= 0) ? 1 : 0;
  ndeg[nd] = cnt;
  double dd = 1.0 + (double)cnt;
  ndinv[nd] = 1.0 / sqrt(dd);
  ndgi[nd] = 1.0 / dd;
}

__global__ void next_fill(const int* __restrict__ off, const int* __restrict__ csrs,
                          const int* __restrict__ knid, const int* __restrict__ noff,
                          const double* __restrict__ ndinv,
                          int* __restrict__ ncsrs, float* __restrict__ ncsrw, int n) {
  int d = blockIdx.x * 256 + threadIdx.x;
  if (d >= n) return;
  int nd = knid[d];
  if (nd < 0) return;
  int pos = noff[nd];
  int p1 = off[d + 1];
  for (int p = off[d]; p < p1; ++p) {
    int s = knid[csrs[p]];
    if (s >= 0) { ncsrs[pos] = s; ncsrw[pos] = (float)ndinv[s]; ++pos; }
  }
}

// fixed grid of 256 blocks; deterministic per-block partials (no atomics).
template <typename T>
__global__ __launch_bounds__(256) void bn_stats(const T* __restrict__ x, int n,
                                                double* __restrict__ part) {
  __shared__ double lsum[256], lsq[256];
  int c = threadIdx.x & 127, half = threadIdx.x >> 7;
  double s = 0, q = 0;
  for (int row = blockIdx.x * 2 + half; row < n; row += 512) {
    double v = (double)x[(size_t)row * 128 + c];
    s += v; q += v * v;
  }
  lsum[threadIdx.x] = s; lsq[threadIdx.x] = q;
  __syncthreads();
  if (half == 0) {
    part[blockIdx.x * 256 + c] = lsum[c] + lsum[c + 128];
    part[blockIdx.x * 256 + 128 + c] = lsq[c] + lsq[c + 128];
  }
}

__global__ void bn_final(const double* __restrict__ part, const float* __restrict__ g,
                         const float* __restrict__ beta, double invn,
                         double* __restrict__ ss) {
  int c = threadIdx.x;  // 128
  double s = 0, q = 0;
  for (int b = 0; b < 256; ++b) {
    s += part[b * 256 + c];
    q += part[b * 256 + 128 + c];
  }
  double m = s * invn;
  double v = q * invn - m * m;
  double sc = (double)g[c] / sqrt(v + 1e-5);
  ss[c] = sc;
  ss[128 + c] = (double)beta[c] - m * sc;
}

// BN+ReLU float4; out may equal x (in place) or be a distinct destination.
__global__ void bn_apply_relu4(const float4* __restrict__ x,
                               const double* __restrict__ ss,
                               float4* __restrict__ out, size_t total4) {
  size_t i = (size_t)blockIdx.x * 256 + threadIdx.x;
  if (i < total4) {
    int c0 = (int)((i & 31) * 4);
    float4 v = x[i];
    double r0 = (double)v.x * ss[c0 + 0] + ss[128 + c0 + 0];
    double r1 = (double)v.y * ss[c0 + 1] + ss[128 + c0 + 1];
    double r2 = (double)v.z * ss[c0 + 2] + ss[128 + c0 + 2];
    double r3 = (double)v.w * ss[c0 + 3] + ss[128 + c0 + 3];
    r0 = r0 > 0.0 ? r0 : 0.0; r1 = r1 > 0.0 ? r1 : 0.0;
    r2 = r2 > 0.0 ? r2 : 0.0; r3 = r3 > 0.0 ? r3 : 0.0;
    out[i] = make_float4((float)r0, (float)r1, (float)r2, (float)r3);
  }
}

__global__ void wnorm_k(const float* __restrict__ w, double* __restrict__ wn) {
  __shared__ double red[128];
  int c = threadIdx.x;
  double v = (double)w[c];
  red[c] = v * v;
  __syncthreads();
  for (int s = 64; s > 0; s >>= 1) { if (c < s) red[c] += red[c + s]; __syncthreads(); }
  if (c == 0) wn[0] = sqrt(red[0]);
}

__global__ __launch_bounds__(256) void score_key_k(const float* __restrict__ x,
    const float* __restrict__ w, const double* __restrict__ wn,
    ull* __restrict__ keys, int n) {
  __shared__ double red[256];
  int c = threadIdx.x & 127;
  int node = blockIdx.x * 2 + (threadIdx.x >> 7);
  double p = 0.0;
  if (node < n) p = (double)x[(size_t)node * 128 + c] * (double)w[c];
  red[threadIdx.x] = p;
  __syncthreads();
  for (int s = 64; s > 0; s >>= 1) {
    if (c < s) red[threadIdx.x] += red[threadIdx.x + s];
    __syncthreads();
  }
  if (c == 0 && node < n) {
    double sc = tanh(red[threadIdx.x] / wn[0]);
    ull u = (ull)__double_as_longlong(sc);
    u = (u >> 63) ? ~u : (u | 0x8000000000000000ULL);
    keys[node] = u;
  }
}

// zero 4*RB hist bins + init sel (k). 1024 blocks x 256 threads.
__global__ void rs_init(int* __restrict__ hist, Sel* sel, int k) {
  int i = blockIdx.x * 256 + threadIdx.x;
  if (i < 4 * RB) hist[i] = 0;
  if (i == 0) { sel->prefix = 0ULL; sel->remaining = k; }
}

// 16-bit radix hist: global atomics into RB bins.
__global__ void rs_hist16(const ull* __restrict__ keys, int n,
                          const Sel* __restrict__ sel, int shift, int pass,
                          int* __restrict__ hist) {
  int i = blockIdx.x * 256 + threadIdx.x;
  if (i < n) {
    ull k = keys[i];
    bool ok = (pass == 0) || (((k ^ sel->prefix) >> (shift + 16)) == 0);
    if (ok) atomicAdd(&hist[(int)((k >> shift) & 65535)], 1);
  }
}

// pick boundary digit among RB bins; 1 block x 1024 threads.
__global__ __launch_bounds__(1024) void rs_pick16(const int* __restrict__ hist,
                                                  Sel* sel, int shift) {
  __shared__ int ls[1024];
  int t = threadIdx.x;
  int base = t * 64;
  int own = 0;
  for (int b = 0; b < 64; ++b) own += hist[base + b];
  ls[t] = own;
  __syncthreads();
  // suffix-inclusive sum: ls[t] = sum_{t' >= t} own_{t'}
  for (int d = 1; d < 1024; d <<= 1) {
    int v = (t + d < 1024) ? ls[t + d] : 0;
    __syncthreads();
    ls[t] += v;
    __syncthreads();
  }
  int rem = sel->remaining;
  int St = ls[t];
  int Snext = St - own;  // count of keys with digit >= (t+1)*64
  if (Snext < rem && rem <= St) {  // exactly one thread
    int cum = Snext;
    for (int b = 63; b >= 0; --b) {
      int c = hist[base + b];
      if (cum + c >= rem) {
        sel->prefix |= ((ull)(base + b)) << shift;
        sel->remaining = rem - cum;
        break;
      }
      cum += c;
    }
  }
}

__global__ void gather_rows4(const float4* __restrict__ xs, const int* __restrict__ idx,
                             float4* __restrict__ xo, int k) {
  int i = blockIdx.x * 256 + threadIdx.x;
  if (i < k * 32) xo[i] = xs[(size_t)idx[i >> 5] * 32 + (i & 31)];
}

__global__ void scatter_add_rows4(float4* __restrict__ h, const float4* __restrict__ t,
                                  const int* __restrict__ idx, int k) {
  int i = blockIdx.x * 256 + threadIdx.x;
  if (i < k * 32) {
    float4 a = h[(size_t)idx[i >> 5] * 32 + (i & 31)];
    float4 b = t[i];
    a.x += b.x; a.y += b.y; a.z += b.z; a.w += b.w;
    h[(size_t)idx[i >> 5] * 32 + (i & 31)] = a;
  }
}

// ---------------- host ----------------

extern "C" void kernel_launch(void* const* d_in, const int* in_sizes, int n_in,
                              void* d_out, int out_size, void* d_ws, size_t ws_size,
                              hipStream_t stream) {
  (void)in_sizes; (void)out_size;
  if (n_in < 17) return;
  const float* x_in   = (const float*)d_in[0];
  const int*   ei     = (const int*)  d_in[1];
  const float* in_W   = (const float*)d_in[2];
  const float* in_b   = (const float*)d_in[3];
  const float* dn_W   = (const float*)d_in[4];
  const float* dn_b   = (const float*)d_in[5];
  const float* dn_g   = (const float*)d_in[6];
  const float* dn_bt  = (const float*)d_in[7];
  const float* pool_w = (const float*)d_in[8];
  const float* bot_W  = (const float*)d_in[9];
  const float* bot_b  = (const float*)d_in[10];
  const float* up_W   = (const float*)d_in[11];
  const float* up_b   = (const float*)d_in[12];
  const float* up_g   = (const float*)d_in[13];
  const float* up_bt  = (const float*)d_in[14];
  const float* out_W  = (const float*)d_in[15];
  const float* out_b  = (const float*)d_in[16];
  float* outp = (float*)d_out;

  char* base = (char*)d_ws;
  size_t off = 0;
  auto alloc = [&](size_t b) -> void* {
    void* r = base + off;
    off = (off + b + 255) & ~(size_t)255;
    return r;
  };
  float* bufA = (float*)alloc((size_t)N0_ * 128 * 4);
  float* bufB = (float*)alloc((size_t)N0_ * 128 * 4);
  float* xs0f = (float*)alloc((size_t)N0_ * 128 * 4);
  float* xs1f = (float*)alloc((size_t)N1_ * 128 * 4);
  float* xs2f = (float*)alloc((size_t)N2_ * 128 * 4);

  int* csrs0 = (int*)alloc((size_t)EDG * 4);
  int* csrs1 = (int*)alloc((size_t)CAP1 * 4);
  int* csrs2 = (int*)alloc((size_t)CAP2 * 4);
  int* csrs3 = (int*)alloc((size_t)CAP3 * 4);
  float* csrw0 = (float*)alloc((size_t)EDG * 4);
  float* csrw1 = (float*)alloc((size_t)CAP1 * 4);
  float* csrw2 = (float*)alloc((size_t)CAP2 * 4);
  float* csrw3 = (float*)alloc((size_t)CAP3 * 4);
  int* csro0 = (int*)alloc((size_t)(N0_ + 1) * 4);
  int* csro1 = (int*)alloc((size_t)(N1_ + 1) * 4);
  int* csro2 = (int*)alloc((size_t)(N2_ + 1) * 4);
  int* csro3 = (int*)alloc((size_t)(N3_ + 1) * 4);
  double* dinv0 = (double*)alloc((size_t)N0_ * 8); double* dgi0 = (double*)alloc((size_t)N0_ * 8);
  double* dinv1 = (double*)alloc((size_t)N1_ * 8); double* dgi1 = (double*)alloc((size_t)N1_ * 8);
  double* dinv2 = (double*)alloc((size_t)N2_ * 8); double* dgi2 = (double*)alloc((size_t)N2_ * 8);
  double* dinv3 = (double*)alloc((size_t)N3_ * 8); double* dgi3 = (double*)alloc((size_t)N3_ * 8);
  ull* keys = (ull*)alloc((size_t)N0_ * 8);
  int* eqpre = (int*)alloc((size_t)(N0_ + 1) * 4);
  int* knid  = (int*)alloc((size_t)N0_ * 4);
  int* degcnt = (int*)alloc((size_t)N0_ * 4);
  int* cursor = (int*)alloc((size_t)N0_ * 4);
  int* idx0 = (int*)alloc((size_t)N1_ * 4);
  int* idx1 = (int*)alloc((size_t)N2_ * 4);
  int* idx2 = (int*)alloc((size_t)N3_ * 4);
  int* hist = (int*)alloc((size_t)4 * RB * 4);     // 1 MB: 4 passes x 64K bins
  Sel* sel  = (Sel*)alloc(256);
  int* bscan = (int*)alloc(256 * 4);
  double* bns = (double*)alloc((size_t)256 * 256 * 8);
  double* ssb = (double*)alloc(256 * 8);
  double* wn  = (double*)alloc(256);
  if (off > ws_size) {
    sentinel_k<<<1, 64, 0, stream>>>(outp, (float)ws_size);
    return;
  }

  const int nL[4]   = {N0_, N1_, N2_, N3_};
  int* csrsL[4] = {csrs0, csrs1, csrs2, csrs3};
  float* csrwL[4] = {csrw0, csrw1, csrw2, csrw3};
  int* csroL[4] = {csro0, csro1, csro2, csro3};
  double* dinvL[4] = {dinv0, dinv1, dinv2, dinv3};
  double* dgiL[4]  = {dgi0, dgi1, dgi2, dgi3};
  int* idxL[3] = {idx0, idx1, idx2};

  auto cdiv = [](int a, int b) { return (a + b - 1) / b; };

  auto scan = [&](const int* in, int* out, int n) {
    int nb = cdiv(n, 1024);
    scan_part<<<nb, 256, 0, stream>>>(in, bscan, n);
    scan_bsum<<<1, 256, 0, stream>>>(bscan, nb);
    scan_out<<<nb, 256, 0, stream>>>(in, bscan, out, n, nb);
  };

  // BN: stats -> final -> apply(out). out==xp for in-place, or snap dest.
  auto bn_f = [&](float* xp, int n, const float* g, const float* b, float* outb) {
    bn_stats<float><<<256, 256, 0, stream>>>(xp, n, bns);
    bn_final<<<1, 128, 0, stream>>>(bns, g, b, 1.0 / (double)n, ssb);
    bn_apply_relu4<<<cdiv(n * 32, 256), 256, 0, stream>>>(
        (const float4*)xp, ssb, (float4*)outb, (size_t)n * 32);
  };

  // pool level i: top-k on xcur (16-bit radix, flag-fused scans); gather kept
  // rows into xnext; build level i+1 CSR directly from level-i CSR.
  auto pool = [&](int i, const float* xcur, float* xnext) {
    int n = nL[i], k = nL[i + 1];
    int nb = cdiv(n, 1024);
    wnorm_k<<<1, 128, 0, stream>>>(pool_w + i * 128, wn);
    score_key_k<<<cdiv(n, 2), 256, 0, stream>>>(xcur, pool_w + i * 128, wn, keys, n);
    rs_init<<<1024, 256, 0, stream>>>(hist, sel, k);
    for (int p = 0; p < 4; ++p) {
      int shift = 48 - 16 * p;
      rs_hist16<<<cdiv(n, 256), 256, 0, stream>>>(keys, n, sel, shift, p, hist + p * RB);
      rs_pick16<<<1, 1024, 0, stream>>>(hist + p * RB, sel, shift);
    }
    // eq-prefix scan (flags computed on the fly)
    fscan_part<1><<<nb, 256, 0, stream>>>(keys, nullptr, sel, bscan, n);
    scan_bsum<<<1, 256, 0, stream>>>(bscan, nb);
    fscan_out1<<<nb, 256, 0, stream>>>(keys, sel, bscan, eqpre, n);
    // kept scan + build_idx fused
    fscan_part<2><<<nb, 256, 0, stream>>>(keys, eqpre, sel, bscan, n);
    scan_bsum<<<1, 256, 0, stream>>>(bscan, nb);
    fscan_out2<<<nb, 256, 0, stream>>>(keys, eqpre, sel, bscan, knid, idxL[i], n);
    gather_rows4<<<cdiv(k * 32, 256), 256, 0, stream>>>(
        (const float4*)xcur, idxL[i], (float4*)xnext, k);
    // next-level CSR: deg+dinv/dgi -> offsets -> fill
    next_deg_fin<<<cdiv(n, 256), 256, 0, stream>>>(csroL[i], csrsL[i], knid, degcnt,
                                                   dinvL[i + 1], dgiL[i + 1], n);
    scan(degcnt, csroL[i + 1], k);
    next_fill<<<cdiv(n, 256), 256, 0, stream>>>(csroL[i], csrsL[i], knid,
        csroL[i + 1], dinvL[i + 1], csrsL[i + 1], csrwL[i + 1], n);
  };

  // ---- level 0 CSR (from raw edge list) ----
  hipMemsetAsync(degcnt, 0, (size_t)N0_ * 4, stream);
  count_deg<<<cdiv(EDG, 256), 256, 0, stream>>>(ei + EDG, EDG, degcnt);
  fin_deg<<<cdiv(N0_, 256), 256, 0, stream>>>(degcnt, dinv0, dgi0, N0_);
  scan(degcnt, csro0, N0_);
  hipMemsetAsync(cursor, 0, (size_t)N0_ * 4, stream);
  csr_fill<<<cdiv(EDG, 256), 256, 0, stream>>>(ei, ei + EDG, EDG, csro0, cursor,
                                               csrs0, csrw0, dinv0);

  // ---- initial conv (agg-first: agg(x W)+b = (agg x) W + b) ----
  agg_conv<false><<<cdiv(N0_, 4), 256, 0, stream>>>(
      x_in, csro0, csrs0, csrw0, dinv0, dgi0, nullptr, bufB, N0_);
  matmul128<float, float, double><<<cdiv(N0_, 64), 256, 0, stream>>>(bufB, in_W, in_b, bufA, N0_);

  // ---- down level 0: x in A, h in B, y back to A; bn -> xs0f; x1 -> B ----
  matmul128<float, float, double><<<cdiv(N0_, 64), 256, 0, stream>>>(bufA, dn_W, nullptr, bufB, N0_);
  agg_conv<false><<<cdiv(N0_, 4), 256, 0, stream>>>(
      bufB, csro0, csrs0, csrw0, dinv0, dgi0, dn_b, bufA, N0_);
  bn_f(bufA, N0_, dn_g, dn_bt, xs0f);
  pool(0, xs0f, bufB);

  // ---- down level 1: x in B, h in A, y back to B; bn -> xs1f; x2 -> A ----
  matmul128<float, float, double><<<cdiv(N1_, 64), 256, 0, stream>>>(bufB, dn_W + 16384, nullptr, bufA, N1_);
  agg_conv<false><<<cdiv(N1_, 4), 256, 0, stream>>>(
      bufA, csro1, csrs1, csrw1, dinv1, dgi1, dn_b + 128, bufB, N1_);
  bn_f(bufB, N1_, dn_g + 128, dn_bt + 128, xs1f);
  pool(1, xs1f, bufA);

  // ---- down level 2: x in A, h in B, y back to A; bn -> xs2f; x3 -> B ----
  matmul128<float, float, double><<<cdiv(N2_, 64), 256, 0, stream>>>(bufA, dn_W + 32768, nullptr, bufB, N2_);
  agg_conv<false><<<cdiv(N2_, 4), 256, 0, stream>>>(
      bufB, csro2, csrs2, csrw2, dinv2, dgi2, dn_b + 256, bufA, N2_);
  bn_f(bufA, N2_, dn_g + 256, dn_bt + 256, xs2f);
  pool(2, xs2f, bufB);

  // ---- bottom: x3 in B, h3 -> A, z3 (relu) -> B ----
  matmul128<float, float, double><<<cdiv(N3_, 64), 256, 0, stream>>>(bufB, bot_W, nullptr, bufA, N3_);
  float* zf = bufB;
  float* hf = bufA;
  float* tf = outp;  // d_out as scratch until final write (fully overwritten)
  agg_conv<true><<<cdiv(N3_, 4), 256, 0, stream>>>(
      bufA, csro3, csrs3, csrw3, dinv3, dgi3, bot_b, zf, N3_);

  // ---- up path: z in B, hf in A ----
  for (int u = 0; u < 3; ++u) {
    int l = 2 - u;
    int nl = nL[l], nz = nL[l + 1];
    const float* Wt = up_W + u * 32768;
    const float* Wb = up_W + u * 32768 + 16384;
    const float* xsf = (u == 0) ? xs2f : (u == 1) ? xs1f : xs0f;
    matmul128<float, float, float><<<cdiv(nz, 64), 256, 0, stream>>>(zf, Wt, nullptr, tf, nz);
    matmul128<float, float, float><<<cdiv(nl, 64), 256, 0, stream>>>(xsf, Wb, nullptr, hf, nl);
    scatter_add_rows4<<<cdiv(nz * 32, 256), 256, 0, stream>>>(
        (float4*)hf, (const float4*)tf, idxL[l], nz);
    agg_conv<false><<<cdiv(nl, 4), 256, 0, stream>>>(
        hf, csroL[l], csrsL[l], csrwL[l], dinvL[l], dgiL[l], up_b + u * 128, zf, nl);
    bn_f(zf, nl, up_g + u * 128, up_bt + u * 128, zf);
  }

  // ---- final conv -> d_out ----
  matmul128<float, float, float><<<cdiv(N0_, 64), 256, 0, stream>>>(zf, out_W, nullptr, hf, N0_);
  agg_conv<false><<<cdiv(N0_, 4), 256, 0, stream>>>(
      hf, csro0, csrs0, csrw0, dinv0, dgi0, out_b, outp, N0_);
}

// Round 9
// 2453.206 us; speedup vs baseline: 1.6384x; 1.0456x over previous
//
#include <hip/hip_runtime.h>

typedef unsigned long long ull;

#define N0_ 100000
#define N1_ 50000
#define N2_ 25000
#define N3_ 12500
#define EDG 1600000
#define CAP1 600000
#define CAP2 200000
#define CAP3 80000
#define RB 65536

struct Sel { ull prefix; int remaining; };

// ---------------- kernels ----------------

__global__ void sentinel_k(float* o, float v) { if (threadIdx.x == 0) o[0] = v; }

// C[n,128] = A[n,128] @ W[128,128] (+bias), ACC-typed accumulate. 64 rows/block.
template <typename TA, typename TC, typename ACC>
__global__ __launch_bounds__(256) void matmul128(const TA* __restrict__ A,
    const float* __restrict__ W, const float* __restrict__ bias,
    TC* __restrict__ C, int n) {
  __shared__ float Al[64 * 33];
  __shared__ float Wl[32 * 128];
  int tid = threadIdx.x;
  int colb = tid & 31;
  int rg = tid >> 5;
  int row0 = blockIdx.x * 64;
  ACC acc[8][4];
#pragma unroll
  for (int r = 0; r < 8; ++r)
#pragma unroll
    for (int j = 0; j < 4; ++j) acc[r][j] = (ACC)0;
  for (int kt = 0; kt < 128; kt += 32) {
    for (int i = tid; i < 64 * 32; i += 256) {
      int r = i >> 5, kk = i & 31;
      int row = row0 + r;
      Al[r * 33 + kk] = (row < n) ? (float)A[(size_t)row * 128 + kt + kk] : 0.0f;
    }
    for (int i = tid; i < 32 * 128; i += 256) {
      int kk = i >> 7, c = i & 127;
      Wl[i] = W[(size_t)(kt + kk) * 128 + c];
    }
    __syncthreads();
#pragma unroll 4
    for (int kk = 0; kk < 32; ++kk) {
      ACC b0 = (ACC)Wl[kk * 128 + colb];
      ACC b1 = (ACC)Wl[kk * 128 + colb + 32];
      ACC b2 = (ACC)Wl[kk * 128 + colb + 64];
      ACC b3 = (ACC)Wl[kk * 128 + colb + 96];
#pragma unroll
      for (int r = 0; r < 8; ++r) {
        ACC a = (ACC)Al[(rg * 8 + r) * 33 + kk];
        acc[r][0] += a * b0; acc[r][1] += a * b1;
        acc[r][2] += a * b2; acc[r][3] += a * b3;
      }
    }
    __syncthreads();
  }
  ACC bb0 = 0, bb1 = 0, bb2 = 0, bb3 = 0;
  if (bias) {
    bb0 = (ACC)bias[colb]; bb1 = (ACC)bias[colb + 32];
    bb2 = (ACC)bias[colb + 64]; bb3 = (ACC)bias[colb + 96];
  }
  for (int r = 0; r < 8; ++r) {
    int row = row0 + rg * 8 + r;
    if (row < n) {
      size_t o = (size_t)row * 128 + colb;
      C[o] = (TC)(acc[r][0] + bb0); C[o + 32] = (TC)(acc[r][1] + bb1);
      C[o + 64] = (TC)(acc[r][2] + bb2); C[o + 96] = (TC)(acc[r][3] + bb3);
    }
  }
}

// matmul with scatter-add output: C[idx[row]] += A[row] @ W (fp32).
// Bit-identical to matmul->tmp->scatter_add (one add per element, same order).
__global__ __launch_bounds__(256) void matmul128_sadd(const float* __restrict__ A,
    const float* __restrict__ W, const int* __restrict__ idx,
    float* __restrict__ C, int n) {
  __shared__ float Al[64 * 33];
  __shared__ float Wl[32 * 128];
  int tid = threadIdx.x;
  int colb = tid & 31;
  int rg = tid >> 5;
  int row0 = blockIdx.x * 64;
  float acc[8][4];
#pragma unroll
  for (int r = 0; r < 8; ++r)
#pragma unroll
    for (int j = 0; j < 4; ++j) acc[r][j] = 0.0f;
  for (int kt = 0; kt < 128; kt += 32) {
    for (int i = tid; i < 64 * 32; i += 256) {
      int r = i >> 5, kk = i & 31;
      int row = row0 + r;
      Al[r * 33 + kk] = (row < n) ? A[(size_t)row * 128 + kt + kk] : 0.0f;
    }
    for (int i = tid; i < 32 * 128; i += 256) {
      int kk = i >> 7, c = i & 127;
      Wl[i] = W[(size_t)(kt + kk) * 128 + c];
    }
    __syncthreads();
#pragma unroll 4
    for (int kk = 0; kk < 32; ++kk) {
      float b0 = Wl[kk * 128 + colb];
      float b1 = Wl[kk * 128 + colb + 32];
      float b2 = Wl[kk * 128 + colb + 64];
      float b3 = Wl[kk * 128 + colb + 96];
#pragma unroll
      for (int r = 0; r < 8; ++r) {
        float a = Al[(rg * 8 + r) * 33 + kk];
        acc[r][0] += a * b0; acc[r][1] += a * b1;
        acc[r][2] += a * b2; acc[r][3] += a * b3;
      }
    }
    __syncthreads();
  }
  for (int r = 0; r < 8; ++r) {
    int row = row0 + rg * 8 + r;
    if (row < n) {
      size_t o = (size_t)idx[row] * 128 + colb;
      C[o] += acc[r][0]; C[o + 32] += acc[r][1];
      C[o + 64] += acc[r][2]; C[o + 96] += acc[r][3];
    }
  }
}

// Full-wave float4 agg: 1 wave per node; lanes 0-31 even edges, 32-63 odd.
template <bool RELU>
__global__ __launch_bounds__(256) void agg_conv(const float* __restrict__ hp,
    const int* __restrict__ off, const int* __restrict__ csrc,
    const float* __restrict__ csrw,
    const double* __restrict__ dinv, const double* __restrict__ dgi,
    const float* __restrict__ bias, float* __restrict__ yp, int n) {
  const float4* __restrict__ h = (const float4*)hp;
  float4* __restrict__ y = (float4*)yp;
  int lane = threadIdx.x & 63;
  int c4 = lane & 31;
  int half = lane >> 5;
  int node = blockIdx.x * 4 + (threadIdx.x >> 6);
  if (node >= n) return;
  double di = dinv[node];
  double dg = dgi[node];
  double aX = 0, aY = 0, aZ = 0, aW = 0;
  int p0 = off[node], p1 = off[node + 1];
  int m = p1 - p0;
  int npair = m >> 1;
  int j = 0;
  for (; j + 8 <= npair; j += 8) {
    int e0 = p0 + 2 * j + half;
    int s0 = csrc[e0],      s1 = csrc[e0 + 2],  s2 = csrc[e0 + 4],  s3 = csrc[e0 + 6];
    int s4 = csrc[e0 + 8],  s5 = csrc[e0 + 10], s6 = csrc[e0 + 12], s7 = csrc[e0 + 14];
    double w0 = (double)csrw[e0],      w1 = (double)csrw[e0 + 2];
    double w2 = (double)csrw[e0 + 4],  w3 = (double)csrw[e0 + 6];
    double w4 = (double)csrw[e0 + 8],  w5 = (double)csrw[e0 + 10];
    double w6 = (double)csrw[e0 + 12], w7 = (double)csrw[e0 + 14];
    float4 v0 = h[(size_t)s0 * 32 + c4];
    float4 v1 = h[(size_t)s1 * 32 + c4];
    float4 v2 = h[(size_t)s2 * 32 + c4];
    float4 v3 = h[(size_t)s3 * 32 + c4];
    float4 v4 = h[(size_t)s4 * 32 + c4];
    float4 v5 = h[(size_t)s5 * 32 + c4];
    float4 v6 = h[(size_t)s6 * 32 + c4];
    float4 v7 = h[(size_t)s7 * 32 + c4];
    aX += (double)v0.x * w0; aY += (double)v0.y * w0;
    aZ += (double)v0.z * w0; aW += (double)v0.w * w0;
    aX += (double)v1.x * w1; aY += (double)v1.y * w1;
    aZ += (double)v1.z * w1; aW += (double)v1.w * w1;
    aX += (double)v2.x * w2; aY += (double)v2.y * w2;
    aZ += (double)v2.z * w2; aW += (double)v2.w * w2;
    aX += (double)v3.x * w3; aY += (double)v3.y * w3;
    aZ += (double)v3.z * w3; aW += (double)v3.w * w3;
    aX += (double)v4.x * w4; aY += (double)v4.y * w4;
    aZ += (double)v4.z * w4; aW += (double)v4.w * w4;
    aX += (double)v5.x * w5; aY += (double)v5.y * w5;
    aZ += (double)v5.z * w5; aW += (double)v5.w * w5;
    aX += (double)v6.x * w6; aY += (double)v6.y * w6;
    aZ += (double)v6.z * w6; aW += (double)v6.w * w6;
    aX += (double)v7.x * w7; aY += (double)v7.y * w7;
    aZ += (double)v7.z * w7; aW += (double)v7.w * w7;
  }
  for (; j + 4 <= npair; j += 4) {
    int e0 = p0 + 2 * j + half;
    int s0 = csrc[e0], s1 = csrc[e0 + 2], s2 = csrc[e0 + 4], s3 = csrc[e0 + 6];
    double w0 = (double)csrw[e0],     w1 = (double)csrw[e0 + 2];
    double w2 = (double)csrw[e0 + 4], w3 = (double)csrw[e0 + 6];
    float4 v0 = h[(size_t)s0 * 32 + c4];
    float4 v1 = h[(size_t)s1 * 32 + c4];
    float4 v2 = h[(size_t)s2 * 32 + c4];
    float4 v3 = h[(size_t)s3 * 32 + c4];
    aX += (double)v0.x * w0; aY += (double)v0.y * w0;
    aZ += (double)v0.z * w0; aW += (double)v0.w * w0;
    aX += (double)v1.x * w1; aY += (double)v1.y * w1;
    aZ += (double)v1.z * w1; aW += (double)v1.w * w1;
    aX += (double)v2.x * w2; aY += (double)v2.y * w2;
    aZ += (double)v2.z * w2; aW += (double)v2.w * w2;
    aX += (double)v3.x * w3; aY += (double)v3.y * w3;
    aZ += (double)v3.z * w3; aW += (double)v3.w * w3;
  }
  for (; j < npair; ++j) {
    int e = p0 + 2 * j + half;
    double w = (double)csrw[e];
    float4 v = h[(size_t)csrc[e] * 32 + c4];
    aX += (double)v.x * w; aY += (double)v.y * w;
    aZ += (double)v.z * w; aW += (double)v.w * w;
  }
  if ((m & 1) && half == 0) {
    int e = p1 - 1;
    double w = (double)csrw[e];
    float4 v = h[(size_t)csrc[e] * 32 + c4];
    aX += (double)v.x * w; aY += (double)v.y * w;
    aZ += (double)v.z * w; aW += (double)v.w * w;
  }
  double sX = aX + __shfl_xor(aX, 32);
  double sY = aY + __shfl_xor(aY, 32);
  double sZ = aZ + __shfl_xor(aZ, 32);
  double sW = aW + __shfl_xor(aW, 32);
  if (half == 0) {
    float4 hv = h[(size_t)node * 32 + c4];
    double bx = 0, by = 0, bz = 0, bw = 0;
    if (bias) {
      bx = (double)bias[c4 * 4 + 0]; by = (double)bias[c4 * 4 + 1];
      bz = (double)bias[c4 * 4 + 2]; bw = (double)bias[c4 * 4 + 3];
    }
    double rx = sX * di + (double)hv.x * dg + bx;
    double ry = sY * di + (double)hv.y * dg + by;
    double rz = sZ * di + (double)hv.z * dg + bz;
    double rw = sW * di + (double)hv.w * dg + bw;
    if (RELU) {
      rx = rx > 0.0 ? rx : 0.0; ry = ry > 0.0 ? ry : 0.0;
      rz = rz > 0.0 ? rz : 0.0; rw = rw > 0.0 ? rw : 0.0;
    }
    y[(size_t)node * 32 + c4] = make_float4((float)rx, (float)ry, (float)rz, (float)rw);
  }
}

// level-0 CSR build only
__global__ void count_deg(const int* __restrict__ dst, int m, int* __restrict__ cnt) {
  int e = blockIdx.x * 256 + threadIdx.x;
  if (e < m) atomicAdd(&cnt[dst[e]], 1);
}

__global__ void fin_deg(const int* __restrict__ cnt, double* __restrict__ dinv,
                        double* __restrict__ dgi, int n) {
  int i = blockIdx.x * 256 + threadIdx.x;
  if (i < n) {
    double d = 1.0 + (double)cnt[i];
    dinv[i] = 1.0 / sqrt(d);
    dgi[i] = 1.0 / d;
  }
}

// ---- deterministic 3-phase multi-block exclusive scan (int input) ----
__global__ __launch_bounds__(256) void scan_part(const int* __restrict__ in,
                                                 int* __restrict__ bsum, int n) {
  __shared__ int ts[256];
  int base = blockIdx.x * 1024 + threadIdx.x * 4;
  int s = 0;
#pragma unroll
  for (int j = 0; j < 4; ++j) { int i = base + j; if (i < n) s += in[i]; }
  ts[threadIdx.x] = s;
  __syncthreads();
  for (int d = 128; d > 0; d >>= 1) {
    if (threadIdx.x < d) ts[threadIdx.x] += ts[threadIdx.x + d];
    __syncthreads();
  }
  if (threadIdx.x == 0) bsum[blockIdx.x] = ts[0];
}

__global__ __launch_bounds__(256) void scan_bsum(int* __restrict__ bsum, int nb) {
  __shared__ int ls[256];
  int t = threadIdx.x;
  int v = (t < nb) ? bsum[t] : 0;
  ls[t] = v;
  __syncthreads();
  for (int d = 1; d < 256; d <<= 1) {
    int u = (t >= d) ? ls[t - d] : 0;
    __syncthreads();
    ls[t] += u;
    __syncthreads();
  }
  if (t < nb) bsum[t] = ls[t] - v;
}

__global__ __launch_bounds__(256) void scan_out(const int* __restrict__ in,
    const int* __restrict__ bsum, int* __restrict__ out, int n, int nb) {
  __shared__ int ts[256];
  int base = blockIdx.x * 1024 + threadIdx.x * 4;
  int loc[4];
  int s = 0;
#pragma unroll
  for (int j = 0; j < 4; ++j) {
    int i = base + j;
    int v = (i < n) ? in[i] : 0;
    loc[j] = s; s += v;
  }
  ts[threadIdx.x] = s;
  __syncthreads();
  int mine = s;
  for (int d = 1; d < 256; d <<= 1) {
    int u = (threadIdx.x >= d) ? ts[threadIdx.x - d] : 0;
    __syncthreads();
    ts[threadIdx.x] += u;
    __syncthreads();
  }
  int toff = bsum[blockIdx.x] + ts[threadIdx.x] - mine;
#pragma unroll
  for (int j = 0; j < 4; ++j) {
    int i = base + j;
    if (i < n) out[i] = toff + loc[j];
  }
  if (blockIdx.x == nb - 1 && threadIdx.x == 255) out[n] = bsum[blockIdx.x] + ts[255];
}

// ---- dual-scan top-k select: one 3-phase scan carrying (gt, eq) counts ----
// kept(i) = u>pref || (u==pref && eqpre_i < rem); knid = gtpre + min(eqpre, rem)
__global__ __launch_bounds__(256) void dsel_part(const ull* __restrict__ keys,
    const Sel* __restrict__ sel, int2* __restrict__ bsum, int n) {
  __shared__ int tg[256], te[256];
  ull pref = sel->prefix;
  int base = blockIdx.x * 1024 + threadIdx.x * 4;
  int g = 0, e = 0;
#pragma unroll
  for (int j = 0; j < 4; ++j) {
    int i = base + j;
    if (i < n) {
      ull u = keys[i];
      g += (u > pref) ? 1 : 0;
      e += (u == pref) ? 1 : 0;
    }
  }
  tg[threadIdx.x] = g; te[threadIdx.x] = e;
  __syncthreads();
  for (int d = 128; d > 0; d >>= 1) {
    if (threadIdx.x < d) { tg[threadIdx.x] += tg[threadIdx.x + d]; te[threadIdx.x] += te[threadIdx.x + d]; }
    __syncthreads();
  }
  if (threadIdx.x == 0) bsum[blockIdx.x] = make_int2(tg[0], te[0]);
}

__global__ __launch_bounds__(256) void dsel_mid(int2* __restrict__ bsum, int nb) {
  __shared__ int lg[256], le[256];
  int t = threadIdx.x;
  int2 v = (t < nb) ? bsum[t] : make_int2(0, 0);
  lg[t] = v.x; le[t] = v.y;
  __syncthreads();
  for (int d = 1; d < 256; d <<= 1) {
    int u1 = (t >= d) ? lg[t - d] : 0;
    int u2 = (t >= d) ? le[t - d] : 0;
    __syncthreads();
    lg[t] += u1; le[t] += u2;
    __syncthreads();
  }
  if (t < nb) bsum[t] = make_int2(lg[t] - v.x, le[t] - v.y);
}

__global__ __launch_bounds__(256) void dsel_out(const ull* __restrict__ keys,
    const Sel* __restrict__ sel, const int2* __restrict__ bsum,
    int* __restrict__ knid, int* __restrict__ idx, int n) {
  __shared__ int tg[256], te[256];
  ull pref = sel->prefix;
  int rem = sel->remaining;
  int base = blockIdx.x * 1024 + threadIdx.x * 4;
  int gflg[4], eflg[4], gloc[4], eloc[4];
  int g = 0, e = 0;
#pragma unroll
  for (int j = 0; j < 4; ++j) {
    int i = base + j;
    int gf = 0, ef = 0;
    if (i < n) {
      ull u = keys[i];
      gf = (u > pref) ? 1 : 0;
      ef = (u == pref) ? 1 : 0;
    }
    gflg[j] = gf; eflg[j] = ef; gloc[j] = g; eloc[j] = e;
    g += gf; e += ef;
  }
  tg[threadIdx.x] = g; te[threadIdx.x] = e;
  __syncthreads();
  int gm = g, em = e;
  for (int d = 1; d < 256; d <<= 1) {
    int u1 = (threadIdx.x >= d) ? tg[threadIdx.x - d] : 0;
    int u2 = (threadIdx.x >= d) ? te[threadIdx.x - d] : 0;
    __syncthreads();
    tg[threadIdx.x] += u1; te[threadIdx.x] += u2;
    __syncthreads();
  }
  int2 bo = bsum[blockIdx.x];
  int goff = bo.x + tg[threadIdx.x] - gm;
  int eoff = bo.y + te[threadIdx.x] - em;
#pragma unroll
  for (int j = 0; j < 4; ++j) {
    int i = base + j;
    if (i < n) {
      int gp = goff + gloc[j];
      int ep = eoff + eloc[j];
      if (gflg[j] || (eflg[j] && ep < rem)) {
        int nid = gp + (ep < rem ? ep : rem);
        knid[i] = nid;
        idx[nid] = i;
      } else {
        knid[i] = -1;
      }
    }
  }
}

__global__ void csr_fill(const int* __restrict__ src, const int* __restrict__ dst,
                         int m, const int* __restrict__ off,
                         int* __restrict__ cursor, int* __restrict__ csrs,
                         float* __restrict__ csrw, const double* __restrict__ dinv) {
  int e = blockIdx.x * 256 + threadIdx.x;
  if (e < m) {
    int d = dst[e];
    int s = src[e];
    int pos = off[d] + atomicAdd(&cursor[d], 1);
    csrs[pos] = s;
    csrw[pos] = (float)dinv[s];
  }
}

// next_deg fused with fin_deg.
__global__ void next_deg_fin(const int* __restrict__ off, const int* __restrict__ csrs,
                             const int* __restrict__ knid, int* __restrict__ ndeg,
                             double* __restrict__ ndinv, double* __restrict__ ndgi,
                             int n) {
  int d = blockIdx.x * 256 + threadIdx.x;
  if (d >= n) return;
  int nd = knid[d];
  if (nd < 0) return;
  int cnt = 0;
  int p1 = off[d + 1];
  for (int p = off[d]; p < p1; ++p) cnt += (knid[csrs[p]] >= 0) ? 1 : 0;
  ndeg[nd] = cnt;
  double dd = 1.0 + (double)cnt;
  ndinv[nd] = 1.0 / sqrt(dd);
  ndgi[nd] = 1.0 / dd;
}

__global__ void next_fill(const int* __restrict__ off, const int* __restrict__ csrs,
                          const int* __restrict__ knid, const int* __restrict__ noff,
                          const double* __restrict__ ndinv,
                          int* __restrict__ ncsrs, float* __restrict__ ncsrw, int n) {
  int d = blockIdx.x * 256 + threadIdx.x;
  if (d >= n) return;
  int nd = knid[d];
  if (nd < 0) return;
  int pos = noff[nd];
  int p1 = off[d + 1];
  for (int p = off[d]; p < p1; ++p) {
    int s = knid[csrs[p]];
    if (s >= 0) { ncsrs[pos] = s; ncsrw[pos] = (float)ndinv[s]; ++pos; }
  }
}

// fixed grid of 256 blocks; deterministic per-block partials (no atomics).
template <typename T>
__global__ __launch_bounds__(256) void bn_stats(const T* __restrict__ x, int n,
                                                double* __restrict__ part) {
  __shared__ double lsum[256], lsq[256];
  int c = threadIdx.x & 127, half = threadIdx.x >> 7;
  double s = 0, q = 0;
  for (int row = blockIdx.x * 2 + half; row < n; row += 512) {
    double v = (double)x[(size_t)row * 128 + c];
    s += v; q += v * v;
  }
  lsum[threadIdx.x] = s; lsq[threadIdx.x] = q;
  __syncthreads();
  if (half == 0) {
    part[blockIdx.x * 256 + c] = lsum[c] + lsum[c + 128];
    part[blockIdx.x * 256 + 128 + c] = lsq[c] + lsq[c + 128];
  }
}

__global__ void bn_final(const double* __restrict__ part, const float* __restrict__ g,
                         const float* __restrict__ beta, double invn,
                         double* __restrict__ ss) {
  int c = threadIdx.x;  // 128
  double s = 0, q = 0;
  for (int b = 0; b < 256; ++b) {
    s += part[b * 256 + c];
    q += part[b * 256 + 128 + c];
  }
  double m = s * invn;
  double v = q * invn - m * m;
  double sc = (double)g[c] / sqrt(v + 1e-5);
  ss[c] = sc;
  ss[128 + c] = (double)beta[c] - m * sc;
}

// BN+ReLU float4, in place (up path).
__global__ void bn_apply_relu4(float4* __restrict__ x, const double* __restrict__ ss,
                               size_t total4) {
  size_t i = (size_t)blockIdx.x * 256 + threadIdx.x;
  if (i < total4) {
    int c0 = (int)((i & 31) * 4);
    float4 v = x[i];
    double r0 = (double)v.x * ss[c0 + 0] + ss[128 + c0 + 0];
    double r1 = (double)v.y * ss[c0 + 1] + ss[128 + c0 + 1];
    double r2 = (double)v.z * ss[c0 + 2] + ss[128 + c0 + 2];
    double r3 = (double)v.w * ss[c0 + 3] + ss[128 + c0 + 3];
    r0 = r0 > 0.0 ? r0 : 0.0; r1 = r1 > 0.0 ? r1 : 0.0;
    r2 = r2 > 0.0 ? r2 : 0.0; r3 = r3 > 0.0 ? r3 : 0.0;
    x[i] = make_float4((float)r0, (float)r1, (float)r2, (float)r3);
  }
}

// Fused (down levels): BN+ReLU -> write snap (fp32) -> top-k score keys.
// Extra 1024 blocks (blockIdx >= nodeBlocks) zero the radix hist + init sel.
// 32 lanes per node, 8 nodes per 256-block; dot in double, shfl-xor reduce.
__global__ __launch_bounds__(256) void bn_score_k(const float4* __restrict__ x,
    const double* __restrict__ ss, float4* __restrict__ snap,
    const float* __restrict__ w, ull* __restrict__ keys, int n,
    int nodeBlocks, int* __restrict__ hist, Sel* sel, int k) {
  if ((int)blockIdx.x >= nodeBlocks) {
    int i = (blockIdx.x - nodeBlocks) * 256 + threadIdx.x;
    if (i < 4 * RB) hist[i] = 0;
    if (i == 0) { sel->prefix = 0ULL; sel->remaining = k; }
    return;
  }
  __shared__ double wsh[128];
  __shared__ double wnv;
  int tid = threadIdx.x;
  if (tid < 128) wsh[tid] = (double)w[tid] * (double)w[tid];
  __syncthreads();
  for (int s = 64; s > 0; s >>= 1) {
    if (tid < s) wsh[tid] += wsh[tid + s];
    __syncthreads();
  }
  if (tid == 0) wnv = sqrt(wsh[0]);
  __syncthreads();
  int c4 = tid & 31;
  int node = blockIdx.x * 8 + (tid >> 5);
  if (node >= n) return;
  float4 v = x[(size_t)node * 32 + c4];
  int c0 = c4 * 4;
  double r0 = (double)v.x * ss[c0 + 0] + ss[128 + c0 + 0];
  double r1 = (double)v.y * ss[c0 + 1] + ss[128 + c0 + 1];
  double r2 = (double)v.z * ss[c0 + 2] + ss[128 + c0 + 2];
  double r3 = (double)v.w * ss[c0 + 3] + ss[128 + c0 + 3];
  r0 = r0 > 0.0 ? r0 : 0.0; r1 = r1 > 0.0 ? r1 : 0.0;
  r2 = r2 > 0.0 ? r2 : 0.0; r3 = r3 > 0.0 ? r3 : 0.0;
  float4 o = make_float4((float)r0, (float)r1, (float)r2, (float)r3);
  snap[(size_t)node * 32 + c4] = o;
  // score dot from the fp32-rounded snap values (matches reference semantics)
  double p = (double)o.x * (double)w[c0 + 0] + (double)o.y * (double)w[c0 + 1]
           + (double)o.z * (double)w[c0 + 2] + (double)o.w * (double)w[c0 + 3];
  p += __shfl_xor(p, 1);
  p += __shfl_xor(p, 2);
  p += __shfl_xor(p, 4);
  p += __shfl_xor(p, 8);
  p += __shfl_xor(p, 16);
  if (c4 == 0) {
    double sc = tanh(p / wnv);
    ull u = (ull)__double_as_longlong(sc);
    u = (u >> 63) ? ~u : (u | 0x8000000000000000ULL);
    keys[node] = u;
  }
}

// 16-bit radix hist: global atomics into RB bins.
__global__ void rs_hist16(const ull* __restrict__ keys, int n,
                          const Sel* __restrict__ sel, int shift, int pass,
                          int* __restrict__ hist) {
  int i = blockIdx.x * 256 + threadIdx.x;
  if (i < n) {
    ull k = keys[i];
    bool ok = (pass == 0) || (((k ^ sel->prefix) >> (shift + 16)) == 0);
    if (ok) atomicAdd(&hist[(int)((k >> shift) & 65535)], 1);
  }
}

// pick boundary digit among RB bins; 1 block x 1024 threads.
__global__ __launch_bounds__(1024) void rs_pick16(const int* __restrict__ hist,
                                                  Sel* sel, int shift) {
  __shared__ int ls[1024];
  int t = threadIdx.x;
  int base = t * 64;
  int own = 0;
  for (int b = 0; b < 64; ++b) own += hist[base + b];
  ls[t] = own;
  __syncthreads();
  for (int d = 1; d < 1024; d <<= 1) {
    int v = (t + d < 1024) ? ls[t + d] : 0;
    __syncthreads();
    ls[t] += v;
    __syncthreads();
  }
  int rem = sel->remaining;
  int St = ls[t];
  int Snext = St - own;
  if (Snext < rem && rem <= St) {
    int cum = Snext;
    for (int b = 63; b >= 0; --b) {
      int c = hist[base + b];
      if (cum + c >= rem) {
        sel->prefix |= ((ull)(base + b)) << shift;
        sel->remaining = rem - cum;
        break;
      }
      cum += c;
    }
  }
}

__global__ void gather_rows4(const float4* __restrict__ xs, const int* __restrict__ idx,
                             float4* __restrict__ xo, int k) {
  int i = blockIdx.x * 256 + threadIdx.x;
  if (i < k * 32) xo[i] = xs[(size_t)idx[i >> 5] * 32 + (i & 31)];
}

// ---------------- host ----------------

extern "C" void kernel_launch(void* const* d_in, const int* in_sizes, int n_in,
                              void* d_out, int out_size, void* d_ws, size_t ws_size,
                              hipStream_t stream) {
  (void)in_sizes; (void)out_size;
  if (n_in < 17) return;
  const float* x_in   = (const float*)d_in[0];
  const int*   ei     = (const int*)  d_in[1];
  const float* in_W   = (const float*)d_in[2];
  const float* in_b   = (const float*)d_in[3];
  const float* dn_W   = (const float*)d_in[4];
  const float* dn_b   = (const float*)d_in[5];
  const float* dn_g   = (const float*)d_in[6];
  const float* dn_bt  = (const float*)d_in[7];
  const float* pool_w = (const float*)d_in[8];
  const float* bot_W  = (const float*)d_in[9];
  const float* bot_b  = (const float*)d_in[10];
  const float* up_W   = (const float*)d_in[11];
  const float* up_b   = (const float*)d_in[12];
  const float* up_g   = (const float*)d_in[13];
  const float* up_bt  = (const float*)d_in[14];
  const float* out_W  = (const float*)d_in[15];
  const float* out_b  = (const float*)d_in[16];
  float* outp = (float*)d_out;

  char* base = (char*)d_ws;
  size_t off = 0;
  auto alloc = [&](size_t b) -> void* {
    void* r = base + off;
    off = (off + b + 255) & ~(size_t)255;
    return r;
  };
  float* bufA = (float*)alloc((size_t)N0_ * 128 * 4);
  float* bufB = (float*)alloc((size_t)N0_ * 128 * 4);
  float* xs0f = (float*)alloc((size_t)N0_ * 128 * 4);
  float* xs1f = (float*)alloc((size_t)N1_ * 128 * 4);
  float* xs2f = (float*)alloc((size_t)N2_ * 128 * 4);

  int* csrs0 = (int*)alloc((size_t)EDG * 4);
  int* csrs1 = (int*)alloc((size_t)CAP1 * 4);
  int* csrs2 = (int*)alloc((size_t)CAP2 * 4);
  int* csrs3 = (int*)alloc((size_t)CAP3 * 4);
  float* csrw0 = (float*)alloc((size_t)EDG * 4);
  float* csrw1 = (float*)alloc((size_t)CAP1 * 4);
  float* csrw2 = (float*)alloc((size_t)CAP2 * 4);
  float* csrw3 = (float*)alloc((size_t)CAP3 * 4);
  int* csro0 = (int*)alloc((size_t)(N0_ + 1) * 4);
  int* csro1 = (int*)alloc((size_t)(N1_ + 1) * 4);
  int* csro2 = (int*)alloc((size_t)(N2_ + 1) * 4);
  int* csro3 = (int*)alloc((size_t)(N3_ + 1) * 4);
  double* dinv0 = (double*)alloc((size_t)N0_ * 8); double* dgi0 = (double*)alloc((size_t)N0_ * 8);
  double* dinv1 = (double*)alloc((size_t)N1_ * 8); double* dgi1 = (double*)alloc((size_t)N1_ * 8);
  double* dinv2 = (double*)alloc((size_t)N2_ * 8); double* dgi2 = (double*)alloc((size_t)N2_ * 8);
  double* dinv3 = (double*)alloc((size_t)N3_ * 8); double* dgi3 = (double*)alloc((size_t)N3_ * 8);
  ull* keys = (ull*)alloc((size_t)N0_ * 8);
  int* knid  = (int*)alloc((size_t)N0_ * 4);
  int* degcnt = (int*)alloc((size_t)N0_ * 4);
  int* cursor = (int*)alloc((size_t)N0_ * 4);
  int* idx0 = (int*)alloc((size_t)N1_ * 4);
  int* idx1 = (int*)alloc((size_t)N2_ * 4);
  int* idx2 = (int*)alloc((size_t)N3_ * 4);
  int* hist = (int*)alloc((size_t)4 * RB * 4);     // 1 MB: 4 passes x 64K bins
  Sel* sel  = (Sel*)alloc(256);
  int* bscan = (int*)alloc(256 * 8);               // 256 int2 (dual-scan) / 256 int
  double* bns = (double*)alloc((size_t)256 * 256 * 8);
  double* ssb = (double*)alloc(256 * 8);
  if (off > ws_size) {
    sentinel_k<<<1, 64, 0, stream>>>(outp, (float)ws_size);
    return;
  }

  const int nL[4]   = {N0_, N1_, N2_, N3_};
  int* csrsL[4] = {csrs0, csrs1, csrs2, csrs3};
  float* csrwL[4] = {csrw0, csrw1, csrw2, csrw3};
  int* csroL[4] = {csro0, csro1, csro2, csro3};
  double* dinvL[4] = {dinv0, dinv1, dinv2, dinv3};
  double* dgiL[4]  = {dgi0, dgi1, dgi2, dgi3};
  int* idxL[3] = {idx0, idx1, idx2};

  auto cdiv = [](int a, int b) { return (a + b - 1) / b; };

  auto scan = [&](const int* in, int* out, int n) {
    int nb = cdiv(n, 1024);
    scan_part<<<nb, 256, 0, stream>>>(in, bscan, n);
    scan_bsum<<<1, 256, 0, stream>>>(bscan, nb);
    scan_out<<<nb, 256, 0, stream>>>(in, bscan, out, n, nb);
  };

  // down-level BN + score (fused): stats -> final -> bn_score (snap + keys +
  // hist-zero + sel-init for the upcoming pool).
  auto bn_score = [&](float* xp, int n, const float* g, const float* b,
                      float* snap, const float* pw, int k) {
    bn_stats<float><<<256, 256, 0, stream>>>(xp, n, bns);
    bn_final<<<1, 128, 0, stream>>>(bns, g, b, 1.0 / (double)n, ssb);
    int nodeBlocks = cdiv(n, 8);
    bn_score_k<<<nodeBlocks + 1024, 256, 0, stream>>>(
        (const float4*)xp, ssb, (float4*)snap, pw, keys, n, nodeBlocks, hist, sel, k);
  };

  // up-level BN (in place, no score).
  auto bn_up = [&](float* xp, int n, const float* g, const float* b) {
    bn_stats<float><<<256, 256, 0, stream>>>(xp, n, bns);
    bn_final<<<1, 128, 0, stream>>>(bns, g, b, 1.0 / (double)n, ssb);
    bn_apply_relu4<<<cdiv(n * 32, 256), 256, 0, stream>>>(
        (float4*)xp, ssb, (size_t)n * 32);
  };

  // pool level i: radix-select on keys (already built by bn_score), dual-scan
  // kept/build_idx, gather, next-level CSR build.
  auto pool = [&](int i, const float* xcur, float* xnext) {
    int n = nL[i], k = nL[i + 1];
    int nb = cdiv(n, 1024);
    for (int p = 0; p < 4; ++p) {
      int shift = 48 - 16 * p;
      rs_hist16<<<cdiv(n, 256), 256, 0, stream>>>(keys, n, sel, shift, p, hist + p * RB);
      rs_pick16<<<1, 1024, 0, stream>>>(hist + p * RB, sel, shift);
    }
    dsel_part<<<nb, 256, 0, stream>>>(keys, sel, (int2*)bscan, n);
    dsel_mid<<<1, 256, 0, stream>>>((int2*)bscan, nb);
    dsel_out<<<nb, 256, 0, stream>>>(keys, sel, (int2*)bscan, knid, idxL[i], n);
    gather_rows4<<<cdiv(k * 32, 256), 256, 0, stream>>>(
        (const float4*)xcur, idxL[i], (float4*)xnext, k);
    next_deg_fin<<<cdiv(n, 256), 256, 0, stream>>>(csroL[i], csrsL[i], knid, degcnt,
                                                   dinvL[i + 1], dgiL[i + 1], n);
    scan(degcnt, csroL[i + 1], k);
    next_fill<<<cdiv(n, 256), 256, 0, stream>>>(csroL[i], csrsL[i], knid,
        csroL[i + 1], dinvL[i + 1], csrsL[i + 1], csrwL[i + 1], n);
  };

  // ---- level 0 CSR (from raw edge list) ----
  hipMemsetAsync(degcnt, 0, (size_t)N0_ * 4, stream);
  count_deg<<<cdiv(EDG, 256), 256, 0, stream>>>(ei + EDG, EDG, degcnt);
  fin_deg<<<cdiv(N0_, 256), 256, 0, stream>>>(degcnt, dinv0, dgi0, N0_);
  scan(degcnt, csro0, N0_);
  hipMemsetAsync(cursor, 0, (size_t)N0_ * 4, stream);
  csr_fill<<<cdiv(EDG, 256), 256, 0, stream>>>(ei, ei + EDG, EDG, csro0, cursor,
                                               csrs0, csrw0, dinv0);

  // ---- initial conv (agg-first: agg(x W)+b = (agg x) W + b) ----
  agg_conv<false><<<cdiv(N0_, 4), 256, 0, stream>>>(
      x_in, csro0, csrs0, csrw0, dinv0, dgi0, nullptr, bufB, N0_);
  matmul128<float, float, double><<<cdiv(N0_, 64), 256, 0, stream>>>(bufB, in_W, in_b, bufA, N0_);

  // ---- down level 0 ----
  matmul128<float, float, double><<<cdiv(N0_, 64), 256, 0, stream>>>(bufA, dn_W, nullptr, bufB, N0_);
  agg_conv<false><<<cdiv(N0_, 4), 256, 0, stream>>>(
      bufB, csro0, csrs0, csrw0, dinv0, dgi0, dn_b, bufA, N0_);
  bn_score(bufA, N0_, dn_g, dn_bt, xs0f, pool_w, N1_);
  pool(0, xs0f, bufB);

  // ---- down level 1 ----
  matmul128<float, float, double><<<cdiv(N1_, 64), 256, 0, stream>>>(bufB, dn_W + 16384, nullptr, bufA, N1_);
  agg_conv<false><<<cdiv(N1_, 4), 256, 0, stream>>>(
      bufA, csro1, csrs1, csrw1, dinv1, dgi1, dn_b + 128, bufB, N1_);
  bn_score(bufB, N1_, dn_g + 128, dn_bt + 128, xs1f, pool_w + 128, N2_);
  pool(1, xs1f, bufA);

  // ---- down level 2 ----
  matmul128<float, float, double><<<cdiv(N2_, 64), 256, 0, stream>>>(bufA, dn_W + 32768, nullptr, bufB, N2_);
  agg_conv<false><<<cdiv(N2_, 4), 256, 0, stream>>>(
      bufB, csro2, csrs2, csrw2, dinv2, dgi2, dn_b + 256, bufA, N2_);
  bn_score(bufA, N2_, dn_g + 256, dn_bt + 256, xs2f, pool_w + 256, N3_);
  pool(2, xs2f, bufB);

  // ---- bottom: x3 in B, h3 -> A, z3 (relu) -> B ----
  matmul128<float, float, double><<<cdiv(N3_, 64), 256, 0, stream>>>(bufB, bot_W, nullptr, bufA, N3_);
  float* zf = bufB;
  float* hf = bufA;
  agg_conv<true><<<cdiv(N3_, 4), 256, 0, stream>>>(
      bufA, csro3, csrs3, csrw3, dinv3, dgi3, bot_b, zf, N3_);

  // ---- up path: z in B, hf in A; scatter-add fused into the z matmul ----
  for (int u = 0; u < 3; ++u) {
    int l = 2 - u;
    int nl = nL[l], nz = nL[l + 1];
    const float* Wt = up_W + u * 32768;
    const float* Wb = up_W + u * 32768 + 16384;
    const float* xsf = (u == 0) ? xs2f : (u == 1) ? xs1f : xs0f;
    matmul128<float, float, float><<<cdiv(nl, 64), 256, 0, stream>>>(xsf, Wb, nullptr, hf, nl);
    matmul128_sadd<<<cdiv(nz, 64), 256, 0, stream>>>(zf, Wt, idxL[l], hf, nz);
    agg_conv<false><<<cdiv(nl, 4), 256, 0, stream>>>(
        hf, csroL[l], csrsL[l], csrwL[l], dinvL[l], dgiL[l], up_b + u * 128, zf, nl);
    bn_up(zf, nl, up_g + u * 128, up_bt + u * 128);
  }

  // ---- final conv -> d_out ----
  matmul128<float, float, float><<<cdiv(N0_, 64), 256, 0, stream>>>(zf, out_W, nullptr, hf, N0_);
  agg_conv<false><<<cdiv(N0_, 4), 256, 0, stream>>>(
      hf, csro0, csrs0, csrw0, dinv0, dgi0, out_b, outp, N0_);
}